// Round 2
// baseline (5053.914 us; speedup 1.0000x reference)
//
#include <hip/hip_runtime.h>
#include <math.h>

typedef long long i64;

#define DIMC 384
#define DIM3 1152
#define HC 48
#define HWN 4096

// ---------------- utility kernels ----------------

__global__ void zero_kernel(float* __restrict__ p, int n) {
  int i = blockIdx.x * 256 + threadIdx.x;
  if (i < n) p[i] = 0.f;
}

// per-pixel LayerNorm stats over C=384 channels. one thread per pixel.
__global__ void stats_kernel(const float* __restrict__ x, float* __restrict__ mu,
                             float* __restrict__ rs, int npix) {
  int idx = blockIdx.x * 256 + threadIdx.x;
  if (idx >= npix) return;
  int b = idx >> 12, p = idx & 4095;
  const float* xp = x + ((i64)b * DIMC) * HWN + p;
  float s = 0.f, ss = 0.f;
  for (int c = 0; c < DIMC; ++c) { float v = xp[(i64)c * HWN]; s += v; ss += v * v; }
  float m = s * (1.f / DIMC);
  float var = ss * (1.f / DIMC) - m * m;
  mu[idx] = m;
  rs[idx] = rsqrtf(var + 1e-5f);
}

// depthwise 3x3, pad 1
__global__ void dw3x3_kernel(const float* __restrict__ in, const float* __restrict__ w,
                             const float* __restrict__ bias, float* __restrict__ out, int C) {
  i64 idx = (i64)blockIdx.x * 256 + threadIdx.x;  // over Bchunk*C*HW
  int xc = (int)(idx & 63);
  int yr = (int)((idx >> 6) & 63);
  i64 bc = idx >> 12;
  int c = (int)(bc % C);
  const float* ip = in + (bc << 12);
  const float* wp = w + (i64)c * 9;
  float acc = bias[c];
#pragma unroll
  for (int dy = -1; dy <= 1; ++dy) {
    int yy = yr + dy; if ((unsigned)yy >= 64u) continue;
#pragma unroll
    for (int dx = -1; dx <= 1; ++dx) {
      int xx = xc + dx; if ((unsigned)xx >= 64u) continue;
      acc += ip[yy * 64 + xx] * wp[(dy + 1) * 3 + (dx + 1)];
    }
  }
  out[idx] = acc;
}

// l2-normalize rows of 64 (one 64-thread block per row)
__global__ void l2row_kernel(const float* __restrict__ in, float* __restrict__ out) {
  int r = blockIdx.x;
  int lane = threadIdx.x;
  float v = in[r * 64 + lane];
  float ss = v * v;
  for (int o = 32; o > 0; o >>= 1) ss += __shfl_xor(ss, o);
  float n = fmaxf(sqrtf(ss), 1e-12f);
  out[r * 64 + lane] = v / n;
}

// conv 3x3, 3 -> 384 channels (batch-independent)
__global__ void spm_kernel(const float* __restrict__ s, const float* __restrict__ w,
                           const float* __restrict__ bias, float* __restrict__ out) {
  int idx = blockIdx.x * 256 + threadIdx.x;   // 384*4096
  int xc = idx & 63, yr = (idx >> 6) & 63, c = idx >> 12;
  const float* wp = w + c * 27;
  float acc = bias[c];
  for (int ic = 0; ic < 3; ++ic)
    for (int dy = -1; dy <= 1; ++dy) {
      int yy = yr + dy; if ((unsigned)yy >= 64u) continue;
      for (int dx = -1; dx <= 1; ++dx) {
        int xx = xc + dx; if ((unsigned)xx >= 64u) continue;
        acc += s[ic * 4096 + yy * 64 + xx] * wp[ic * 9 + (dy + 1) * 3 + (dx + 1)];
      }
    }
  out[idx] = acc;
}

// q/k normalization. QMODE: per-row l2n over W(64), * spm, then plane l2n over 4096.
// !QMODE: plane l2n only. One 256-thread block per (b,c) plane. coff = channel offset in input.
template <bool QMODE>
__global__ void qknorm_kernel(const float* __restrict__ in, int coff,
                              const float* __restrict__ spm, float* __restrict__ outp) {
  int blk = blockIdx.x;
  int b = blk / DIMC, c = blk % DIMC;
  const float* ip = in + ((i64)b * DIM3 + coff + c) * HWN;
  float* op = outp + ((i64)b * DIMC + c) * HWN;
  int t = threadIdx.x, wv = t >> 6, lane = t & 63;
  float tmp[16];
  float acc = 0.f;
#pragma unroll
  for (int i = 0; i < 16; ++i) {
    int y = wv + 4 * i;
    float v = ip[y * 64 + lane];
    if (QMODE) {
      float ss = v * v;
      for (int o = 32; o > 0; o >>= 1) ss += __shfl_xor(ss, o);
      v = v / fmaxf(sqrtf(ss), 1e-12f);
      v *= spm[(i64)c * HWN + y * 64 + lane];
    }
    tmp[i] = v;
    acc += v * v;
  }
  for (int o = 32; o > 0; o >>= 1) acc += __shfl_xor(acc, o);
  __shared__ float red[4];
  if (lane == 0) red[wv] = acc;
  __syncthreads();
  float inv = 1.f / fmaxf(sqrtf(red[0] + red[1] + red[2] + red[3]), 1e-12f);
#pragma unroll
  for (int i = 0; i < 16; ++i) op[(wv + 4 * i) * 64 + lane] = tmp[i] * inv;
}

// attn partials: attnP[bh][split][48][48] = qs_bh[:,slice] @ kr_bh[:,slice]^T (no atomics)
__global__ __launch_bounds__(256) void attnS_kernel(const float* __restrict__ qs,
                                                    const float* __restrict__ kr,
                                                    float* __restrict__ attnP) {
  int ksp = blockIdx.x;  // 0..15
  int bh = blockIdx.y;   // 0..C*8-1
  int b = bh >> 3, h = bh & 7;
  const float* qp = qs + ((i64)b * DIMC + h * HC) * HWN;
  const float* kp = kr + ((i64)b * DIMC + h * HC) * HWN;
  __shared__ float qsm[48][65];
  __shared__ float ksm[48][65];
  int t = threadIdx.x;
  int tc = t & 15, td = t >> 4;
  float acc[3][3] = {{0.f}};
  for (int sub = 0; sub < 4; ++sub) {
    int nb = ksp * 256 + sub * 64;
    __syncthreads();
    for (int l = t; l < 48 * 64; l += 256) {
      int rr = l >> 6, nn = l & 63;
      qsm[rr][nn] = qp[(i64)rr * HWN + nb + nn];
      ksm[rr][nn] = kp[(i64)rr * HWN + nb + nn];
    }
    __syncthreads();
#pragma unroll 4
    for (int nn = 0; nn < 64; ++nn) {
      float a0 = qsm[tc][nn], a1 = qsm[tc + 16][nn], a2 = qsm[tc + 32][nn];
      float b0 = ksm[td][nn], b1 = ksm[td + 16][nn], b2 = ksm[td + 32][nn];
      acc[0][0] += a0 * b0; acc[0][1] += a0 * b1; acc[0][2] += a0 * b2;
      acc[1][0] += a1 * b0; acc[1][1] += a1 * b1; acc[1][2] += a1 * b2;
      acc[2][0] += a2 * b0; acc[2][1] += a2 * b1; acc[2][2] += a2 * b2;
    }
  }
  float* ap = attnP + ((i64)bh * 16 + ksp) * 2304;
#pragma unroll
  for (int i = 0; i < 3; ++i)
#pragma unroll
    for (int j = 0; j < 3; ++j)
      ap[(tc + 16 * i) * HC + (td + 16 * j)] = acc[i][j];
}

// combined blend weights: comb = wsm0*(Σc)*relu(a) + wsm1*Σ c_i*masked_softmax_{k_i}(a)
__global__ void blend_kernel(const float* __restrict__ attnP, const float* __restrict__ temp,
                             const float* __restrict__ wmix, const float* __restrict__ pa1,
                             const float* __restrict__ pa2, const float* __restrict__ pa3,
                             const float* __restrict__ pa4, float* __restrict__ comb) {
  int row = blockIdx.x * 4 + (threadIdx.x >> 6);  // 0..C*384-1
  int lane = threadIdx.x & 63;
  int bh = row / 48, cc = row - bh * 48;
  int h = bh & 7;
  float a;
  if (lane < 48) {
    const float* pp = attnP + ((i64)bh * 16) * 2304 + cc * 48 + lane;
    float s = 0.f;
#pragma unroll
    for (int sp = 0; sp < 16; ++sp) s += pp[(i64)sp * 2304];
    a = s * temp[h];
  } else {
    a = -INFINITY;
  }
  int rank = 0;
  for (int j = 0; j < 48; ++j) {
    float aj = __shfl(a, j);
    rank += (aj > a) ? 1 : 0;
  }
  float w0 = wmix[0], w1 = wmix[1];
  float wm = fmaxf(w0, w1);
  float e0 = expf(w0 - wm), e1 = expf(w1 - wm);
  float ws0 = e0 / (e0 + e1), ws1 = e1 / (e0 + e1);
  float c1 = pa1[0], c2 = pa2[0], c3 = pa3[0], c4 = pa4[0];
  float outv = ws0 * (c1 + c2 + c3 + c4) * fmaxf(a, 0.f);
  const int kks[4] = {24, 32, 36, 38};
  const float cs[4] = {c1, c2, c3, c4};
#pragma unroll
  for (int q = 0; q < 4; ++q) {
    float mv = (lane < 48) ? ((rank < kks[q]) ? a : a * 1e-6f) : -INFINITY;
    float mx = mv;
    for (int o = 32; o > 0; o >>= 1) mx = fmaxf(mx, __shfl_xor(mx, o));
    float e = (lane < 48) ? expf(mv - mx) : 0.f;
    float s = e;
    for (int o = 32; o > 0; o >>= 1) s += __shfl_xor(s, o);
    outv += ws1 * cs[q] * (e / s);
  }
  if (lane < 48) comb[(i64)row * 48 + lane] = outv;
}

// mat-vec: out[o] = sum_k Wm[o*ldw + koff + k]*v[k] + add[o]
__global__ void matvec_kernel(const float* __restrict__ Wm, int ldw, int koff,
                              const float* __restrict__ v, const float* __restrict__ add,
                              float* __restrict__ out, int K) {
  int ro = blockIdx.x;
  int t = threadIdx.x;
  const float* wp = Wm + (i64)ro * ldw + koff;
  float s = 0.f;
  for (int k = t; k < K; k += 256) s += wp[k] * v[k];
  __shared__ float sred[256];
  sred[t] = s;
  __syncthreads();
  for (int o = 128; o > 0; o >>= 1) {
    if (t < o) sred[t] += sred[t + o];
    __syncthreads();
  }
  if (t == 0) out[ro] = sred[0] + (add ? add[ro] : 0.f);
}

// 64x64 tile GEMM, 4x4 micro, dual batch dims + optional split-K with atomics.
__global__ __launch_bounds__(256) void gemm64_kernel(
    const float* __restrict__ W, int ldw, i64 wbo, i64 wbi,
    const float* __restrict__ X, i64 xbo, i64 xbi,
    const float* __restrict__ bias,
    float* __restrict__ Y, i64 ybo, i64 ybi,
    int M, int N, int K, int nbi, int ksplit) {
  int nt = blockIdx.x, mt = blockIdx.y;
  int zz = blockIdx.z;
  int ks = zz % ksplit;
  int batch = zz / ksplit;
  int bo = batch / nbi, bi = batch % nbi;
  const float* Wp = W + (i64)bo * wbo + (i64)bi * wbi;
  const float* Xp = X + (i64)bo * xbo + (i64)bi * xbi;
  float* Yp = Y + (i64)bo * ybo + (i64)bi * ybi;
  int kchunk = (((K + ksplit - 1) / ksplit) + 15) & ~15;
  int kbeg = ks * kchunk;
  int kend = min(K, kbeg + kchunk);
  __shared__ float As[16][68];
  __shared__ float Bs[16][68];
  int t = threadIdx.x, tx = t & 15, ty = t >> 4;
  int m0 = mt * 64, n0 = nt * 64;
  float acc[4][4];
#pragma unroll
  for (int i = 0; i < 4; ++i)
#pragma unroll
    for (int j = 0; j < 4; ++j) acc[i][j] = 0.f;
  for (int k0 = kbeg; k0 < kend; k0 += 16) {
    int kk = t & 15;
#pragma unroll
    for (int r = 0; r < 4; ++r) {
      int mm = (t >> 4) + r * 16;
      int gm = m0 + mm, gk = k0 + kk;
      As[kk][mm] = (gm < M && gk < kend) ? Wp[(i64)gm * ldw + gk] : 0.f;
    }
    int nn = t & 63;
#pragma unroll
    for (int r = 0; r < 4; ++r) {
      int k2 = (t >> 6) + r * 4;
      int gk = k0 + k2;
      Bs[k2][nn] = (gk < kend && n0 + nn < N) ? Xp[(i64)gk * N + n0 + nn] : 0.f;
    }
    __syncthreads();
#pragma unroll
    for (int kk3 = 0; kk3 < 16; ++kk3) {
      float4 av = *(const float4*)&As[kk3][ty * 4];
      float4 bv = *(const float4*)&Bs[kk3][tx * 4];
      float aa[4] = {av.x, av.y, av.z, av.w};
      float bb2[4] = {bv.x, bv.y, bv.z, bv.w};
#pragma unroll
      for (int i = 0; i < 4; ++i)
#pragma unroll
        for (int j = 0; j < 4; ++j) acc[i][j] += aa[i] * bb2[j];
    }
    __syncthreads();
  }
#pragma unroll
  for (int i = 0; i < 4; ++i) {
    int gm = m0 + ty * 4 + i;
    if (gm >= M || n0 + tx * 4 >= N) continue;
    if (ksplit > 1) {
      for (int j = 0; j < 4; ++j) atomicAdd(&Yp[(i64)gm * N + n0 + tx * 4 + j], acc[i][j]);
    } else {
      float bvv = bias ? bias[gm] : 0.f;
      float4* yp = (float4*)(Yp + (i64)gm * N + n0 + tx * 4);
      *yp = make_float4(acc[i][0] + bvv, acc[i][1] + bvv, acc[i][2] + bvv, acc[i][3] + bvv);
    }
  }
}

// 128x128 tile GEMM, 8x8 micro, N fixed 4096. Optional 2nd pass (W2,X2,K2) K-concat
// accumulated into same output. LayerNorm-on-load applied to pass `lnpass` (-1 = none).
// epilogues: 0=bias, 1=bias+residual, 2=bias+gelu(y)*y
__global__ __launch_bounds__(256) void gemm128_kernel(
    const float* __restrict__ W, int ldw,
    const float* __restrict__ X, i64 xbs,
    const float* __restrict__ W2, int ldw2,
    const float* __restrict__ X2, i64 x2bs, int K2,
    const float* __restrict__ mu, const float* __restrict__ rs,
    const float* __restrict__ gln, const float* __restrict__ bln, int lnpass,
    const float* __restrict__ bias,
    const float* __restrict__ R, i64 rbs,
    float* __restrict__ Y, i64 ybs,
    int M, int K, int epi) {
  const int N = HWN;
  int nt = blockIdx.x, mt = blockIdx.y, b = blockIdx.z;
  __shared__ float As[16][132];
  __shared__ float Bs[16][132];
  int t = threadIdx.x;
  int tx = t & 15, ty = t >> 4;
  int m0 = mt * 128, n0 = nt * 128;
  int nn = t & 127;
  float mun = 0.f, rsn = 1.f;
  if (lnpass >= 0) {
    mun = mu[(i64)b * HWN + n0 + nn];
    rsn = rs[(i64)b * HWN + n0 + nn];
  }
  float acc[8][8];
#pragma unroll
  for (int i = 0; i < 8; ++i)
#pragma unroll
    for (int j = 0; j < 8; ++j) acc[i][j] = 0.f;

  for (int pass = 0; pass < 2; ++pass) {
    const float* Wc;
    const float* Xc;
    int Kc, ldc;
    if (pass == 0) {
      Wc = W; Xc = X + (i64)b * xbs; Kc = K; ldc = ldw;
    } else {
      if (!W2) break;
      Wc = W2; Xc = X2 + (i64)b * x2bs; Kc = K2; ldc = ldw2;
    }
    bool doln = (lnpass == pass);
    for (int k0 = 0; k0 < Kc; k0 += 16) {
      int kk = t & 15;
#pragma unroll
      for (int r = 0; r < 8; ++r) {
        int mm = (t >> 4) + r * 16;
        int gm = m0 + mm, gk = k0 + kk;
        As[kk][mm] = (gm < M && gk < Kc) ? Wc[(i64)gm * ldc + gk] : 0.f;
      }
#pragma unroll
      for (int r = 0; r < 8; ++r) {
        int k2 = (t >> 7) + r * 2;
        int gk = k0 + k2;
        float v = 0.f;
        if (gk < Kc) {
          v = Xc[(i64)gk * N + n0 + nn];
          if (doln) v = (v - mun) * rsn * gln[gk] + bln[gk];
        }
        Bs[k2][nn] = v;
      }
      __syncthreads();
#pragma unroll
      for (int kk3 = 0; kk3 < 16; ++kk3) {
        float4 a0 = *(const float4*)&As[kk3][ty * 8];
        float4 a1 = *(const float4*)&As[kk3][ty * 8 + 4];
        float4 b0 = *(const float4*)&Bs[kk3][tx * 8];
        float4 b1 = *(const float4*)&Bs[kk3][tx * 8 + 4];
        float aa[8] = {a0.x, a0.y, a0.z, a0.w, a1.x, a1.y, a1.z, a1.w};
        float bv[8] = {b0.x, b0.y, b0.z, b0.w, b1.x, b1.y, b1.z, b1.w};
#pragma unroll
        for (int i = 0; i < 8; ++i)
#pragma unroll
          for (int j = 0; j < 8; ++j) acc[i][j] += aa[i] * bv[j];
      }
      __syncthreads();
    }
  }
  float* Yp = Y + (i64)b * ybs;
#pragma unroll
  for (int i = 0; i < 8; ++i) {
    int gm = m0 + ty * 8 + i;
    if (gm >= M) continue;
    float bvv = bias ? bias[gm] : 0.f;
    float o[8];
#pragma unroll
    for (int j = 0; j < 8; ++j) o[j] = acc[i][j] + bvv;
    if (epi == 1) {
      const float4* rp = (const float4*)(R + (i64)b * rbs + (i64)gm * N + n0 + tx * 8);
      float4 r0 = rp[0], r1 = rp[1];
      o[0] += r0.x; o[1] += r0.y; o[2] += r0.z; o[3] += r0.w;
      o[4] += r1.x; o[5] += r1.y; o[6] += r1.z; o[7] += r1.w;
    } else if (epi == 2) {
#pragma unroll
      for (int j = 0; j < 8; ++j) {
        float v = o[j];
        float gg = 0.5f * v * (1.f + erff(v * 0.70710678118f));
        o[j] = gg * v;
      }
    }
    float4* yp4 = (float4*)(Yp + (i64)gm * N + n0 + tx * 8);
    yp4[0] = make_float4(o[0], o[1], o[2], o[3]);
    yp4[1] = make_float4(o[4], o[5], o[6], o[7]);
  }
}

// ---------------- launch ----------------

extern "C" void kernel_launch(void* const* d_in, const int* in_sizes, int n_in,
                              void* d_out, int out_size, void* d_ws, size_t ws_size,
                              hipStream_t stream) {
  (void)in_sizes; (void)n_in; (void)out_size;
  const float* x       = (const float*)d_in[0];
  const float* spf     = (const float*)d_in[1];
  const float* ln1_w   = (const float*)d_in[2];
  const float* ln1_b   = (const float*)d_in[3];
  const float* qkv_w   = (const float*)d_in[4];
  const float* qkv_b   = (const float*)d_in[5];
  const float* qkvdw_w = (const float*)d_in[6];
  const float* qkvdw_b = (const float*)d_in[7];
  const float* proj_w  = (const float*)d_in[8];
  const float* proj_b  = (const float*)d_in[9];
  const float* temp    = (const float*)d_in[10];
  const float* a1      = (const float*)d_in[11];
  const float* a2      = (const float*)d_in[12];
  const float* a3      = (const float*)d_in[13];
  const float* a4      = (const float*)d_in[14];
  const float* wmix    = (const float*)d_in[15];
  const float* pout_w  = (const float*)d_in[16];
  const float* pout_b  = (const float*)d_in[17];
  const float* ln2_w   = (const float*)d_in[18];
  const float* ln2_b   = (const float*)d_in[19];
  const float* pin_w   = (const float*)d_in[20];
  const float* pin_b   = (const float*)d_in[21];
  const float* dw_w    = (const float*)d_in[22];
  const float* dw_b    = (const float*)d_in[23];
  const float* lin_w   = (const float*)d_in[24];
  const float* lin_b   = (const float*)d_in[25];
  const float* adj_w   = (const float*)d_in[26];
  const float* adj_b   = (const float*)d_in[27];
  const float* fout_w  = (const float*)d_in[28];
  const float* fout_b  = (const float*)d_in[29];
  float* out = (float*)d_out;
  float* ws = (float*)d_ws;

  const i64 PLANE = (i64)DIMC * HWN;        // 1,572,864
  const i64 FIXED = 2502400;
  const i64 PER = 9750528;
  int C = 8;
  while (C > 1 && (size_t)(FIXED + PER * C) * 4 > ws_size) C >>= 1;
  if ((size_t)(FIXED + PER * C) * 4 > ws_size) return;  // ws too small -> visible failure
  int nch = 8 / C;

  float* SPM   = ws;
  float* W2v   = SPM + PLANE;
  float* W3v   = W2v + 392064;
  float* b2v   = W3v + 392064;
  float* b3v   = b2v + 1024;
  float* spfn  = b3v + 1024;
  float* mu1   = spfn + 12288;
  float* rs1   = mu1 + 32768;
  float* mu2   = rs1 + 32768;
  float* rs2   = mu2 + 32768;
  float* attnP = rs2 + 32768;
  float* comb  = attnP + (i64)C * 294912;
  float* BufQ  = comb + (i64)C * 18432;
  float* BufD  = BufQ + (i64)C * 4718592;

  // ---- precompute (once) ----
  zero_kernel<<<dim3(3063), dim3(256), 0, stream>>>(W2v, 784128);
  matvec_kernel<<<dim3(1021), dim3(256), 0, stream>>>(lin_w, 1021, 0, pin_b + 1021, lin_b, b2v, 1021);
  gemm64_kernel<<<dim3(6, 16, 8), dim3(256), 0, stream>>>(
      lin_w, 1021, 0, 0, pin_w + (i64)1021 * 384, 0, 0, nullptr, W2v, 0, 0,
      1021, 384, 1021, 1, 8);
  matvec_kernel<<<dim3(1021), dim3(256), 0, stream>>>(adj_w, 2042, 1021, b2v, adj_b, b3v, 1021);
  gemm64_kernel<<<dim3(6, 16, 8), dim3(256), 0, stream>>>(
      adj_w + 1021, 2042, 0, 0, W2v, 0, 0, nullptr, W3v, 0, 0,
      1021, 384, 1021, 1, 8);
  l2row_kernel<<<dim3(192), dim3(64), 0, stream>>>(spf, spfn);
  spm_kernel<<<dim3(6144), dim3(256), 0, stream>>>(spfn, proj_w, proj_b, SPM);
  stats_kernel<<<dim3(128), dim3(256), 0, stream>>>(x, mu1, rs1, 32768);

  for (int ch = 0; ch < nch; ++ch) {
    int b0 = ch * C;
    const float* xb = x + (i64)b0 * PLANE;
    float* outb = out + (i64)b0 * PLANE;
    const float* m1 = mu1 + (i64)b0 * HWN;
    const float* r1 = rs1 + (i64)b0 * HWN;
    float* m2 = mu2 + (i64)b0 * HWN;
    float* r2 = rs2 + (i64)b0 * HWN;
    float* QS = BufQ;
    float* KR = BufQ + (i64)C * PLANE;

    // ---- attention ----
    gemm128_kernel<<<dim3(32, 9, C), dim3(256), 0, stream>>>(
        qkv_w, 384, xb, PLANE, nullptr, 0, nullptr, 0, 0,
        m1, r1, ln1_w, ln1_b, 0,
        qkv_b, nullptr, 0, BufQ, (i64)DIM3 * HWN, 1152, 384, 0);
    dw3x3_kernel<<<dim3(18432 * C), dim3(256), 0, stream>>>(BufQ, qkvdw_w, qkvdw_b, BufD, 1152);
    qknorm_kernel<true><<<dim3(C * 384), dim3(256), 0, stream>>>(BufD, 0, SPM, QS);
    qknorm_kernel<false><<<dim3(C * 384), dim3(256), 0, stream>>>(BufD, 384, nullptr, KR);
    attnS_kernel<<<dim3(16, C * 8), dim3(256), 0, stream>>>(QS, KR, attnP);
    blend_kernel<<<dim3(96 * C), dim3(256), 0, stream>>>(attnP, temp, wmix, a1, a2, a3, a4, comb);
    gemm64_kernel<<<dim3(64, 1, C * 8), dim3(256), 0, stream>>>(
        comb, 48, (i64)8 * 2304, 2304,
        BufD + (i64)768 * HWN, (i64)DIM3 * HWN, (i64)HC * HWN,
        nullptr, BufQ, PLANE, (i64)HC * HWN,
        48, 4096, 48, 8, 1);
    gemm128_kernel<<<dim3(32, 3, C), dim3(256), 0, stream>>>(
        pout_w, 384, BufQ, PLANE, nullptr, 0, nullptr, 0, 0,
        nullptr, nullptr, nullptr, nullptr, -1,
        pout_b, xb, PLANE, outb, PLANE, 384, 384, 1);

    // ---- feed-forward ----
    stats_kernel<<<dim3(16 * C), dim3(256), 0, stream>>>(outb, m2, r2, C * 4096);
    gemm128_kernel<<<dim3(32, 8, C), dim3(256), 0, stream>>>(
        pin_w, 384, outb, PLANE, nullptr, 0, nullptr, 0, 0,
        m2, r2, ln2_w, ln2_b, 0,
        pin_b, nullptr, 0, BufQ, (i64)1021 * HWN, 1021, 384, 0);
    dw3x3_kernel<<<dim3(16336 * C), dim3(256), 0, stream>>>(BufQ, dw_w, dw_b, BufD, 1021);
    gemm128_kernel<<<dim3(32, 8, C), dim3(256), 0, stream>>>(
        adj_w, 2042, BufD, (i64)1021 * HWN,
        W3v, 384, outb, PLANE, 384,
        m2, r2, ln2_w, ln2_b, 1,
        b3v, nullptr, 0, BufQ, (i64)1021 * HWN, 1021, 1021, 2);
    gemm128_kernel<<<dim3(32, 3, C), dim3(256), 0, stream>>>(
        fout_w, 1021, BufQ, (i64)1021 * HWN, nullptr, 0, nullptr, 0, 0,
        nullptr, nullptr, nullptr, nullptr, -1,
        fout_b, outb, PLANE, outb, PLANE, 384, 1021, 1);
  }
}

// Round 3
// 1780.376 us; speedup vs baseline: 2.8387x; 2.8387x over previous
//
#include <hip/hip_runtime.h>
#include <math.h>

typedef long long i64;
typedef unsigned short u16;
typedef unsigned int u32;

#define DIMC 384
#define DIM3 1152
#define HC 48
#define HWN 4096

using bf16x8 = __attribute__((ext_vector_type(8))) short;
using f32x4 = __attribute__((ext_vector_type(4))) float;

__device__ __forceinline__ float bf2f(u16 u) { u32 x = ((u32)u) << 16; return __uint_as_float(x); }
__device__ __forceinline__ u16 f2bf(float f) {
  u32 u = __float_as_uint(f);
  u32 r = u + 0x7FFFu + ((u >> 16) & 1u);
  return (u16)(r >> 16);
}
__device__ __forceinline__ float cvt_in(float x) { return x; }
__device__ __forceinline__ float cvt_in(u16 x) { return bf2f(x); }
__device__ __forceinline__ void st_out(float* p, float v) { *p = v; }
__device__ __forceinline__ void st_out(u16* p, float v) { *p = f2bf(v); }

// ---------------- utility kernels ----------------

__global__ void zero_kernel(float* __restrict__ p, int n) {
  int i = blockIdx.x * 256 + threadIdx.x;
  if (i < n) p[i] = 0.f;
}

// per-pixel LayerNorm stats over C=384 channels. one thread per pixel.
__global__ void stats_kernel(const float* __restrict__ x, float* __restrict__ mu,
                             float* __restrict__ rs, int npix) {
  int idx = blockIdx.x * 256 + threadIdx.x;
  if (idx >= npix) return;
  int b = idx >> 12, p = idx & 4095;
  const float* xp = x + ((i64)b * DIMC) * HWN + p;
  float s = 0.f, ss = 0.f;
  for (int c = 0; c < DIMC; ++c) { float v = xp[(i64)c * HWN]; s += v; ss += v * v; }
  float m = s * (1.f / DIMC);
  float var = ss * (1.f / DIMC) - m * m;
  mu[idx] = m;
  rs[idx] = rsqrtf(var + 1e-5f);
}

// LayerNorm apply -> bf16. layout [Cb][384][4096]
__global__ void ln_bf16_kernel(const float* __restrict__ x, const float* __restrict__ mu,
                               const float* __restrict__ rs, const float* __restrict__ g,
                               const float* __restrict__ bb, u16* __restrict__ y, i64 total) {
  i64 idx = (i64)blockIdx.x * 256 + threadIdx.x;
  if (idx >= total) return;
  int p = (int)(idx & 4095);
  int c = (int)((idx >> 12) % DIMC);
  int b = (int)(idx / ((i64)DIMC * HWN));
  float v = (x[idx] - mu[b * HWN + p]) * rs[b * HWN + p] * g[c] + bb[c];
  y[idx] = f2bf(v);
}

// depthwise 3x3, pad 1 (templated in/out types)
template <typename TI, typename TO>
__global__ void dw3x3_kernel(const TI* __restrict__ in, const float* __restrict__ w,
                             const float* __restrict__ bias, TO* __restrict__ out, int C) {
  i64 idx = (i64)blockIdx.x * 256 + threadIdx.x;
  int xc = (int)(idx & 63);
  int yr = (int)((idx >> 6) & 63);
  i64 bc = idx >> 12;
  int c = (int)(bc % C);
  const TI* ip = in + (bc << 12);
  const float* wp = w + (i64)c * 9;
  float acc = bias[c];
#pragma unroll
  for (int dy = -1; dy <= 1; ++dy) {
    int yy = yr + dy; if ((unsigned)yy >= 64u) continue;
#pragma unroll
    for (int dx = -1; dx <= 1; ++dx) {
      int xx = xc + dx; if ((unsigned)xx >= 64u) continue;
      acc += cvt_in(ip[yy * 64 + xx]) * wp[(dy + 1) * 3 + (dx + 1)];
    }
  }
  st_out(&out[idx], acc);
}

// l2-normalize rows of 64
__global__ void l2row_kernel(const float* __restrict__ in, float* __restrict__ out) {
  int r = blockIdx.x;
  int lane = threadIdx.x;
  float v = in[r * 64 + lane];
  float ss = v * v;
  for (int o = 32; o > 0; o >>= 1) ss += __shfl_xor(ss, o);
  float n = fmaxf(sqrtf(ss), 1e-12f);
  out[r * 64 + lane] = v / n;
}

// conv 3x3, 3 -> 384 channels
__global__ void spm_kernel(const float* __restrict__ s, const float* __restrict__ w,
                           const float* __restrict__ bias, float* __restrict__ out) {
  int idx = blockIdx.x * 256 + threadIdx.x;
  int xc = idx & 63, yr = (idx >> 6) & 63, c = idx >> 12;
  const float* wp = w + c * 27;
  float acc = bias[c];
  for (int ic = 0; ic < 3; ++ic)
    for (int dy = -1; dy <= 1; ++dy) {
      int yy = yr + dy; if ((unsigned)yy >= 64u) continue;
      for (int dx = -1; dx <= 1; ++dx) {
        int xx = xc + dx; if ((unsigned)xx >= 64u) continue;
        acc += s[ic * 4096 + yy * 64 + xx] * wp[ic * 9 + (dy + 1) * 3 + (dx + 1)];
      }
    }
  out[idx] = acc;
}

// q/k normalization (input fp32 from dw output). QMODE: row-l2n*spm then plane-l2n.
template <bool QMODE>
__global__ void qknorm_kernel(const float* __restrict__ in, int coff,
                              const float* __restrict__ spm, float* __restrict__ outp) {
  int blk = blockIdx.x;
  int b = blk / DIMC, c = blk % DIMC;
  const float* ip = in + ((i64)b * DIM3 + coff + c) * HWN;
  float* op = outp + ((i64)b * DIMC + c) * HWN;
  int t = threadIdx.x, wv = t >> 6, lane = t & 63;
  float tmp[16];
  float acc = 0.f;
#pragma unroll
  for (int i = 0; i < 16; ++i) {
    int y = wv + 4 * i;
    float v = ip[y * 64 + lane];
    if (QMODE) {
      float ss = v * v;
      for (int o = 32; o > 0; o >>= 1) ss += __shfl_xor(ss, o);
      v = v / fmaxf(sqrtf(ss), 1e-12f);
      v *= spm[(i64)c * HWN + y * 64 + lane];
    }
    tmp[i] = v;
    acc += v * v;
  }
  for (int o = 32; o > 0; o >>= 1) acc += __shfl_xor(acc, o);
  __shared__ float red[4];
  if (lane == 0) red[wv] = acc;
  __syncthreads();
  float inv = 1.f / fmaxf(sqrtf(red[0] + red[1] + red[2] + red[3]), 1e-12f);
#pragma unroll
  for (int i = 0; i < 16; ++i) op[(wv + 4 * i) * 64 + lane] = tmp[i] * inv;
}

// attn partials: attnP[bh][split][48][48]
__global__ __launch_bounds__(256) void attnS_kernel(const float* __restrict__ qs,
                                                    const float* __restrict__ kr,
                                                    float* __restrict__ attnP) {
  int ksp = blockIdx.x;
  int bh = blockIdx.y;
  int b = bh >> 3, h = bh & 7;
  const float* qp = qs + ((i64)b * DIMC + h * HC) * HWN;
  const float* kp = kr + ((i64)b * DIMC + h * HC) * HWN;
  __shared__ float qsm[48][65];
  __shared__ float ksm[48][65];
  int t = threadIdx.x;
  int tc = t & 15, td = t >> 4;
  float acc[3][3] = {{0.f}};
  for (int sub = 0; sub < 4; ++sub) {
    int nb = ksp * 256 + sub * 64;
    __syncthreads();
    for (int l = t; l < 48 * 64; l += 256) {
      int rr = l >> 6, nn = l & 63;
      qsm[rr][nn] = qp[(i64)rr * HWN + nb + nn];
      ksm[rr][nn] = kp[(i64)rr * HWN + nb + nn];
    }
    __syncthreads();
#pragma unroll 4
    for (int nn = 0; nn < 64; ++nn) {
      float a0 = qsm[tc][nn], a1 = qsm[tc + 16][nn], a2 = qsm[tc + 32][nn];
      float b0 = ksm[td][nn], b1 = ksm[td + 16][nn], b2 = ksm[td + 32][nn];
      acc[0][0] += a0 * b0; acc[0][1] += a0 * b1; acc[0][2] += a0 * b2;
      acc[1][0] += a1 * b0; acc[1][1] += a1 * b1; acc[1][2] += a1 * b2;
      acc[2][0] += a2 * b0; acc[2][1] += a2 * b1; acc[2][2] += a2 * b2;
    }
  }
  float* ap = attnP + ((i64)bh * 16 + ksp) * 2304;
#pragma unroll
  for (int i = 0; i < 3; ++i)
#pragma unroll
    for (int j = 0; j < 3; ++j)
      ap[(tc + 16 * i) * HC + (td + 16 * j)] = acc[i][j];
}

// combined blend weights
__global__ void blend_kernel(const float* __restrict__ attnP, const float* __restrict__ temp,
                             const float* __restrict__ wmix, const float* __restrict__ pa1,
                             const float* __restrict__ pa2, const float* __restrict__ pa3,
                             const float* __restrict__ pa4, float* __restrict__ comb) {
  int row = blockIdx.x * 4 + (threadIdx.x >> 6);
  int lane = threadIdx.x & 63;
  int bh = row / 48, cc = row - bh * 48;
  int h = bh & 7;
  float a;
  if (lane < 48) {
    const float* pp = attnP + ((i64)bh * 16) * 2304 + cc * 48 + lane;
    float s = 0.f;
#pragma unroll
    for (int sp = 0; sp < 16; ++sp) s += pp[(i64)sp * 2304];
    a = s * temp[h];
  } else {
    a = -INFINITY;
  }
  int rank = 0;
  for (int j = 0; j < 48; ++j) {
    float aj = __shfl(a, j);
    rank += (aj > a) ? 1 : 0;
  }
  float w0 = wmix[0], w1 = wmix[1];
  float wm = fmaxf(w0, w1);
  float e0 = expf(w0 - wm), e1 = expf(w1 - wm);
  float ws0 = e0 / (e0 + e1), ws1 = e1 / (e0 + e1);
  float c1 = pa1[0], c2 = pa2[0], c3 = pa3[0], c4 = pa4[0];
  float outv = ws0 * (c1 + c2 + c3 + c4) * fmaxf(a, 0.f);
  const int kks[4] = {24, 32, 36, 38};
  const float cs[4] = {c1, c2, c3, c4};
#pragma unroll
  for (int q = 0; q < 4; ++q) {
    float mv = (lane < 48) ? ((rank < kks[q]) ? a : a * 1e-6f) : -INFINITY;
    float mx = mv;
    for (int o = 32; o > 0; o >>= 1) mx = fmaxf(mx, __shfl_xor(mx, o));
    float e = (lane < 48) ? expf(mv - mx) : 0.f;
    float s = e;
    for (int o = 32; o > 0; o >>= 1) s += __shfl_xor(s, o);
    outv += ws1 * cs[q] * (e / s);
  }
  if (lane < 48) comb[(i64)row * 48 + lane] = outv;
}

// mat-vec
__global__ void matvec_kernel(const float* __restrict__ Wm, int ldw, int koff,
                              const float* __restrict__ v, const float* __restrict__ add,
                              float* __restrict__ out, int K) {
  int ro = blockIdx.x;
  int t = threadIdx.x;
  const float* wp = Wm + (i64)ro * ldw + koff;
  float s = 0.f;
  for (int k = t; k < K; k += 256) s += wp[k] * v[k];
  __shared__ float sred[256];
  sred[t] = s;
  __syncthreads();
  for (int o = 128; o > 0; o >>= 1) {
    if (t < o) sred[t] += sred[t + o];
    __syncthreads();
  }
  if (t == 0) out[ro] = sred[0] + (add ? add[ro] : 0.f);
}

// 64x64 fp32 GEMM (precompute + comb@vr). outbf: write bf16 (non-splitK path only).
__global__ __launch_bounds__(256) void gemm64_kernel(
    const float* __restrict__ W, int ldw, i64 wbo, i64 wbi,
    const float* __restrict__ X, i64 xbo, i64 xbi,
    const float* __restrict__ bias,
    void* __restrict__ Y, i64 ybo, i64 ybi,
    int M, int N, int K, int nbi, int ksplit, int outbf) {
  int nt = blockIdx.x, mt = blockIdx.y;
  int zz = blockIdx.z;
  int ks = zz % ksplit;
  int batch = zz / ksplit;
  int bo = batch / nbi, bi = batch % nbi;
  const float* Wp = W + (i64)bo * wbo + (i64)bi * wbi;
  const float* Xp = X + (i64)bo * xbo + (i64)bi * xbi;
  int kchunk = (((K + ksplit - 1) / ksplit) + 15) & ~15;
  int kbeg = ks * kchunk;
  int kend = min(K, kbeg + kchunk);
  __shared__ float As[16][68];
  __shared__ float Bs[16][68];
  int t = threadIdx.x, tx = t & 15, ty = t >> 4;
  int m0 = mt * 64, n0 = nt * 64;
  float acc[4][4];
#pragma unroll
  for (int i = 0; i < 4; ++i)
#pragma unroll
    for (int j = 0; j < 4; ++j) acc[i][j] = 0.f;
  for (int k0 = kbeg; k0 < kend; k0 += 16) {
    int kk = t & 15;
#pragma unroll
    for (int r = 0; r < 4; ++r) {
      int mm = (t >> 4) + r * 16;
      int gm = m0 + mm, gk = k0 + kk;
      As[kk][mm] = (gm < M && gk < kend) ? Wp[(i64)gm * ldw + gk] : 0.f;
    }
    int nn = t & 63;
#pragma unroll
    for (int r = 0; r < 4; ++r) {
      int k2 = (t >> 6) + r * 4;
      int gk = k0 + k2;
      Bs[k2][nn] = (gk < kend && n0 + nn < N) ? Xp[(i64)gk * N + n0 + nn] : 0.f;
    }
    __syncthreads();
#pragma unroll
    for (int kk3 = 0; kk3 < 16; ++kk3) {
      float4 av = *(const float4*)&As[kk3][ty * 4];
      float4 bv = *(const float4*)&Bs[kk3][tx * 4];
      float aa[4] = {av.x, av.y, av.z, av.w};
      float bb2[4] = {bv.x, bv.y, bv.z, bv.w};
#pragma unroll
      for (int i = 0; i < 4; ++i)
#pragma unroll
        for (int j = 0; j < 4; ++j) acc[i][j] += aa[i] * bb2[j];
    }
    __syncthreads();
  }
#pragma unroll
  for (int i = 0; i < 4; ++i) {
    int gm = m0 + ty * 4 + i;
    if (gm >= M || n0 + tx * 4 >= N) continue;
    float bvv = bias ? bias[gm] : 0.f;
    if (ksplit > 1) {
      float* Yp = (float*)Y + (i64)bo * ybo + (i64)bi * ybi;
      for (int j = 0; j < 4; ++j) atomicAdd(&Yp[(i64)gm * N + n0 + tx * 4 + j], acc[i][j]);
    } else if (outbf) {
      u16* Yp = (u16*)Y + (i64)bo * ybo + (i64)bi * ybi;
      for (int j = 0; j < 4; ++j) Yp[(i64)gm * N + n0 + tx * 4 + j] = f2bf(acc[i][j] + bvv);
    } else {
      float* Yp = (float*)Y + (i64)bo * ybo + (i64)bi * ybi;
      float4* yp = (float4*)(Yp + (i64)gm * N + n0 + tx * 4);
      *yp = make_float4(acc[i][0] + bvv, acc[i][1] + bvv, acc[i][2] + bvv, acc[i][3] + bvv);
    }
  }
}

// pack fp32 weight [M][ldw] (cols koff..koff+K) into MFMA fragment order:
// out[((fm*KS+ks)*64 + lane)*8 + j] = bf16(W[fm*16 + (lane&15)][koff + ks*32 + (lane>>4)*8 + j])
__global__ void pack_w_kernel(const float* __restrict__ W, int ldw, int koff, int M, int K,
                              int KS, u16* __restrict__ out, int nfrag) {
  int tid = blockIdx.x * 256 + threadIdx.x;
  int lane = tid & 63;
  int idx = tid >> 6;
  if (idx >= nfrag * KS) return;
  int ks = idx % KS, fm = idx / KS;
  int row = fm * 16 + (lane & 15);
  int kb = ks * 32 + (lane >> 4) * 8;
  union { u16 us[8]; uint4 q; } u;
#pragma unroll
  for (int j = 0; j < 8; ++j) {
    int k = kb + j;
    u.us[j] = (row < M && k < K) ? f2bf(W[(i64)row * ldw + koff + k]) : (u16)0;
  }
  *(uint4*)(out + (i64)idx * 512 + lane * 8) = u.q;
}

// ---------------- MFMA GEMM ----------------
// Y[M][4096] (+batch) = Wp1 @ B1 (+ Wp2 @ B2, K-concat) + bias, epilogues.
// Wp*: packed bf16 weights (see pack_w_kernel). B*: bf16 [K][4096] row-major per batch.
// epi: 0 = bias -> bf16 out; 1 = bias + residual(fp32) -> fp32 out; 2 = bias + gelu(y)*y -> bf16 out
__global__ __launch_bounds__(256) void gemm_mfma_kernel(
    const u16* __restrict__ Wp1, int KS1, int K1, const u16* __restrict__ B1g, i64 b1s,
    const u16* __restrict__ Wp2, int KS2, int K2, const u16* __restrict__ B2g, i64 b2s,
    const float* __restrict__ bias, const float* __restrict__ R, i64 rbs,
    void* __restrict__ Yv, i64 ybs, int M, int epi) {
  __shared__ __align__(16) u16 Bp[2][8][64][8];
  int t = threadIdx.x;
  int lane = t & 63, wave = t >> 6;
  int mh = wave >> 1, nh = wave & 1;
  int nt = blockIdx.x, mt = blockIdx.y, bz = blockIdx.z;
  int n0 = nt * 128;
  const u16* B1 = B1g + (i64)bz * b1s;
  const u16* B2 = B2g ? B2g + (i64)bz * b2s : nullptr;

  int sn = t & 127;   // n within tile
  int kh = t >> 7;    // 0/1

  f32x4 acc[4][4];
#pragma unroll
  for (int mi = 0; mi < 4; ++mi)
#pragma unroll
    for (int ni = 0; ni < 4; ++ni) acc[mi][ni] = (f32x4){0.f, 0.f, 0.f, 0.f};

  auto STAGE = [&](const u16* Bsrc, int K, int ks, int sb) {
    int kb = ks * 32;
#pragma unroll
    for (int g2 = 0; g2 < 2; ++g2) {
      int g = kh + g2 * 2;
      int kbase = kb + g * 8;
      union { u16 us[8]; uint4 q; } u;
#pragma unroll
      for (int j = 0; j < 8; ++j) {
        int k = kbase + j;
        u.us[j] = (k < K) ? Bsrc[(i64)k * HWN + n0 + sn] : (u16)0;
      }
      *(uint4*)(&Bp[sb][sn >> 4][g * 16 + (sn & 15)][0]) = u.q;
    }
  };

  int s = 0;
  STAGE(B1, K1, 0, 0);
  __syncthreads();

  for (int ks = 0; ks < KS1; ++ks) {
    if (ks + 1 < KS1) STAGE(B1, K1, ks + 1, s ^ 1);
    else if (Wp2) STAGE(B2, K2, 0, s ^ 1);
    bf16x8 a[4];
#pragma unroll
    for (int r = 0; r < 4; ++r) {
      int fm = mt * 8 + mh * 4 + r;
      a[r] = *reinterpret_cast<const bf16x8*>(Wp1 + ((i64)fm * KS1 + ks) * 512 + lane * 8);
    }
    bf16x8 bfr[4];
#pragma unroll
    for (int ni = 0; ni < 4; ++ni)
      bfr[ni] = *reinterpret_cast<const bf16x8*>(&Bp[s][nh * 4 + ni][lane][0]);
#pragma unroll
    for (int mi = 0; mi < 4; ++mi)
#pragma unroll
      for (int ni = 0; ni < 4; ++ni)
        acc[mi][ni] = __builtin_amdgcn_mfma_f32_16x16x32_bf16(a[mi], bfr[ni], acc[mi][ni], 0, 0, 0);
    __syncthreads();
    s ^= 1;
  }
  if (Wp2) {
    for (int ks = 0; ks < KS2; ++ks) {
      if (ks + 1 < KS2) STAGE(B2, K2, ks + 1, s ^ 1);
      bf16x8 a[4];
#pragma unroll
      for (int r = 0; r < 4; ++r) {
        int fm = mt * 8 + mh * 4 + r;
        a[r] = *reinterpret_cast<const bf16x8*>(Wp2 + ((i64)fm * KS2 + ks) * 512 + lane * 8);
      }
      bf16x8 bfr[4];
#pragma unroll
      for (int ni = 0; ni < 4; ++ni)
        bfr[ni] = *reinterpret_cast<const bf16x8*>(&Bp[s][nh * 4 + ni][lane][0]);
#pragma unroll
      for (int mi = 0; mi < 4; ++mi)
#pragma unroll
        for (int ni = 0; ni < 4; ++ni)
          acc[mi][ni] = __builtin_amdgcn_mfma_f32_16x16x32_bf16(a[mi], bfr[ni], acc[mi][ni], 0, 0, 0);
      __syncthreads();
      s ^= 1;
    }
  }

  float* Yf = (float*)Yv;
  u16* Yb = (u16*)Yv;
#pragma unroll
  for (int mi = 0; mi < 4; ++mi) {
#pragma unroll
    for (int ii = 0; ii < 4; ++ii) {
      int gm = mt * 128 + mh * 64 + mi * 16 + (lane >> 4) * 4 + ii;
      if (gm >= M) continue;
      float bv = bias[gm];
#pragma unroll
      for (int ni = 0; ni < 4; ++ni) {
        int gn = n0 + nh * 64 + ni * 16 + (lane & 15);
        float v = acc[mi][ni][ii] + bv;
        i64 off = (i64)bz * ybs + (i64)gm * HWN + gn;
        if (epi == 0) {
          Yb[off] = f2bf(v);
        } else if (epi == 1) {
          Yf[off] = v + R[(i64)bz * rbs + (i64)gm * HWN + gn];
        } else {
          float gg = 0.5f * v * (1.f + erff(v * 0.70710678118f));
          Yb[off] = f2bf(gg * v);
        }
      }
    }
  }
}

// ---------------- launch ----------------

extern "C" void kernel_launch(void* const* d_in, const int* in_sizes, int n_in,
                              void* d_out, int out_size, void* d_ws, size_t ws_size,
                              hipStream_t stream) {
  (void)in_sizes; (void)n_in; (void)out_size;
  const float* x       = (const float*)d_in[0];
  const float* spf     = (const float*)d_in[1];
  const float* ln1_w   = (const float*)d_in[2];
  const float* ln1_b   = (const float*)d_in[3];
  const float* qkv_w   = (const float*)d_in[4];
  const float* qkv_b   = (const float*)d_in[5];
  const float* qkvdw_w = (const float*)d_in[6];
  const float* qkvdw_b = (const float*)d_in[7];
  const float* proj_w  = (const float*)d_in[8];
  const float* proj_b  = (const float*)d_in[9];
  const float* temp    = (const float*)d_in[10];
  const float* a1      = (const float*)d_in[11];
  const float* a2      = (const float*)d_in[12];
  const float* a3      = (const float*)d_in[13];
  const float* a4      = (const float*)d_in[14];
  const float* wmix    = (const float*)d_in[15];
  const float* pout_w  = (const float*)d_in[16];
  const float* pout_b  = (const float*)d_in[17];
  const float* ln2_w   = (const float*)d_in[18];
  const float* ln2_b   = (const float*)d_in[19];
  const float* pin_w   = (const float*)d_in[20];
  const float* pin_b   = (const float*)d_in[21];
  const float* dw_w    = (const float*)d_in[22];
  const float* dw_b    = (const float*)d_in[23];
  const float* lin_w   = (const float*)d_in[24];
  const float* lin_b   = (const float*)d_in[25];
  const float* adj_w   = (const float*)d_in[26];
  const float* adj_b   = (const float*)d_in[27];
  const float* fout_w  = (const float*)d_in[28];
  const float* fout_b  = (const float*)d_in[29];
  float* out = (float*)d_out;
  float* ws = (float*)d_ws;

  const i64 PLANE = (i64)DIMC * HWN;        // 1,572,864
  const i64 FIXED = 5320448;
  const i64 PER = 9750528;
  int C = 8;
  while (C > 1 && (size_t)(FIXED + PER * C) * 4 > ws_size) C >>= 1;
  if ((size_t)(FIXED + PER * C) * 4 > ws_size) return;  // ws too small -> visible failure
  int nch = 8 / C;

  float* SPM   = ws;
  float* W2v   = SPM + PLANE;
  float* W3v   = W2v + 392064;
  float* b2v   = W3v + 392064;
  float* b3v   = b2v + 1024;
  float* spfn  = b3v + 1024;
  float* mu1   = spfn + 12288;
  float* rs1   = mu1 + 32768;
  float* mu2   = rs1 + 32768;
  float* rs2   = mu2 + 32768;
  float* packbase = rs2 + 32768;
  u16* qkv_wp  = (u16*)packbase;            // 884736 u16
  u16* pout_wp = qkv_wp + 884736;           // 294912
  u16* pin_wp  = pout_wp + 294912;          // 786432
  u16* adj1_wp = pin_wp + 786432;           // 2097152
  u16* W3_wp   = adj1_wp + 2097152;         // 786432
  u16* fout_wp = W3_wp + 786432;            // 786432
  float* dyn   = packbase + 2818048;
  float* attnP = dyn;                        // C*294912
  float* comb  = attnP + (i64)C * 294912;    // C*18432
  float* BufQ  = comb + (i64)C * 18432;      // C*4718592
  float* BufD  = BufQ + (i64)C * 4718592;    // C*4718592

  // ---- precompute: folded weights ----
  zero_kernel<<<dim3(3063), dim3(256), 0, stream>>>(W2v, 784128);
  matvec_kernel<<<dim3(1021), dim3(256), 0, stream>>>(lin_w, 1021, 0, pin_b + 1021, lin_b, b2v, 1021);
  gemm64_kernel<<<dim3(6, 16, 8), dim3(256), 0, stream>>>(
      lin_w, 1021, 0, 0, pin_w + (i64)1021 * 384, 0, 0, nullptr, W2v, 0, 0,
      1021, 384, 1021, 1, 8, 0);
  matvec_kernel<<<dim3(1021), dim3(256), 0, stream>>>(adj_w, 2042, 1021, b2v, adj_b, b3v, 1021);
  gemm64_kernel<<<dim3(6, 16, 8), dim3(256), 0, stream>>>(
      adj_w + 1021, 2042, 0, 0, W2v, 0, 0, nullptr, W3v, 0, 0,
      1021, 384, 1021, 1, 8, 0);

  // ---- pack weights to MFMA layout (bf16) ----
  pack_w_kernel<<<dim3(216), dim3(256), 0, stream>>>(qkv_w, 384, 0, 1152, 384, 12, qkv_wp, 72);
  pack_w_kernel<<<dim3(72), dim3(256), 0, stream>>>(pout_w, 384, 0, 384, 384, 12, pout_wp, 24);
  pack_w_kernel<<<dim3(192), dim3(256), 0, stream>>>(pin_w, 384, 0, 1021, 384, 12, pin_wp, 64);
  pack_w_kernel<<<dim3(512), dim3(256), 0, stream>>>(adj_w, 2042, 0, 1021, 1021, 32, adj1_wp, 64);
  pack_w_kernel<<<dim3(192), dim3(256), 0, stream>>>(W3v, 384, 0, 1021, 384, 12, W3_wp, 64);
  pack_w_kernel<<<dim3(192), dim3(256), 0, stream>>>(fout_w, 1021, 0, 384, 1021, 32, fout_wp, 24);

  // ---- shared precompute ----
  l2row_kernel<<<dim3(192), dim3(64), 0, stream>>>(spf, spfn);
  spm_kernel<<<dim3(6144), dim3(256), 0, stream>>>(spfn, proj_w, proj_b, SPM);
  stats_kernel<<<dim3(128), dim3(256), 0, stream>>>(x, mu1, rs1, 32768);

  for (int ch = 0; ch < nch; ++ch) {
    int b0 = ch * C;
    const float* xb = x + (i64)b0 * PLANE;
    float* outb = out + (i64)b0 * PLANE;
    const float* m1 = mu1 + (i64)b0 * HWN;
    const float* r1 = rs1 + (i64)b0 * HWN;
    float* m2 = mu2 + (i64)b0 * HWN;
    float* r2 = rs2 + (i64)b0 * HWN;

    u16* Xbf = (u16*)BufD;                                 // C*1572864 u16
    u16* qkv_bf = (u16*)BufQ;                              // C*4718592 u16
    float* DWo = BufD;                                     // C*4718592 f32 (overwrites Xbf)
    float* QS = BufQ;                                      // C*PLANE f32
    float* KR = BufQ + (i64)C * PLANE;                     // C*PLANE f32
    u16* AObf = (u16*)(BufQ + (i64)2 * C * PLANE);         // C*1572864 u16
    u16* xn2 = (u16*)BufD;                                 // C*1572864 u16
    u16* x1 = (u16*)BufQ;                                  // C*4182016 u16
    u16* x1d = (u16*)BufD + (i64)C * 1572864;              // C*4182016 u16
    u16* fbf = (u16*)BufQ;                                 // C*4182016 u16

    // ---- attention ----
    ln_bf16_kernel<<<dim3(C * 6144), dim3(256), 0, stream>>>(xb, m1, r1, ln1_w, ln1_b, Xbf,
                                                             (i64)C * PLANE);
    gemm_mfma_kernel<<<dim3(32, 9, C), dim3(256), 0, stream>>>(
        qkv_wp, 12, 384, Xbf, PLANE, nullptr, 0, 0, nullptr, 0,
        qkv_b, nullptr, 0, qkv_bf, (i64)DIM3 * HWN, 1152, 0);
    dw3x3_kernel<u16, float><<<dim3(C * 18432), dim3(256), 0, stream>>>(qkv_bf, qkvdw_w, qkvdw_b,
                                                                        DWo, 1152);
    qknorm_kernel<true><<<dim3(C * 384), dim3(256), 0, stream>>>(DWo, 0, SPM, QS);
    qknorm_kernel<false><<<dim3(C * 384), dim3(256), 0, stream>>>(DWo, 384, nullptr, KR);
    attnS_kernel<<<dim3(16, C * 8), dim3(256), 0, stream>>>(QS, KR, attnP);
    blend_kernel<<<dim3(96 * C), dim3(256), 0, stream>>>(attnP, temp, wmix, a1, a2, a3, a4, comb);
    gemm64_kernel<<<dim3(64, 1, C * 8), dim3(256), 0, stream>>>(
        comb, 48, (i64)8 * 2304, 2304,
        DWo + (i64)768 * HWN, (i64)DIM3 * HWN, (i64)HC * HWN,
        nullptr, AObf, PLANE, (i64)HC * HWN,
        48, 4096, 48, 8, 1, 1);
    gemm_mfma_kernel<<<dim3(32, 3, C), dim3(256), 0, stream>>>(
        pout_wp, 12, 384, AObf, PLANE, nullptr, 0, 0, nullptr, 0,
        pout_b, xb, PLANE, outb, PLANE, 384, 1);

    // ---- feed-forward ----
    stats_kernel<<<dim3(C * 16), dim3(256), 0, stream>>>(outb, m2, r2, C * 4096);
    ln_bf16_kernel<<<dim3(C * 6144), dim3(256), 0, stream>>>(outb, m2, r2, ln2_w, ln2_b, xn2,
                                                             (i64)C * PLANE);
    gemm_mfma_kernel<<<dim3(32, 8, C), dim3(256), 0, stream>>>(
        pin_wp, 12, 384, xn2, PLANE, nullptr, 0, 0, nullptr, 0,
        pin_b, nullptr, 0, x1, (i64)1021 * HWN, 1021, 0);
    dw3x3_kernel<u16, u16><<<dim3(C * 16336), dim3(256), 0, stream>>>(x1, dw_w, dw_b, x1d, 1021);
    gemm_mfma_kernel<<<dim3(32, 8, C), dim3(256), 0, stream>>>(
        adj1_wp, 32, 1021, x1d, (i64)1021 * HWN, W3_wp, 12, 384, xn2, PLANE,
        b3v, nullptr, 0, fbf, (i64)1021 * HWN, 1021, 2);
    gemm_mfma_kernel<<<dim3(32, 3, C), dim3(256), 0, stream>>>(
        fout_wp, 32, 1021, fbf, (i64)1021 * HWN, nullptr, 0, 0, nullptr, 0,
        fout_b, outb, PLANE, outb, PLANE, 384, 1);
  }
}

// Round 5
// 1414.371 us; speedup vs baseline: 3.5733x; 1.2588x over previous
//
#include <hip/hip_runtime.h>
#include <math.h>

typedef long long i64;
typedef unsigned short u16;
typedef unsigned int u32;

#define DIMC 384
#define DIM3 1152
#define HC 48
#define HWN 4096

using bf16x8 = __attribute__((ext_vector_type(8))) short;
using f32x4 = __attribute__((ext_vector_type(4))) float;

__device__ __forceinline__ float bf2f(u16 u) { u32 x = ((u32)u) << 16; return __uint_as_float(x); }
__device__ __forceinline__ u16 f2bf(float f) {
  u32 u = __float_as_uint(f);
  u32 r = u + 0x7FFFu + ((u >> 16) & 1u);
  return (u16)(r >> 16);
}
__device__ __forceinline__ void st_out(float* p, float v) { *p = v; }
__device__ __forceinline__ void st_out(u16* p, float v) { *p = f2bf(v); }

__device__ __forceinline__ void gld_lds16(const u16* g, u16* l) {
  __builtin_amdgcn_global_load_lds(
      (const __attribute__((address_space(1))) void*)g,
      (__attribute__((address_space(3))) void*)l, 16, 0, 0);
}

// ---------------- utility kernels ----------------

__global__ void zero_kernel(float* __restrict__ p, int n) {
  int i = blockIdx.x * 256 + threadIdx.x;
  if (i < n) p[i] = 0.f;
}

// per-pixel LayerNorm stats over C=384 channels (input NCHW fp32)
__global__ void stats_kernel(const float* __restrict__ x, float* __restrict__ mu,
                             float* __restrict__ rs, int npix) {
  int idx = blockIdx.x * 256 + threadIdx.x;
  if (idx >= npix) return;
  int b = idx >> 12, p = idx & 4095;
  const float* xp = x + ((i64)b * DIMC) * HWN + p;
  float s = 0.f, ss = 0.f;
  for (int c = 0; c < DIMC; ++c) { float v = xp[(i64)c * HWN]; s += v; ss += v * v; }
  float m = s * (1.f / DIMC);
  float var = ss * (1.f / DIMC) - m * m;
  mu[idx] = m;
  rs[idx] = rsqrtf(var + 1e-5f);
}

// LN apply + transpose NCHW fp32 -> [n][384] bf16 (64x64 LDS tile)
__global__ __launch_bounds__(256) void ln_t_kernel(
    const float* __restrict__ x, const float* __restrict__ mu, const float* __restrict__ rs,
    const float* __restrict__ g, const float* __restrict__ bb, u16* __restrict__ y) {
  __shared__ u16 tile[64][66];
  int p0 = blockIdx.x * 64, c0 = blockIdx.y * 64, b = blockIdx.z;
  int t = threadIdx.x;
  int tp = t & 63, tq = t >> 6;
  float m = mu[b * 4096 + p0 + tp], r = rs[b * 4096 + p0 + tp];
  const float* xp = x + (i64)b * DIMC * HWN + (i64)c0 * 4096 + p0;
#pragma unroll
  for (int i = 0; i < 16; ++i) {
    int c = tq + i * 4;
    float v = xp[(i64)c * 4096 + tp];
    tile[c][tp] = f2bf((v - m) * r * g[c0 + c] + bb[c0 + c]);
  }
  __syncthreads();
#pragma unroll
  for (int i = 0; i < 16; ++i) {
    int p = tq + i * 4;
    y[((i64)b * 4096 + p0 + p) * 384 + c0 + tp] = tile[tp][p];
  }
}

// depthwise 3x3 pad1 in [n][c] layout; 4 px per block, threads along c.
template <typename TO>
__global__ __launch_bounds__(256) void dw_nc_kernel(const u16* __restrict__ in, int ldin,
                                                    const float* __restrict__ w,
                                                    const float* __restrict__ bias,
                                                    TO* __restrict__ out, int ldo, int CH) {
  int c = blockIdx.y * 256 + threadIdx.x;
  if (c >= ldo) return;
  i64 p0 = (i64)blockIdx.x * 4;
  i64 pb = p0 & ~4095LL;
  int sp = (int)(p0 & 4095);
  int y = sp >> 6, x0 = sp & 63;
  bool valid = (c < CH);
  float wv[9];
#pragma unroll
  for (int i = 0; i < 9; ++i) wv[i] = valid ? w[c * 9 + i] : 0.f;
  float bv = valid ? bias[c] : 0.f;
  float vin[3][6];
#pragma unroll
  for (int dy = 0; dy < 3; ++dy) {
    int yy = y - 1 + dy;
#pragma unroll
    for (int dx = 0; dx < 6; ++dx) {
      int xx = x0 - 1 + dx;
      float v = 0.f;
      if (valid && (unsigned)yy < 64u && (unsigned)xx < 64u)
        v = bf2f(in[(pb + yy * 64 + xx) * ldin + c]);
      vin[dy][dx] = v;
    }
  }
#pragma unroll
  for (int i = 0; i < 4; ++i) {
    float acc = bv;
#pragma unroll
    for (int dy = 0; dy < 3; ++dy)
#pragma unroll
      for (int dx = 0; dx < 3; ++dx) acc += vin[dy][i + dx] * wv[dy * 3 + dx];
    st_out(&out[(p0 + i) * ldo + c], valid ? acc : 0.f);
  }
}

// l2-normalize rows of 64
__global__ void l2row_kernel(const float* __restrict__ in, float* __restrict__ out) {
  int r = blockIdx.x;
  int lane = threadIdx.x;
  float v = in[r * 64 + lane];
  float ss = v * v;
  for (int o = 32; o > 0; o >>= 1) ss += __shfl_xor(ss, o);
  float n = fmaxf(sqrtf(ss), 1e-12f);
  out[r * 64 + lane] = v / n;
}

// conv 3x3, 3 -> 384 channels, output [p][384]
__global__ void spm_kernel(const float* __restrict__ s, const float* __restrict__ w,
                           const float* __restrict__ bias, float* __restrict__ out) {
  int idx = blockIdx.x * 256 + threadIdx.x;  // 4096*384
  int c = idx % 384, p = idx / 384;
  int xc = p & 63, yr = p >> 6;
  const float* wp = w + c * 27;
  float acc = bias[c];
  for (int ic = 0; ic < 3; ++ic)
    for (int dy = -1; dy <= 1; ++dy) {
      int yy = yr + dy; if ((unsigned)yy >= 64u) continue;
      for (int dx = -1; dx <= 1; ++dx) {
        int xx = xc + dx; if ((unsigned)xx >= 64u) continue;
        acc += s[ic * 4096 + yy * 64 + xx] * wp[ic * 9 + (dy + 1) * 3 + (dx + 1)];
      }
    }
  out[idx] = acc;
}

// Q: W-axis l2n + spm mult -> QS fp32 [n][384]; plane ssq partials for q and k (atomics).
__global__ __launch_bounds__(384) void qknorm2_kernel(
    const float* __restrict__ dwo, const float* __restrict__ spm,
    float* __restrict__ QS, float* __restrict__ qssq, float* __restrict__ kssq) {
  int y = blockIdx.x;
  int b = blockIdx.y;
  int c = threadIdx.x;
  i64 base = ((i64)b * 4096 + y * 64) * 1152;
  float ks = 0.f;
  for (int x = 0; x < 64; ++x) {
    float v = dwo[base + (i64)x * 1152 + 384 + c];
    ks += v * v;
  }
  atomicAdd(&kssq[b * 384 + c], ks);
  float qs = 0.f;
  for (int x = 0; x < 64; ++x) {
    float v = dwo[base + (i64)x * 1152 + c];
    qs += v * v;
  }
  float rw = 1.f / fmaxf(sqrtf(qs), 1e-12f);
  float ps = 0.f;
  for (int x = 0; x < 64; ++x) {
    float v = dwo[base + (i64)x * 1152 + c] * rw * spm[(y * 64 + x) * 384 + c];
    QS[((i64)b * 4096 + y * 64 + x) * 384 + c] = v;
    ps += v * v;
  }
  atomicAdd(&qssq[b * 384 + c], ps);
}

// attn partials: attnP[bh][ksp][48][48] = sum_n QS[n][qc] * K[n][kc]  ([n][c] inputs)
__global__ __launch_bounds__(256) void attnS_kernel(const float* __restrict__ QS,
                                                    const float* __restrict__ dwo,
                                                    float* __restrict__ attnP) {
  int ksp = blockIdx.x;
  int bh = blockIdx.y;
  int b = bh >> 3, h = bh & 7;
  __shared__ float qsm[64][49];
  __shared__ float ksm[64][49];
  int t = threadIdx.x, tc = t & 15, td = t >> 4;
  float acc[3][3] = {{0.f}};
  for (int sub = 0; sub < 4; ++sub) {
    i64 nb = (i64)b * 4096 + ksp * 256 + sub * 64;
    __syncthreads();
    for (int l = t; l < 4096; l += 256) {
      int row = l >> 6, cq = l & 63;
      if (cq < 48) {
        qsm[row][cq] = QS[(nb + row) * 384 + h * 48 + cq];
        ksm[row][cq] = dwo[(nb + row) * 1152 + 384 + h * 48 + cq];
      }
    }
    __syncthreads();
#pragma unroll 4
    for (int nn = 0; nn < 64; ++nn) {
      float a0 = qsm[nn][tc], a1 = qsm[nn][tc + 16], a2 = qsm[nn][tc + 32];
      float b0 = ksm[nn][td], b1 = ksm[nn][td + 16], b2 = ksm[nn][td + 32];
      acc[0][0] += a0 * b0; acc[0][1] += a0 * b1; acc[0][2] += a0 * b2;
      acc[1][0] += a1 * b0; acc[1][1] += a1 * b1; acc[1][2] += a1 * b2;
      acc[2][0] += a2 * b0; acc[2][1] += a2 * b1; acc[2][2] += a2 * b2;
    }
  }
  float* ap = attnP + ((i64)bh * 16 + ksp) * 2304;
#pragma unroll
  for (int i = 0; i < 3; ++i)
#pragma unroll
    for (int j = 0; j < 3; ++j)
      ap[(tc + 16 * i) * HC + (td + 16 * j)] = acc[i][j];
}

// blend: fold plane-l2n of q (row) and k (col) + temperature, relu/top-k softmax mix
__global__ void blend_kernel(const float* __restrict__ attnP, const float* __restrict__ qssq,
                             const float* __restrict__ kssq, const float* __restrict__ temp,
                             const float* __restrict__ wmix, const float* __restrict__ pa1,
                             const float* __restrict__ pa2, const float* __restrict__ pa3,
                             const float* __restrict__ pa4, float* __restrict__ comb) {
  int row = blockIdx.x * 4 + (threadIdx.x >> 6);
  int lane = threadIdx.x & 63;
  int bh = row / 48, cc = row - bh * 48;
  int b = bh >> 3, h = bh & 7;
  float a;
  if (lane < 48) {
    const float* pp = attnP + ((i64)bh * 16) * 2304 + cc * 48 + lane;
    float s = 0.f;
#pragma unroll
    for (int sp = 0; sp < 16; ++sp) s += pp[(i64)sp * 2304];
    float qn = 1.f / fmaxf(sqrtf(qssq[b * 384 + h * 48 + cc]), 1e-12f);
    float kn = 1.f / fmaxf(sqrtf(kssq[b * 384 + h * 48 + lane]), 1e-12f);
    a = s * qn * kn * temp[h];
  } else {
    a = -INFINITY;
  }
  int rank = 0;
  for (int j = 0; j < 48; ++j) {
    float aj = __shfl(a, j);
    rank += (aj > a) ? 1 : 0;
  }
  float w0 = wmix[0], w1 = wmix[1];
  float wm = fmaxf(w0, w1);
  float e0 = expf(w0 - wm), e1 = expf(w1 - wm);
  float ws0 = e0 / (e0 + e1), ws1 = e1 / (e0 + e1);
  float c1 = pa1[0], c2 = pa2[0], c3 = pa3[0], c4 = pa4[0];
  float outv = ws0 * (c1 + c2 + c3 + c4) * fmaxf(a, 0.f);
  const int kks[4] = {24, 32, 36, 38};
  const float cs[4] = {c1, c2, c3, c4};
#pragma unroll
  for (int q = 0; q < 4; ++q) {
    float mv = (lane < 48) ? ((rank < kks[q]) ? a : a * 1e-6f) : -INFINITY;
    float mx = mv;
    for (int o = 32; o > 0; o >>= 1) mx = fmaxf(mx, __shfl_xor(mx, o));
    float e = (lane < 48) ? expf(mv - mx) : 0.f;
    float s = e;
    for (int o = 32; o > 0; o >>= 1) s += __shfl_xor(s, o);
    outv += ws1 * cs[q] * (e / s);
  }
  if (lane < 48) comb[(i64)row * 48 + lane] = outv;
}

// attn_out[n][c] = sum_d comb[b,h,cc,d] * V[n][768+h*48+d]  (V from dwo fp32) -> bf16
__global__ __launch_bounds__(384) void combv_kernel(const float* __restrict__ dwo,
                                                    const float* __restrict__ comb,
                                                    u16* __restrict__ AO) {
  __shared__ float Vs[4][8][49];
  i64 p0 = (i64)blockIdx.x * 4;
  int b = (int)(p0 >> 12);
  int t = threadIdx.x;
  int h = t / 48, cc = t - h * 48;
#pragma unroll
  for (int px = 0; px < 4; ++px)
    Vs[px][h][cc] = dwo[(p0 + px) * 1152 + 768 + t];
  __syncthreads();
  float cr[48];
  const float* cp = comb + ((i64)(b * 8 + h) * 48 + cc) * 48;
#pragma unroll
  for (int d = 0; d < 48; d += 4) {
    float4 v = *(const float4*)(cp + d);
    cr[d] = v.x; cr[d + 1] = v.y; cr[d + 2] = v.z; cr[d + 3] = v.w;
  }
#pragma unroll
  for (int px = 0; px < 4; ++px) {
    float s = 0.f;
#pragma unroll
    for (int d = 0; d < 48; ++d) s += cr[d] * Vs[px][h][d];
    AO[(p0 + px) * 384 + t] = f2bf(s);
  }
}

// mat-vec (precompute)
__global__ void matvec_kernel(const float* __restrict__ Wm, int ldw, int koff,
                              const float* __restrict__ v, const float* __restrict__ add,
                              float* __restrict__ out, int K) {
  int ro = blockIdx.x;
  int t = threadIdx.x;
  const float* wp = Wm + (i64)ro * ldw + koff;
  float s = 0.f;
  for (int k = t; k < K; k += 256) s += wp[k] * v[k];
  __shared__ float sred[256];
  sred[t] = s;
  __syncthreads();
  for (int o = 128; o > 0; o >>= 1) {
    if (t < o) sred[t] += sred[t + o];
    __syncthreads();
  }
  if (t == 0) out[ro] = sred[0] + (add ? add[ro] : 0.f);
}

// 64x64 fp32 GEMM (weight-fold precompute only), split-K atomics
__global__ __launch_bounds__(256) void gemm64_kernel(
    const float* __restrict__ W, int ldw,
    const float* __restrict__ X,
    float* __restrict__ Y,
    int M, int N, int K, int ksplit) {
  int nt = blockIdx.x, mt = blockIdx.y;
  int ks = blockIdx.z;
  int kchunk = (((K + ksplit - 1) / ksplit) + 15) & ~15;
  int kbeg = ks * kchunk;
  int kend = min(K, kbeg + kchunk);
  __shared__ float As[16][68];
  __shared__ float Bs[16][68];
  int t = threadIdx.x, tx = t & 15, ty = t >> 4;
  int m0 = mt * 64, n0 = nt * 64;
  float acc[4][4];
#pragma unroll
  for (int i = 0; i < 4; ++i)
#pragma unroll
    for (int j = 0; j < 4; ++j) acc[i][j] = 0.f;
  for (int k0 = kbeg; k0 < kend; k0 += 16) {
    int kk = t & 15;
#pragma unroll
    for (int r = 0; r < 4; ++r) {
      int mm = (t >> 4) + r * 16;
      int gm = m0 + mm, gk = k0 + kk;
      As[kk][mm] = (gm < M && gk < kend) ? W[(i64)gm * ldw + gk] : 0.f;
    }
    int nn = t & 63;
#pragma unroll
    for (int r = 0; r < 4; ++r) {
      int k2 = (t >> 6) + r * 4;
      int gk = k0 + k2;
      Bs[k2][nn] = (gk < kend && n0 + nn < N) ? X[(i64)gk * N + n0 + nn] : 0.f;
    }
    __syncthreads();
#pragma unroll
    for (int kk3 = 0; kk3 < 16; ++kk3) {
      float4 av = *(const float4*)&As[kk3][ty * 4];
      float4 bv = *(const float4*)&Bs[kk3][tx * 4];
      float aa[4] = {av.x, av.y, av.z, av.w};
      float bb2[4] = {bv.x, bv.y, bv.z, bv.w};
#pragma unroll
      for (int i = 0; i < 4; ++i)
#pragma unroll
        for (int j = 0; j < 4; ++j) acc[i][j] += aa[i] * bb2[j];
    }
    __syncthreads();
  }
#pragma unroll
  for (int i = 0; i < 4; ++i) {
    int gm = m0 + ty * 4 + i;
    if (gm >= M || n0 + tx * 4 >= N) continue;
    for (int j = 0; j < 4; ++j) atomicAdd(&Y[(i64)gm * N + n0 + tx * 4 + j], acc[i][j]);
  }
}

// pack fp32 weight [M][ldw] (cols koff..koff+K) into MFMA B-fragment order
__global__ void pack_w_kernel(const float* __restrict__ W, int ldw, int koff, int M, int K,
                              int KS, u16* __restrict__ out, int nfrag) {
  int tid = blockIdx.x * 256 + threadIdx.x;
  int lane = tid & 63;
  int idx = tid >> 6;
  if (idx >= nfrag * KS) return;
  int ks = idx % KS, fm = idx / KS;
  int row = fm * 16 + (lane & 15);
  int kb = ks * 32 + (lane >> 4) * 8;
  union { u16 us[8]; uint4 q; } u;
#pragma unroll
  for (int j = 0; j < 8; ++j) {
    int k = kb + j;
    u.us[j] = (row < M && k < K) ? f2bf(W[(i64)row * ldw + koff + k]) : (u16)0;
  }
  *(uint4*)(out + (i64)idx * 512 + lane * 8) = u.q;
}

// ---------------- MFMA GEMM, activations [n][k] as A-operand ----------------
// Y[n][m] = sum_k A1[n][k] W1[m][k] (+ A2/W2 K-concat) + bias[m]; epilogues:
// epi 0: -> bf16 Yh[n][ldo]; epi 2: gelu(v)*v -> bf16 Yh[n][ldo];
// epi 1: + Res([b][c][p] fp32) -> fp32 Yf[b][c][p] (M=384)
__global__ __launch_bounds__(256) void gemm_nk_kernel(
    const u16* __restrict__ A1, int lda1, int KS1, const u16* __restrict__ Wp1,
    const u16* __restrict__ A2, int lda2, int KS2, const u16* __restrict__ Wp2,
    int nfrag, const float* __restrict__ bias,
    const float* __restrict__ Res, float* __restrict__ Yf, u16* __restrict__ Yh,
    int ldo, int M, int epi) {
  __shared__ __align__(16) u16 As[2][4096];  // [frag 0..7][lane][8]
  int t = threadIdx.x, lane = t & 63, w = t >> 6;
  i64 n0 = (i64)blockIdx.x * 128;
  int mt = blockIdx.y;

  f32x4 acc[8][4];
#pragma unroll
  for (int f = 0; f < 8; ++f)
#pragma unroll
    for (int r = 0; r < 4; ++r) acc[f][r] = (f32x4){0.f, 0.f, 0.f, 0.f};

#define STAGE_K(Aptr, lda, ks, buf)                                                   \
  {                                                                                   \
    _Pragma("unroll") for (int j = 0; j < 2; ++j) {                                   \
      int f = w * 2 + j;                                                              \
      const u16* src =                                                                \
          (Aptr) + (n0 + f * 16 + (lane & 15)) * (i64)(lda) + (ks) * 32 + (lane >> 4) * 8; \
      gld_lds16(src, &As[buf][f * 512]);                                              \
    }                                                                                 \
  }

  int KT = KS1 + KS2;
  int s = 0;
  STAGE_K(A1, lda1, 0, 0);
  __syncthreads();

  for (int kt = 0; kt < KT; ++kt) {
    if (kt + 1 < KS1) {
      STAGE_K(A1, lda1, kt + 1, s ^ 1);
    } else if (kt + 1 < KT) {
      STAGE_K(A2, lda2, kt + 1 - KS1, s ^ 1);
    }
    const u16* Wp = (kt < KS1) ? Wp1 : Wp2;
    int ks = (kt < KS1) ? kt : kt - KS1;
    int KSc = (kt < KS1) ? KS1 : KS2;
    bf16x8 bfr[4];
#pragma unroll
    for (int r = 0; r < 4; ++r) {
      int fm = mt * 16 + w * 4 + r;
      int fmc = min(fm, nfrag - 1);
      bfr[r] = *reinterpret_cast<const bf16x8*>(Wp + ((i64)fmc * KSc + ks) * 512 + lane * 8);
    }
#pragma unroll
    for (int f = 0; f < 8; ++f) {
      bf16x8 a = *reinterpret_cast<const bf16x8*>(&As[s][f * 512 + lane * 8]);
#pragma unroll
      for (int r = 0; r < 4; ++r)
        acc[f][r] = __builtin_amdgcn_mfma_f32_16x16x32_bf16(a, bfr[r], acc[f][r], 0, 0, 0);
    }
    __syncthreads();
    s ^= 1;
  }

#pragma unroll
  for (int f = 0; f < 8; ++f) {
    int nbase = (int)n0 + f * 16 + ((lane >> 4) << 2);
#pragma unroll
    for (int r = 0; r < 4; ++r) {
      int m = mt * 256 + w * 64 + r * 16 + (lane & 15);
      if (epi == 1) {
        if (m < M) {
          float bv = bias[m];
          int b = nbase >> 12, p = nbase & 4095;
          i64 off = ((i64)b * DIMC + m) * 4096 + p;
          float4 rv = *(const float4*)(Res + off);
          float4 o;
          o.x = acc[f][r][0] + bv + rv.x;
          o.y = acc[f][r][1] + bv + rv.y;
          o.z = acc[f][r][2] + bv + rv.z;
          o.w = acc[f][r][3] + bv + rv.w;
          *(float4*)(Yf + off) = o;
        }
      } else {
        if (m < ldo) {
          float bv = (m < M) ? bias[m] : 0.f;
#pragma unroll
          for (int ii = 0; ii < 4; ++ii) {
            float v = acc[f][r][ii] + bv;
            if (epi == 2) {
              float gg = 0.5f * v * (1.f + erff(v * 0.70710678118f));
              v = gg * v;
            }
            if (m >= M) v = 0.f;
            Yh[(i64)(nbase + ii) * ldo + m] = f2bf(v);
          }
        }
      }
    }
  }
#undef STAGE_K
}

// ---------------- launch ----------------

extern "C" void kernel_launch(void* const* d_in, const int* in_sizes, int n_in,
                              void* d_out, int out_size, void* d_ws, size_t ws_size,
                              hipStream_t stream) {
  (void)in_sizes; (void)n_in; (void)out_size;
  const float* x       = (const float*)d_in[0];
  const float* spf     = (const float*)d_in[1];
  const float* ln1_w   = (const float*)d_in[2];
  const float* ln1_b   = (const float*)d_in[3];
  const float* qkv_w   = (const float*)d_in[4];
  const float* qkv_b   = (const float*)d_in[5];
  const float* qkvdw_w = (const float*)d_in[6];
  const float* qkvdw_b = (const float*)d_in[7];
  const float* proj_w  = (const float*)d_in[8];
  const float* proj_b  = (const float*)d_in[9];
  const float* temp    = (const float*)d_in[10];
  const float* a1      = (const float*)d_in[11];
  const float* a2      = (const float*)d_in[12];
  const float* a3      = (const float*)d_in[13];
  const float* a4      = (const float*)d_in[14];
  const float* wmix    = (const float*)d_in[15];
  const float* pout_w  = (const float*)d_in[16];
  const float* pout_b  = (const float*)d_in[17];
  const float* ln2_w   = (const float*)d_in[18];
  const float* ln2_b   = (const float*)d_in[19];
  const float* pin_w   = (const float*)d_in[20];
  const float* pin_b   = (const float*)d_in[21];
  const float* dw_w    = (const float*)d_in[22];
  const float* dw_b    = (const float*)d_in[23];
  const float* lin_w   = (const float*)d_in[24];
  const float* lin_b   = (const float*)d_in[25];
  const float* adj_w   = (const float*)d_in[26];
  const float* adj_b   = (const float*)d_in[27];
  const float* fout_w  = (const float*)d_in[28];
  const float* fout_b  = (const float*)d_in[29];
  float* out = (float*)d_out;
  float* ws = (float*)d_ws;

  const i64 PLANE = (i64)DIMC * HWN;  // 1,572,864
  const i64 FIXED = 5326592;
  const i64 PER = 9750528;
  int C = 8;
  while (C > 1 && (size_t)(FIXED + PER * C) * 4 > ws_size) C >>= 1;
  if ((size_t)(FIXED + PER * C) * 4 > ws_size) return;  // ws too small -> visible failure
  int nch = 8 / C;

  float* SPM   = ws;                          // [p][384] fp32
  float* W2v   = SPM + 1572864;
  float* W3v   = W2v + 392064;
  float* b2v   = W3v + 392064;
  float* b3v   = b2v + 1024;
  float* spfn  = b3v + 1024;
  float* mu1   = spfn + 12288;
  float* rs1   = mu1 + 32768;
  float* mu2   = rs1 + 32768;
  float* rs2   = mu2 + 32768;
  float* qssq  = rs2 + 32768;                 // C*384 (alloc 3072)
  float* kssq  = qssq + 3072;                 // C*384 (alloc 3072)
  float* packbase = kssq + 3072;
  u16* qkv_wp  = (u16*)packbase;              // 884736 u16
  u16* pout_wp = qkv_wp + 884736;             // 294912
  u16* pin_wp  = pout_wp + 294912;            // 786432
  u16* adj1_wp = pin_wp + 786432;             // 2097152
  u16* W3_wp   = adj1_wp + 2097152;           // 786432
  u16* fout_wp = W3_wp + 786432;              // 786432
  float* dyn   = packbase + 2818048;
  float* attnP = dyn;                         // C*294912
  float* comb  = attnP + (i64)C * 294912;     // C*18432
  float* arena4 = comb + (i64)C * 18432;      // C*786432 f32 (Xbf / AO / xn2: [n][384] bf16)
  float* arena3 = arena4 + (i64)C * 786432;   // C*1572864 f32 (x_attn [b][c][p] fp32)
  float* arena2 = arena3 + (i64)C * 1572864;  // C*2359296 f32 (qkv_bf / QS / fbf)
  float* arena1 = arena2 + (i64)C * 2359296;  // C*4718592 f32 (DWo / x1+x1d)

  // ---- precompute: folded weights W2 = lin@pin2, W3 = adj2@W2 ----
  zero_kernel<<<dim3(3063), dim3(256), 0, stream>>>(W2v, 784128);
  matvec_kernel<<<dim3(1021), dim3(256), 0, stream>>>(lin_w, 1021, 0, pin_b + 1021, lin_b, b2v, 1021);
  gemm64_kernel<<<dim3(6, 16, 8), dim3(256), 0, stream>>>(
      lin_w, 1021, pin_w + (i64)1021 * 384, W2v, 1021, 384, 1021, 8);
  matvec_kernel<<<dim3(1021), dim3(256), 0, stream>>>(adj_w, 2042, 1021, b2v, adj_b, b3v, 1021);
  gemm64_kernel<<<dim3(6, 16, 8), dim3(256), 0, stream>>>(
      adj_w + 1021, 2042, W2v, W3v, 1021, 384, 1021, 8);

  // ---- pack weights to MFMA fragment layout (bf16) ----
  pack_w_kernel<<<dim3(216), dim3(256), 0, stream>>>(qkv_w, 384, 0, 1152, 384, 12, qkv_wp, 72);
  pack_w_kernel<<<dim3(72), dim3(256), 0, stream>>>(pout_w, 384, 0, 384, 384, 12, pout_wp, 24);
  pack_w_kernel<<<dim3(192), dim3(256), 0, stream>>>(pin_w, 384, 0, 1021, 384, 12, pin_wp, 64);
  pack_w_kernel<<<dim3(512), dim3(256), 0, stream>>>(adj_w, 2042, 0, 1021, 1021, 32, adj1_wp, 64);
  pack_w_kernel<<<dim3(192), dim3(256), 0, stream>>>(W3v, 384, 0, 1021, 384, 12, W3_wp, 64);
  pack_w_kernel<<<dim3(192), dim3(256), 0, stream>>>(fout_w, 1021, 0, 384, 1021, 32, fout_wp, 24);

  // ---- shared precompute ----
  l2row_kernel<<<dim3(192), dim3(64), 0, stream>>>(spf, spfn);
  spm_kernel<<<dim3(6144), dim3(256), 0, stream>>>(spfn, proj_w, proj_b, SPM);
  stats_kernel<<<dim3(128), dim3(256), 0, stream>>>(x, mu1, rs1, 32768);

  for (int ch = 0; ch < nch; ++ch) {
    int b0 = ch * C;
    const float* xb = x + (i64)b0 * PLANE;
    float* outb = out + (i64)b0 * PLANE;
    const float* m1 = mu1 + (i64)b0 * HWN;
    const float* r1 = rs1 + (i64)b0 * HWN;

    u16* Xbf    = (u16*)arena4;               // [n][384] bf16
    u16* qkv_bf = (u16*)arena2;               // [n][1152] bf16
    float* DWo  = arena1;                     // [n][1152] fp32
    float* QS   = arena2;                     // [n][384] fp32 (qkv_bf dead)
    u16* AO     = (u16*)arena4;               // [n][384] bf16 (Xbf dead)
    float* xatt = arena3;                     // [b][c][p] fp32
    u16* xn2    = (u16*)arena4;               // [n][384] bf16 (AO dead)
    u16* x1     = (u16*)arena1;               // [n][1024] bf16 (DWo dead)
    u16* x1d    = (u16*)(arena1 + (i64)C * 2097152);  // [n][1024] bf16
    u16* fbf    = (u16*)arena2;               // [n][1024] bf16 (QS dead)

    int NB = C * 32;  // n-tiles of 128: C*4096/128

    // ---- attention ----
    zero_kernel<<<dim3((2 * C * 384 + 255) / 256), dim3(256), 0, stream>>>(qssq, 2 * C * 384);
    ln_t_kernel<<<dim3(64, 6, C), dim3(256), 0, stream>>>(xb, m1, r1, ln1_w, ln1_b, Xbf);
    gemm_nk_kernel<<<dim3(NB, 5), dim3(256), 0, stream>>>(
        Xbf, 384, 12, qkv_wp, nullptr, 0, 0, nullptr, 72,
        qkv_b, nullptr, nullptr, qkv_bf, 1152, 1152, 0);
    dw_nc_kernel<float><<<dim3(C * 1024, 5), dim3(256), 0, stream>>>(
        qkv_bf, 1152, qkvdw_w, qkvdw_b, DWo, 1152, 1152);
    qknorm2_kernel<<<dim3(64, C), dim3(384), 0, stream>>>(DWo, SPM, QS, qssq, kssq);
    attnS_kernel<<<dim3(16, C * 8), dim3(256), 0, stream>>>(QS, DWo, attnP);
    blend_kernel<<<dim3(96 * C), dim3(256), 0, stream>>>(attnP, qssq, kssq, temp, wmix,
                                                         a1, a2, a3, a4, comb);
    combv_kernel<<<dim3(C * 1024), dim3(384), 0, stream>>>(DWo, comb, AO);
    gemm_nk_kernel<<<dim3(NB, 2), dim3(256), 0, stream>>>(
        AO, 384, 12, pout_wp, nullptr, 0, 0, nullptr, 24,
        pout_b, xb, xatt, nullptr, 0, 384, 1);

    // ---- feed-forward ----
    stats_kernel<<<dim3(C * 16), dim3(256), 0, stream>>>(xatt, mu2, rs2, C * 4096);
    ln_t_kernel<<<dim3(64, 6, C), dim3(256), 0, stream>>>(xatt, mu2, rs2, ln2_w, ln2_b, xn2);
    gemm_nk_kernel<<<dim3(NB, 4), dim3(256), 0, stream>>>(
        xn2, 384, 12, pin_wp, nullptr, 0, 0, nullptr, 64,
        pin_b, nullptr, nullptr, x1, 1024, 1021, 0);
    dw_nc_kernel<u16><<<dim3(C * 1024, 4), dim3(256), 0, stream>>>(
        x1, 1024, dw_w, dw_b, x1d, 1024, 1021);
    gemm_nk_kernel<<<dim3(NB, 4), dim3(256), 0, stream>>>(
        x1d, 1024, 32, adj1_wp, xn2, 384, 12, W3_wp, 64,
        b3v, nullptr, nullptr, fbf, 1024, 1021, 2);
    gemm_nk_kernel<<<dim3(NB, 2), dim3(256), 0, stream>>>(
        fbf, 1024, 32, fout_wp, nullptr, 0, 0, nullptr, 24,
        fout_b, xatt, outb, nullptr, 0, 384, 1);
  }
}

// Round 6
// 1220.932 us; speedup vs baseline: 4.1394x; 1.1584x over previous
//
#include <hip/hip_runtime.h>
#include <math.h>

typedef long long i64;
typedef unsigned short u16;
typedef unsigned int u32;

#define DIMC 384
#define DIM3 1152
#define HC 48
#define HWN 4096

using bf16x8 = __attribute__((ext_vector_type(8))) short;
using f32x4 = __attribute__((ext_vector_type(4))) float;

__device__ __forceinline__ float bf2f(u16 u) { u32 x = ((u32)u) << 16; return __uint_as_float(x); }
__device__ __forceinline__ u16 f2bf(float f) {
  u32 u = __float_as_uint(f);
  u32 r = u + 0x7FFFu + ((u >> 16) & 1u);
  return (u16)(r >> 16);
}
__device__ __forceinline__ void st_out(float* p, float v) { *p = v; }
__device__ __forceinline__ void st_out(u16* p, float v) { *p = f2bf(v); }

__device__ __forceinline__ void gld_lds16(const u16* g, u16* l) {
  __builtin_amdgcn_global_load_lds(
      (const __attribute__((address_space(1))) void*)g,
      (__attribute__((address_space(3))) void*)l, 16, 0, 0);
}

// ---------------- utility kernels ----------------

__global__ void zero_kernel(float* __restrict__ p, int n) {
  int i = blockIdx.x * 256 + threadIdx.x;
  if (i < n) p[i] = 0.f;
}

// per-pixel LayerNorm stats over C=384 channels (input NCHW fp32)
__global__ void stats_kernel(const float* __restrict__ x, float* __restrict__ mu,
                             float* __restrict__ rs, int npix) {
  int idx = blockIdx.x * 256 + threadIdx.x;
  if (idx >= npix) return;
  int b = idx >> 12, p = idx & 4095;
  const float* xp = x + ((i64)b * DIMC) * HWN + p;
  float s = 0.f, ss = 0.f;
  for (int c = 0; c < DIMC; ++c) { float v = xp[(i64)c * HWN]; s += v; ss += v * v; }
  float m = s * (1.f / DIMC);
  float var = ss * (1.f / DIMC) - m * m;
  mu[idx] = m;
  rs[idx] = rsqrtf(var + 1e-5f);
}

// LN apply + transpose NCHW fp32 -> [n][384] bf16 (64x64 LDS tile)
__global__ __launch_bounds__(256) void ln_t_kernel(
    const float* __restrict__ x, const float* __restrict__ mu, const float* __restrict__ rs,
    const float* __restrict__ g, const float* __restrict__ bb, u16* __restrict__ y) {
  __shared__ u16 tile[64][66];
  int p0 = blockIdx.x * 64, c0 = blockIdx.y * 64, b = blockIdx.z;
  int t = threadIdx.x;
  int tp = t & 63, tq = t >> 6;
  float m = mu[b * 4096 + p0 + tp], r = rs[b * 4096 + p0 + tp];
  const float* xp = x + (i64)b * DIMC * HWN + (i64)c0 * 4096 + p0;
#pragma unroll
  for (int i = 0; i < 16; ++i) {
    int c = tq + i * 4;
    float v = xp[(i64)c * 4096 + tp];
    tile[c][tp] = f2bf((v - m) * r * g[c0 + c] + bb[c0 + c]);
  }
  __syncthreads();
#pragma unroll
  for (int i = 0; i < 16; ++i) {
    int p = tq + i * 4;
    y[((i64)b * 4096 + p0 + p) * 384 + c0 + tp] = tile[tp][p];
  }
}

// depthwise 3x3 pad1 in [n][c] layout; 4 px per block, threads along c.
template <typename TO>
__global__ __launch_bounds__(256) void dw_nc_kernel(const u16* __restrict__ in, int ldin,
                                                    const float* __restrict__ w,
                                                    const float* __restrict__ bias,
                                                    TO* __restrict__ out, int ldo, int CH) {
  int c = blockIdx.y * 256 + threadIdx.x;
  if (c >= ldo) return;
  i64 p0 = (i64)blockIdx.x * 4;
  i64 pb = p0 & ~4095LL;
  int sp = (int)(p0 & 4095);
  int y = sp >> 6, x0 = sp & 63;
  bool valid = (c < CH);
  float wv[9];
#pragma unroll
  for (int i = 0; i < 9; ++i) wv[i] = valid ? w[c * 9 + i] : 0.f;
  float bv = valid ? bias[c] : 0.f;
  float vin[3][6];
#pragma unroll
  for (int dy = 0; dy < 3; ++dy) {
    int yy = y - 1 + dy;
#pragma unroll
    for (int dx = 0; dx < 6; ++dx) {
      int xx = x0 - 1 + dx;
      float v = 0.f;
      if (valid && (unsigned)yy < 64u && (unsigned)xx < 64u)
        v = bf2f(in[(pb + yy * 64 + xx) * ldin + c]);
      vin[dy][dx] = v;
    }
  }
#pragma unroll
  for (int i = 0; i < 4; ++i) {
    float acc = bv;
#pragma unroll
    for (int dy = 0; dy < 3; ++dy)
#pragma unroll
      for (int dx = 0; dx < 3; ++dx) acc += vin[dy][i + dx] * wv[dy * 3 + dx];
    st_out(&out[(p0 + i) * ldo + c], valid ? acc : 0.f);
  }
}

// l2-normalize rows of 64
__global__ void l2row_kernel(const float* __restrict__ in, float* __restrict__ out) {
  int r = blockIdx.x;
  int lane = threadIdx.x;
  float v = in[r * 64 + lane];
  float ss = v * v;
  for (int o = 32; o > 0; o >>= 1) ss += __shfl_xor(ss, o);
  float n = fmaxf(sqrtf(ss), 1e-12f);
  out[r * 64 + lane] = v / n;
}

// conv 3x3, 3 -> 384 channels, output [p][384]
__global__ void spm_kernel(const float* __restrict__ s, const float* __restrict__ w,
                           const float* __restrict__ bias, float* __restrict__ out) {
  int idx = blockIdx.x * 256 + threadIdx.x;  // 4096*384
  int c = idx % 384, p = idx / 384;
  int xc = p & 63, yr = p >> 6;
  const float* wp = w + c * 27;
  float acc = bias[c];
  for (int ic = 0; ic < 3; ++ic)
    for (int dy = -1; dy <= 1; ++dy) {
      int yy = yr + dy; if ((unsigned)yy >= 64u) continue;
      for (int dx = -1; dx <= 1; ++dx) {
        int xx = xc + dx; if ((unsigned)xx >= 64u) continue;
        acc += s[ic * 4096 + yy * 64 + xx] * wp[ic * 9 + (dy + 1) * 3 + (dx + 1)];
      }
    }
  out[idx] = acc;
}

// Q: W-axis l2n (row held in regs) + spm mult -> QS fp32 [n][384]; plane ssq for q,k.
__global__ __launch_bounds__(192) void qknorm2_kernel(
    const float* __restrict__ dwo, const float* __restrict__ spm,
    float* __restrict__ QS, float* __restrict__ qssq, float* __restrict__ kssq) {
  int y = blockIdx.x;
  int b = blockIdx.y;
  int c = blockIdx.z * 192 + threadIdx.x;
  i64 base = ((i64)b * 4096 + y * 64) * 1152;
  float v[64];
  float qs = 0.f;
#pragma unroll
  for (int x = 0; x < 64; ++x) {
    v[x] = dwo[base + (i64)x * 1152 + c];
    qs += v[x] * v[x];
  }
  float rw = 1.f / fmaxf(sqrtf(qs), 1e-12f);
  float ps = 0.f;
#pragma unroll
  for (int x = 0; x < 64; ++x) {
    float u = v[x] * rw * spm[(y * 64 + x) * 384 + c];
    QS[((i64)b * 4096 + y * 64 + x) * 384 + c] = u;
    ps += u * u;
  }
  atomicAdd(&qssq[b * 384 + c], ps);
  float ks = 0.f;
#pragma unroll
  for (int x = 0; x < 64; ++x) {
    float kv = dwo[base + (i64)x * 1152 + 384 + c];
    ks += kv * kv;
  }
  atomicAdd(&kssq[b * 384 + c], ks);
}

// attn partials: attnP[bh][ksp][48][48] = sum_n QS[n][qc] * K[n][kc]  ([n][c] inputs)
__global__ __launch_bounds__(256) void attnS_kernel(const float* __restrict__ QS,
                                                    const float* __restrict__ dwo,
                                                    float* __restrict__ attnP) {
  int ksp = blockIdx.x;
  int bh = blockIdx.y;
  int b = bh >> 3, h = bh & 7;
  __shared__ float qsm[64][49];
  __shared__ float ksm[64][49];
  int t = threadIdx.x, tc = t & 15, td = t >> 4;
  float acc[3][3] = {{0.f}};
  for (int sub = 0; sub < 4; ++sub) {
    i64 nb = (i64)b * 4096 + ksp * 256 + sub * 64;
    __syncthreads();
    for (int l = t; l < 4096; l += 256) {
      int row = l >> 6, cq = l & 63;
      if (cq < 48) {
        qsm[row][cq] = QS[(nb + row) * 384 + h * 48 + cq];
        ksm[row][cq] = dwo[(nb + row) * 1152 + 384 + h * 48 + cq];
      }
    }
    __syncthreads();
#pragma unroll 4
    for (int nn = 0; nn < 64; ++nn) {
      float a0 = qsm[nn][tc], a1 = qsm[nn][tc + 16], a2 = qsm[nn][tc + 32];
      float b0 = ksm[nn][td], b1 = ksm[nn][td + 16], b2 = ksm[nn][td + 32];
      acc[0][0] += a0 * b0; acc[0][1] += a0 * b1; acc[0][2] += a0 * b2;
      acc[1][0] += a1 * b0; acc[1][1] += a1 * b1; acc[1][2] += a1 * b2;
      acc[2][0] += a2 * b0; acc[2][1] += a2 * b1; acc[2][2] += a2 * b2;
    }
  }
  float* ap = attnP + ((i64)bh * 16 + ksp) * 2304;
#pragma unroll
  for (int i = 0; i < 3; ++i)
#pragma unroll
    for (int j = 0; j < 3; ++j)
      ap[(tc + 16 * i) * HC + (td + 16 * j)] = acc[i][j];
}

// blend: fold plane-l2n of q (row) and k (col) + temperature, relu/top-k softmax mix
__global__ void blend_kernel(const float* __restrict__ attnP, const float* __restrict__ qssq,
                             const float* __restrict__ kssq, const float* __restrict__ temp,
                             const float* __restrict__ wmix, const float* __restrict__ pa1,
                             const float* __restrict__ pa2, const float* __restrict__ pa3,
                             const float* __restrict__ pa4, float* __restrict__ comb) {
  int row = blockIdx.x * 4 + (threadIdx.x >> 6);
  int lane = threadIdx.x & 63;
  int bh = row / 48, cc = row - bh * 48;
  int b = bh >> 3, h = bh & 7;
  float a;
  if (lane < 48) {
    const float* pp = attnP + ((i64)bh * 16) * 2304 + cc * 48 + lane;
    float s = 0.f;
#pragma unroll
    for (int sp = 0; sp < 16; ++sp) s += pp[(i64)sp * 2304];
    float qn = 1.f / fmaxf(sqrtf(qssq[b * 384 + h * 48 + cc]), 1e-12f);
    float kn = 1.f / fmaxf(sqrtf(kssq[b * 384 + h * 48 + lane]), 1e-12f);
    a = s * qn * kn * temp[h];
  } else {
    a = -INFINITY;
  }
  int rank = 0;
  for (int j = 0; j < 48; ++j) {
    float aj = __shfl(a, j);
    rank += (aj > a) ? 1 : 0;
  }
  float w0 = wmix[0], w1 = wmix[1];
  float wm = fmaxf(w0, w1);
  float e0 = expf(w0 - wm), e1 = expf(w1 - wm);
  float ws0 = e0 / (e0 + e1), ws1 = e1 / (e0 + e1);
  float c1 = pa1[0], c2 = pa2[0], c3 = pa3[0], c4 = pa4[0];
  float outv = ws0 * (c1 + c2 + c3 + c4) * fmaxf(a, 0.f);
  const int kks[4] = {24, 32, 36, 38};
  const float cs[4] = {c1, c2, c3, c4};
#pragma unroll
  for (int q = 0; q < 4; ++q) {
    float mv = (lane < 48) ? ((rank < kks[q]) ? a : a * 1e-6f) : -INFINITY;
    float mx = mv;
    for (int o = 32; o > 0; o >>= 1) mx = fmaxf(mx, __shfl_xor(mx, o));
    float e = (lane < 48) ? expf(mv - mx) : 0.f;
    float s = e;
    for (int o = 32; o > 0; o >>= 1) s += __shfl_xor(s, o);
    outv += ws1 * cs[q] * (e / s);
  }
  if (lane < 48) comb[(i64)row * 48 + lane] = outv;
}

// attn_out[n][c] = sum_d comb[b,h,cc,d] * V[n][768+h*48+d]  (V from dwo fp32) -> bf16
__global__ __launch_bounds__(384) void combv_kernel(const float* __restrict__ dwo,
                                                    const float* __restrict__ comb,
                                                    u16* __restrict__ AO) {
  __shared__ float Vs[4][8][49];
  i64 p0 = (i64)blockIdx.x * 4;
  int b = (int)(p0 >> 12);
  int t = threadIdx.x;
  int h = t / 48, cc = t - h * 48;
#pragma unroll
  for (int px = 0; px < 4; ++px)
    Vs[px][h][cc] = dwo[(p0 + px) * 1152 + 768 + t];
  __syncthreads();
  float cr[48];
  const float* cp = comb + ((i64)(b * 8 + h) * 48 + cc) * 48;
#pragma unroll
  for (int d = 0; d < 48; d += 4) {
    float4 v = *(const float4*)(cp + d);
    cr[d] = v.x; cr[d + 1] = v.y; cr[d + 2] = v.z; cr[d + 3] = v.w;
  }
#pragma unroll
  for (int px = 0; px < 4; ++px) {
    float s = 0.f;
#pragma unroll
    for (int d = 0; d < 48; ++d) s += cr[d] * Vs[px][h][d];
    AO[(p0 + px) * 384 + t] = f2bf(s);
  }
}

// mat-vec (precompute)
__global__ void matvec_kernel(const float* __restrict__ Wm, int ldw, int koff,
                              const float* __restrict__ v, const float* __restrict__ add,
                              float* __restrict__ out, int K) {
  int ro = blockIdx.x;
  int t = threadIdx.x;
  const float* wp = Wm + (i64)ro * ldw + koff;
  float s = 0.f;
  for (int k = t; k < K; k += 256) s += wp[k] * v[k];
  __shared__ float sred[256];
  sred[t] = s;
  __syncthreads();
  for (int o = 128; o > 0; o >>= 1) {
    if (t < o) sred[t] += sred[t + o];
    __syncthreads();
  }
  if (t == 0) out[ro] = sred[0] + (add ? add[ro] : 0.f);
}

// 64x64 fp32 GEMM (weight-fold precompute only), split-K atomics
__global__ __launch_bounds__(256) void gemm64_kernel(
    const float* __restrict__ W, int ldw,
    const float* __restrict__ X,
    float* __restrict__ Y,
    int M, int N, int K, int ksplit) {
  int nt = blockIdx.x, mt = blockIdx.y;
  int ks = blockIdx.z;
  int kchunk = (((K + ksplit - 1) / ksplit) + 15) & ~15;
  int kbeg = ks * kchunk;
  int kend = min(K, kbeg + kchunk);
  __shared__ float As[16][68];
  __shared__ float Bs[16][68];
  int t = threadIdx.x, tx = t & 15, ty = t >> 4;
  int m0 = mt * 64, n0 = nt * 64;
  float acc[4][4];
#pragma unroll
  for (int i = 0; i < 4; ++i)
#pragma unroll
    for (int j = 0; j < 4; ++j) acc[i][j] = 0.f;
  for (int k0 = kbeg; k0 < kend; k0 += 16) {
    int kk = t & 15;
#pragma unroll
    for (int r = 0; r < 4; ++r) {
      int mm = (t >> 4) + r * 16;
      int gm = m0 + mm, gk = k0 + kk;
      As[kk][mm] = (gm < M && gk < kend) ? W[(i64)gm * ldw + gk] : 0.f;
    }
    int nn = t & 63;
#pragma unroll
    for (int r = 0; r < 4; ++r) {
      int k2 = (t >> 6) + r * 4;
      int gk = k0 + k2;
      Bs[k2][nn] = (gk < kend && n0 + nn < N) ? X[(i64)gk * N + n0 + nn] : 0.f;
    }
    __syncthreads();
#pragma unroll
    for (int kk3 = 0; kk3 < 16; ++kk3) {
      float4 av = *(const float4*)&As[kk3][ty * 4];
      float4 bv = *(const float4*)&Bs[kk3][tx * 4];
      float aa[4] = {av.x, av.y, av.z, av.w};
      float bb2[4] = {bv.x, bv.y, bv.z, bv.w};
#pragma unroll
      for (int i = 0; i < 4; ++i)
#pragma unroll
        for (int j = 0; j < 4; ++j) acc[i][j] += aa[i] * bb2[j];
    }
    __syncthreads();
  }
#pragma unroll
  for (int i = 0; i < 4; ++i) {
    int gm = m0 + ty * 4 + i;
    if (gm >= M || n0 + tx * 4 >= N) continue;
    for (int j = 0; j < 4; ++j) atomicAdd(&Y[(i64)gm * N + n0 + tx * 4 + j], acc[i][j]);
  }
}

// pack fp32 weight [M][ldw] (cols koff..koff+K) into MFMA fragment order
__global__ void pack_w_kernel(const float* __restrict__ W, int ldw, int koff, int M, int K,
                              int KS, u16* __restrict__ out, int nfrag) {
  int tid = blockIdx.x * 256 + threadIdx.x;
  int lane = tid & 63;
  int idx = tid >> 6;
  if (idx >= nfrag * KS) return;
  int ks = idx % KS, fm = idx / KS;
  int row = fm * 16 + (lane & 15);
  int kb = ks * 32 + (lane >> 4) * 8;
  union { u16 us[8]; uint4 q; } u;
#pragma unroll
  for (int j = 0; j < 8; ++j) {
    int k = kb + j;
    u.us[j] = (row < M && k < K) ? f2bf(W[(i64)row * ldw + koff + k]) : (u16)0;
  }
  *(uint4*)(out + (i64)idx * 512 + lane * 8) = u.q;
}

// ---------------- MFMA GEMM (m97 structure): 128n x 128m tile, BK=32 ----------------
// Both A (activations [n][k] bf16) and W (packed frags) staged via global_load_lds.
// 4 waves, each computes 64n x 64m (4x4 fragments, 16 MFMA per K-step).
// epi 0: bias -> bf16 Yh[n][ldo]; epi 2: bias+gelu(v)*v -> bf16 Yh[n][ldo];
// epi 1: bias + Res([b][c][p] fp32) -> fp32 Yf[b][c][p]
__global__ __launch_bounds__(256) void gemm_nk_kernel(
    const u16* __restrict__ A1, int lda1, int KS1, const u16* __restrict__ Wp1,
    const u16* __restrict__ A2, int lda2, int KS2, const u16* __restrict__ Wp2,
    int nfrag, const float* __restrict__ bias,
    const float* __restrict__ Res, float* __restrict__ Yf, u16* __restrict__ Yh,
    int ldo, int M, int epi) {
  __shared__ __align__(16) u16 Ls[2][16][512];  // [buf][A frags 0..7 | W frags 8..15][lane*8]
  int t = threadIdx.x, lane = t & 63, w = t >> 6;
  int wn = w >> 1, wm = w & 1;
  i64 n0 = (i64)blockIdx.x * 128;
  int mt = blockIdx.y;

  f32x4 acc[4][4];
#pragma unroll
  for (int i = 0; i < 4; ++i)
#pragma unroll
    for (int r = 0; r < 4; ++r) acc[i][r] = (f32x4){0.f, 0.f, 0.f, 0.f};

  // wave w stages A-frags {2w,2w+1} and W-frags {2w,2w+1} of the step
  auto stage = [&](int kt, int buf) {
    const u16* A; int lda; const u16* Wp; int KSc; int ks;
    if (kt < KS1) { A = A1; lda = lda1; Wp = Wp1; KSc = KS1; ks = kt; }
    else { A = A2; lda = lda2; Wp = Wp2; KSc = KS2; ks = kt - KS1; }
#pragma unroll
    for (int j = 0; j < 2; ++j) {
      int f = w * 2 + j;
      const u16* srcA = A + (n0 + f * 16 + (lane & 15)) * (i64)lda + ks * 32 + (lane >> 4) * 8;
      gld_lds16(srcA, &Ls[buf][f][0]);
      int fm = mt * 8 + f;
      int fmc = min(fm, nfrag - 1);
      const u16* srcW = Wp + ((i64)fmc * KSc + ks) * 512 + lane * 8;
      gld_lds16(srcW, &Ls[buf][8 + f][0]);
    }
  };

  int KT = KS1 + KS2;
  stage(0, 0);
  __syncthreads();
  int s = 0;
  for (int kt = 0; kt < KT; ++kt) {
    if (kt + 1 < KT) stage(kt + 1, s ^ 1);
    bf16x8 af[4], wf[4];
#pragma unroll
    for (int i = 0; i < 4; ++i) {
      af[i] = *reinterpret_cast<const bf16x8*>(&Ls[s][wn * 4 + i][lane * 8]);
      wf[i] = *reinterpret_cast<const bf16x8*>(&Ls[s][8 + wm * 4 + i][lane * 8]);
    }
#pragma unroll
    for (int i = 0; i < 4; ++i)
#pragma unroll
      for (int r = 0; r < 4; ++r)
        acc[i][r] = __builtin_amdgcn_mfma_f32_16x16x32_bf16(af[i], wf[r], acc[i][r], 0, 0, 0);
    __syncthreads();
    s ^= 1;
  }

#pragma unroll
  for (int i = 0; i < 4; ++i) {
    int nbase = (int)n0 + (wn * 4 + i) * 16 + ((lane >> 4) << 2);
#pragma unroll
    for (int r = 0; r < 4; ++r) {
      int m = mt * 128 + (wm * 4 + r) * 16 + (lane & 15);
      if (epi == 1) {
        if (m < M) {
          float bv = bias[m];
          int b = nbase >> 12, p = nbase & 4095;
          i64 off = ((i64)b * DIMC + m) * 4096 + p;
          float4 rv = *(const float4*)(Res + off);
          float4 o;
          o.x = acc[i][r][0] + bv + rv.x;
          o.y = acc[i][r][1] + bv + rv.y;
          o.z = acc[i][r][2] + bv + rv.z;
          o.w = acc[i][r][3] + bv + rv.w;
          *(float4*)(Yf + off) = o;
        }
      } else {
        if (m < ldo) {
          float bv = (m < M) ? bias[m] : 0.f;
#pragma unroll
          for (int ii = 0; ii < 4; ++ii) {
            float v = acc[i][r][ii] + bv;
            if (epi == 2) {
              float gg = 0.5f * v * (1.f + erff(v * 0.70710678118f));
              v = gg * v;
            }
            if (m >= M) v = 0.f;
            Yh[(i64)(nbase + ii) * ldo + m] = f2bf(v);
          }
        }
      }
    }
  }
}

// ---------------- launch ----------------

extern "C" void kernel_launch(void* const* d_in, const int* in_sizes, int n_in,
                              void* d_out, int out_size, void* d_ws, size_t ws_size,
                              hipStream_t stream) {
  (void)in_sizes; (void)n_in; (void)out_size;
  const float* x       = (const float*)d_in[0];
  const float* spf     = (const float*)d_in[1];
  const float* ln1_w   = (const float*)d_in[2];
  const float* ln1_b   = (const float*)d_in[3];
  const float* qkv_w   = (const float*)d_in[4];
  const float* qkv_b   = (const float*)d_in[5];
  const float* qkvdw_w = (const float*)d_in[6];
  const float* qkvdw_b = (const float*)d_in[7];
  const float* proj_w  = (const float*)d_in[8];
  const float* proj_b  = (const float*)d_in[9];
  const float* temp    = (const float*)d_in[10];
  const float* a1      = (const float*)d_in[11];
  const float* a2      = (const float*)d_in[12];
  const float* a3      = (const float*)d_in[13];
  const float* a4      = (const float*)d_in[14];
  const float* wmix    = (const float*)d_in[15];
  const float* pout_w  = (const float*)d_in[16];
  const float* pout_b  = (const float*)d_in[17];
  const float* ln2_w   = (const float*)d_in[18];
  const float* ln2_b   = (const float*)d_in[19];
  const float* pin_w   = (const float*)d_in[20];
  const float* pin_b   = (const float*)d_in[21];
  const float* dw_w    = (const float*)d_in[22];
  const float* dw_b    = (const float*)d_in[23];
  const float* lin_w   = (const float*)d_in[24];
  const float* lin_b   = (const float*)d_in[25];
  const float* adj_w   = (const float*)d_in[26];
  const float* adj_b   = (const float*)d_in[27];
  const float* fout_w  = (const float*)d_in[28];
  const float* fout_b  = (const float*)d_in[29];
  float* out = (float*)d_out;
  float* ws = (float*)d_ws;

  const i64 PLANE = (i64)DIMC * HWN;  // 1,572,864
  const i64 FIXED = 5326592;
  const i64 PER = 9750528;
  int C = 8;
  while (C > 1 && (size_t)(FIXED + PER * C) * 4 > ws_size) C >>= 1;
  if ((size_t)(FIXED + PER * C) * 4 > ws_size) return;  // ws too small -> visible failure
  int nch = 8 / C;

  float* SPM   = ws;                          // [p][384] fp32
  float* W2v   = SPM + 1572864;
  float* W3v   = W2v + 392064;
  float* b2v   = W3v + 392064;
  float* b3v   = b2v + 1024;
  float* spfn  = b3v + 1024;
  float* mu1   = spfn + 12288;
  float* rs1   = mu1 + 32768;
  float* mu2   = rs1 + 32768;
  float* rs2   = mu2 + 32768;
  float* qssq  = rs2 + 32768;                 // C*384 (alloc 3072)
  float* kssq  = qssq + 3072;                 // C*384 (alloc 3072)
  float* packbase = kssq + 3072;
  u16* qkv_wp  = (u16*)packbase;              // 884736 u16
  u16* pout_wp = qkv_wp + 884736;             // 294912
  u16* pin_wp  = pout_wp + 294912;            // 786432
  u16* adj1_wp = pin_wp + 786432;             // 2097152
  u16* W3_wp   = adj1_wp + 2097152;           // 786432
  u16* fout_wp = W3_wp + 786432;              // 786432
  float* dyn   = packbase + 2818048;
  float* attnP = dyn;                         // C*294912
  float* comb  = attnP + (i64)C * 294912;     // C*18432
  float* arena4 = comb + (i64)C * 18432;      // C*786432 f32 (Xbf / AO / xn2: [n][384] bf16)
  float* arena3 = arena4 + (i64)C * 786432;   // C*1572864 f32 (x_attn [b][c][p] fp32)
  float* arena2 = arena3 + (i64)C * 1572864;  // C*2359296 f32 (qkv_bf / QS / fbf)
  float* arena1 = arena2 + (i64)C * 2359296;  // C*4718592 f32 (DWo / x1+x1d)

  // ---- precompute: folded weights W2 = lin@pin2, W3 = adj2@W2 ----
  zero_kernel<<<dim3(3063), dim3(256), 0, stream>>>(W2v, 784128);
  matvec_kernel<<<dim3(1021), dim3(256), 0, stream>>>(lin_w, 1021, 0, pin_b + 1021, lin_b, b2v, 1021);
  gemm64_kernel<<<dim3(6, 16, 8), dim3(256), 0, stream>>>(
      lin_w, 1021, pin_w + (i64)1021 * 384, W2v, 1021, 384, 1021, 8);
  matvec_kernel<<<dim3(1021), dim3(256), 0, stream>>>(adj_w, 2042, 1021, b2v, adj_b, b3v, 1021);
  gemm64_kernel<<<dim3(6, 16, 8), dim3(256), 0, stream>>>(
      adj_w + 1021, 2042, W2v, W3v, 1021, 384, 1021, 8);

  // ---- pack weights to MFMA fragment layout (bf16) ----
  pack_w_kernel<<<dim3(216), dim3(256), 0, stream>>>(qkv_w, 384, 0, 1152, 384, 12, qkv_wp, 72);
  pack_w_kernel<<<dim3(72), dim3(256), 0, stream>>>(pout_w, 384, 0, 384, 384, 12, pout_wp, 24);
  pack_w_kernel<<<dim3(192), dim3(256), 0, stream>>>(pin_w, 384, 0, 1021, 384, 12, pin_wp, 64);
  pack_w_kernel<<<dim3(512), dim3(256), 0, stream>>>(adj_w, 2042, 0, 1021, 1021, 32, adj1_wp, 64);
  pack_w_kernel<<<dim3(192), dim3(256), 0, stream>>>(W3v, 384, 0, 1021, 384, 12, W3_wp, 64);
  pack_w_kernel<<<dim3(192), dim3(256), 0, stream>>>(fout_w, 1021, 0, 384, 1021, 32, fout_wp, 24);

  // ---- shared precompute ----
  l2row_kernel<<<dim3(192), dim3(64), 0, stream>>>(spf, spfn);
  spm_kernel<<<dim3(6144), dim3(256), 0, stream>>>(spfn, proj_w, proj_b, SPM);
  stats_kernel<<<dim3(128), dim3(256), 0, stream>>>(x, mu1, rs1, 32768);

  for (int ch = 0; ch < nch; ++ch) {
    int b0 = ch * C;
    const float* xb = x + (i64)b0 * PLANE;
    float* outb = out + (i64)b0 * PLANE;
    const float* m1 = mu1 + (i64)b0 * HWN;
    const float* r1 = rs1 + (i64)b0 * HWN;

    u16* Xbf    = (u16*)arena4;               // [n][384] bf16
    u16* qkv_bf = (u16*)arena2;               // [n][1152] bf16
    float* DWo  = arena1;                     // [n][1152] fp32
    float* QS   = arena2;                     // [n][384] fp32 (qkv_bf dead)
    u16* AO     = (u16*)arena4;               // [n][384] bf16 (Xbf dead)
    float* xatt = arena3;                     // [b][c][p] fp32
    u16* xn2    = (u16*)arena4;               // [n][384] bf16 (AO dead)
    u16* x1     = (u16*)arena1;               // [n][1024] bf16 (DWo dead)
    u16* x1d    = (u16*)(arena1 + (i64)C * 2097152);  // [n][1024] bf16
    u16* fbf    = (u16*)arena2;               // [n][1024] bf16 (QS dead)

    int NB = C * 32;  // n-tiles of 128

    // ---- attention ----
    zero_kernel<<<dim3((2 * C * 384 + 255) / 256), dim3(256), 0, stream>>>(qssq, 2 * C * 384);
    ln_t_kernel<<<dim3(64, 6, C), dim3(256), 0, stream>>>(xb, m1, r1, ln1_w, ln1_b, Xbf);
    gemm_nk_kernel<<<dim3(NB, 9), dim3(256), 0, stream>>>(
        Xbf, 384, 12, qkv_wp, nullptr, 0, 0, nullptr, 72,
        qkv_b, nullptr, nullptr, qkv_bf, 1152, 1152, 0);
    dw_nc_kernel<float><<<dim3(C * 1024, 5), dim3(256), 0, stream>>>(
        qkv_bf, 1152, qkvdw_w, qkvdw_b, DWo, 1152, 1152);
    qknorm2_kernel<<<dim3(64, C, 2), dim3(192), 0, stream>>>(DWo, SPM, QS, qssq, kssq);
    attnS_kernel<<<dim3(16, C * 8), dim3(256), 0, stream>>>(QS, DWo, attnP);
    blend_kernel<<<dim3(96 * C), dim3(256), 0, stream>>>(attnP, qssq, kssq, temp, wmix,
                                                         a1, a2, a3, a4, comb);
    combv_kernel<<<dim3(C * 1024), dim3(384), 0, stream>>>(DWo, comb, AO);
    gemm_nk_kernel<<<dim3(NB, 3), dim3(256), 0, stream>>>(
        AO, 384, 12, pout_wp, nullptr, 0, 0, nullptr, 24,
        pout_b, xb, xatt, nullptr, 0, 384, 1);

    // ---- feed-forward ----
    stats_kernel<<<dim3(C * 16), dim3(256), 0, stream>>>(xatt, mu2, rs2, C * 4096);
    ln_t_kernel<<<dim3(64, 6, C), dim3(256), 0, stream>>>(xatt, mu2, rs2, ln2_w, ln2_b, xn2);
    gemm_nk_kernel<<<dim3(NB, 8), dim3(256), 0, stream>>>(
        xn2, 384, 12, pin_wp, nullptr, 0, 0, nullptr, 64,
        pin_b, nullptr, nullptr, x1, 1024, 1021, 0);
    dw_nc_kernel<u16><<<dim3(C * 1024, 4), dim3(256), 0, stream>>>(
        x1, 1024, dw_w, dw_b, x1d, 1024, 1021);
    gemm_nk_kernel<<<dim3(NB, 8), dim3(256), 0, stream>>>(
        x1d, 1024, 32, adj1_wp, xn2, 384, 12, W3_wp, 64,
        b3v, nullptr, nullptr, fbf, 1024, 1021, 2);
    gemm_nk_kernel<<<dim3(NB, 3), dim3(256), 0, stream>>>(
        fbf, 1024, 32, fout_wp, nullptr, 0, 0, nullptr, 24,
        fout_b, xatt, outb, nullptr, 0, 384, 1);
  }
}

// Round 7
// 1151.564 us; speedup vs baseline: 4.3887x; 1.0602x over previous
//
#include <hip/hip_runtime.h>
#include <math.h>

typedef long long i64;
typedef unsigned short u16;
typedef unsigned int u32;

#define DIMC 384
#define DIM3 1152
#define HC 48
#define HWN 4096

using bf16x8 = __attribute__((ext_vector_type(8))) short;
using f32x4 = __attribute__((ext_vector_type(4))) float;

__device__ __forceinline__ float bf2f(u16 u) { u32 x = ((u32)u) << 16; return __uint_as_float(x); }
__device__ __forceinline__ u16 f2bf(float f) {
  u32 u = __float_as_uint(f);
  u32 r = u + 0x7FFFu + ((u >> 16) & 1u);
  return (u16)(r >> 16);
}

__device__ __forceinline__ void gld_lds16(const u16* g, u16* l) {
  __builtin_amdgcn_global_load_lds(
      (const __attribute__((address_space(1))) void*)g,
      (__attribute__((address_space(3))) void*)l, 16, 0, 0);
}

// ---------------- utility kernels ----------------

__global__ void zero_kernel(float* __restrict__ p, int n) {
  int i = blockIdx.x * 256 + threadIdx.x;
  if (i < n) p[i] = 0.f;
}

// per-pixel LayerNorm stats over C=384 channels (input NCHW fp32), 4 px/thread
__global__ void stats_kernel(const float* __restrict__ x, float* __restrict__ mu,
                             float* __restrict__ rs, int npix4) {
  int idx = blockIdx.x * 256 + threadIdx.x;
  if (idx >= npix4) return;
  int pg = idx * 4;
  int b = pg >> 12, p = pg & 4095;
  const float* xp = x + ((i64)b * DIMC) * HWN + p;
  float s0 = 0.f, s1 = 0.f, s2 = 0.f, s3 = 0.f;
  float q0 = 0.f, q1 = 0.f, q2 = 0.f, q3 = 0.f;
  for (int c = 0; c < DIMC; ++c) {
    float4 v = *(const float4*)(xp + (i64)c * HWN);
    s0 += v.x; s1 += v.y; s2 += v.z; s3 += v.w;
    q0 += v.x * v.x; q1 += v.y * v.y; q2 += v.z * v.z; q3 += v.w * v.w;
  }
  const float inv = 1.f / DIMC;
  float4 m = make_float4(s0 * inv, s1 * inv, s2 * inv, s3 * inv);
  float4 r;
  r.x = rsqrtf(q0 * inv - m.x * m.x + 1e-5f);
  r.y = rsqrtf(q1 * inv - m.y * m.y + 1e-5f);
  r.z = rsqrtf(q2 * inv - m.z * m.z + 1e-5f);
  r.w = rsqrtf(q3 * inv - m.w * m.w + 1e-5f);
  *(float4*)(mu + (i64)pg) = m;
  *(float4*)(rs + (i64)pg) = r;
}

// LN apply + transpose NCHW fp32 -> [n][384] bf16 (64x64 LDS tile)
__global__ __launch_bounds__(256) void ln_t_kernel(
    const float* __restrict__ x, const float* __restrict__ mu, const float* __restrict__ rs,
    const float* __restrict__ g, const float* __restrict__ bb, u16* __restrict__ y) {
  __shared__ u16 tile[64][66];
  int p0 = blockIdx.x * 64, c0 = blockIdx.y * 64, b = blockIdx.z;
  int t = threadIdx.x;
  int tp = t & 63, tq = t >> 6;
  float m = mu[b * 4096 + p0 + tp], r = rs[b * 4096 + p0 + tp];
  const float* xp = x + (i64)b * DIMC * HWN + (i64)c0 * 4096 + p0;
#pragma unroll
  for (int i = 0; i < 16; ++i) {
    int c = tq + i * 4;
    float v = xp[(i64)c * 4096 + tp];
    tile[c][tp] = f2bf((v - m) * r * g[c0 + c] + bb[c0 + c]);
  }
  __syncthreads();
#pragma unroll
  for (int i = 0; i < 16; ++i) {
    int p = tq + i * 4;
    y[((i64)b * 4096 + p0 + p) * 384 + c0 + tp] = tile[tp][p];
  }
}

// depthwise 3x3 pad1, [n][c] bf16 in -> bf16 out; 4 channels x 4 pixels per thread.
__global__ __launch_bounds__(256) void dw8_kernel(const u16* __restrict__ in, int ld,
                                                  const float* __restrict__ w,
                                                  const float* __restrict__ bias,
                                                  u16* __restrict__ out, int CH) {
  int t = threadIdx.x;
  int g = t & 31;   // channel group of 4
  int s = t >> 5;   // pixel slot of 4
  int c0 = (blockIdx.y * 32 + g) * 4;
  if (c0 >= ld) return;
  i64 p0 = (i64)blockIdx.x * 32 + s * 4;
  i64 pb = p0 & ~4095LL;
  int sp = (int)(p0 & 4095);
  int y = sp >> 6, x0 = sp & 63;
  float wv[9][4];
  float acc[4][4];
#pragma unroll
  for (int cc = 0; cc < 4; ++cc) {
    bool val = (c0 + cc) < CH;
    float bv = val ? bias[c0 + cc] : 0.f;
#pragma unroll
    for (int i = 0; i < 4; ++i) acc[i][cc] = bv;
#pragma unroll
    for (int j = 0; j < 9; ++j) wv[j][cc] = val ? w[(c0 + cc) * 9 + j] : 0.f;
  }
#pragma unroll
  for (int dy = 0; dy < 3; ++dy) {
    int yy = y - 1 + dy;
    if ((unsigned)yy >= 64u) continue;
    float row[6][4];
#pragma unroll
    for (int dx = 0; dx < 6; ++dx) {
      int xx = x0 - 1 + dx;
      if ((unsigned)xx < 64u) {
        ushort4 v = *(const ushort4*)(in + (pb + yy * 64 + xx) * ld + c0);
        row[dx][0] = bf2f(v.x); row[dx][1] = bf2f(v.y);
        row[dx][2] = bf2f(v.z); row[dx][3] = bf2f(v.w);
      } else {
        row[dx][0] = 0.f; row[dx][1] = 0.f; row[dx][2] = 0.f; row[dx][3] = 0.f;
      }
    }
#pragma unroll
    for (int i = 0; i < 4; ++i)
#pragma unroll
      for (int dx = 0; dx < 3; ++dx)
#pragma unroll
        for (int cc = 0; cc < 4; ++cc)
          acc[i][cc] += row[i + dx][cc] * wv[dy * 3 + dx][cc];
  }
#pragma unroll
  for (int i = 0; i < 4; ++i) {
    ushort4 o;
    o.x = (c0 + 0 < CH) ? f2bf(acc[i][0]) : (u16)0;
    o.y = (c0 + 1 < CH) ? f2bf(acc[i][1]) : (u16)0;
    o.z = (c0 + 2 < CH) ? f2bf(acc[i][2]) : (u16)0;
    o.w = (c0 + 3 < CH) ? f2bf(acc[i][3]) : (u16)0;
    *(ushort4*)(out + (p0 + i) * ld + c0) = o;
  }
}

// l2-normalize rows of 64
__global__ void l2row_kernel(const float* __restrict__ in, float* __restrict__ out) {
  int r = blockIdx.x;
  int lane = threadIdx.x;
  float v = in[r * 64 + lane];
  float ss = v * v;
  for (int o = 32; o > 0; o >>= 1) ss += __shfl_xor(ss, o);
  float n = fmaxf(sqrtf(ss), 1e-12f);
  out[r * 64 + lane] = v / n;
}

// conv 3x3, 3 -> 384 channels, output [p][384]
__global__ void spm_kernel(const float* __restrict__ s, const float* __restrict__ w,
                           const float* __restrict__ bias, float* __restrict__ out) {
  int idx = blockIdx.x * 256 + threadIdx.x;  // 4096*384
  int c = idx % 384, p = idx / 384;
  int xc = p & 63, yr = p >> 6;
  const float* wp = w + c * 27;
  float acc = bias[c];
  for (int ic = 0; ic < 3; ++ic)
    for (int dy = -1; dy <= 1; ++dy) {
      int yy = yr + dy; if ((unsigned)yy >= 64u) continue;
      for (int dx = -1; dx <= 1; ++dx) {
        int xx = xc + dx; if ((unsigned)xx >= 64u) continue;
        acc += s[ic * 4096 + yy * 64 + xx] * wp[ic * 9 + (dy + 1) * 3 + (dx + 1)];
      }
    }
  out[idx] = acc;
}

// Q: W-axis l2n (row in regs) + spm mult -> QS bf16 [n][384]; plane ssq for q,k. bf16 input.
__global__ __launch_bounds__(192) void qknorm2_kernel(
    const u16* __restrict__ dwo, const float* __restrict__ spm,
    u16* __restrict__ QS, float* __restrict__ qssq, float* __restrict__ kssq) {
  int y = blockIdx.x;
  int b = blockIdx.y;
  int c = blockIdx.z * 192 + threadIdx.x;
  i64 base = ((i64)b * 4096 + y * 64) * 1152;
  float v[64];
  float qs = 0.f;
#pragma unroll
  for (int x = 0; x < 64; ++x) {
    v[x] = bf2f(dwo[base + (i64)x * 1152 + c]);
    qs += v[x] * v[x];
  }
  float rw = 1.f / fmaxf(sqrtf(qs), 1e-12f);
  float ps = 0.f;
#pragma unroll
  for (int x = 0; x < 64; ++x) {
    float u = v[x] * rw * spm[(y * 64 + x) * 384 + c];
    QS[((i64)b * 4096 + y * 64 + x) * 384 + c] = f2bf(u);
    ps += u * u;
  }
  atomicAdd(&qssq[b * 384 + c], ps);
  float ks = 0.f;
#pragma unroll
  for (int x = 0; x < 64; ++x) {
    float kv = bf2f(dwo[base + (i64)x * 1152 + 384 + c]);
    ks += kv * kv;
  }
  atomicAdd(&kssq[b * 384 + c], ks);
}

// attn partials: attnP[bh][ksp][48][48] = sum_n QS[n][qc] * K[n][kc]  (bf16 inputs)
__global__ __launch_bounds__(256) void attnS_kernel(const u16* __restrict__ QS,
                                                    const u16* __restrict__ dwo,
                                                    float* __restrict__ attnP) {
  int ksp = blockIdx.x;
  int bh = blockIdx.y;
  int b = bh >> 3, h = bh & 7;
  __shared__ float qsm[64][49];
  __shared__ float ksm[64][49];
  int t = threadIdx.x, tc = t & 15, td = t >> 4;
  float acc[3][3] = {{0.f}};
  for (int sub = 0; sub < 4; ++sub) {
    i64 nb = (i64)b * 4096 + ksp * 256 + sub * 64;
    __syncthreads();
    for (int l = t; l < 4096; l += 256) {
      int row = l >> 6, cq = l & 63;
      if (cq < 48) {
        qsm[row][cq] = bf2f(QS[(nb + row) * 384 + h * 48 + cq]);
        ksm[row][cq] = bf2f(dwo[(nb + row) * 1152 + 384 + h * 48 + cq]);
      }
    }
    __syncthreads();
#pragma unroll 4
    for (int nn = 0; nn < 64; ++nn) {
      float a0 = qsm[nn][tc], a1 = qsm[nn][tc + 16], a2 = qsm[nn][tc + 32];
      float b0 = ksm[nn][td], b1 = ksm[nn][td + 16], b2 = ksm[nn][td + 32];
      acc[0][0] += a0 * b0; acc[0][1] += a0 * b1; acc[0][2] += a0 * b2;
      acc[1][0] += a1 * b0; acc[1][1] += a1 * b1; acc[1][2] += a1 * b2;
      acc[2][0] += a2 * b0; acc[2][1] += a2 * b1; acc[2][2] += a2 * b2;
    }
  }
  float* ap = attnP + ((i64)bh * 16 + ksp) * 2304;
#pragma unroll
  for (int i = 0; i < 3; ++i)
#pragma unroll
    for (int j = 0; j < 3; ++j)
      ap[(tc + 16 * i) * HC + (td + 16 * j)] = acc[i][j];
}

// blend: fold plane-l2n of q (row) and k (col) + temperature, relu/top-k softmax mix
__global__ void blend_kernel(const float* __restrict__ attnP, const float* __restrict__ qssq,
                             const float* __restrict__ kssq, const float* __restrict__ temp,
                             const float* __restrict__ wmix, const float* __restrict__ pa1,
                             const float* __restrict__ pa2, const float* __restrict__ pa3,
                             const float* __restrict__ pa4, float* __restrict__ comb) {
  int row = blockIdx.x * 4 + (threadIdx.x >> 6);
  int lane = threadIdx.x & 63;
  int bh = row / 48, cc = row - bh * 48;
  int b = bh >> 3, h = bh & 7;
  float a;
  if (lane < 48) {
    const float* pp = attnP + ((i64)bh * 16) * 2304 + cc * 48 + lane;
    float s = 0.f;
#pragma unroll
    for (int sp = 0; sp < 16; ++sp) s += pp[(i64)sp * 2304];
    float qn = 1.f / fmaxf(sqrtf(qssq[b * 384 + h * 48 + cc]), 1e-12f);
    float kn = 1.f / fmaxf(sqrtf(kssq[b * 384 + h * 48 + lane]), 1e-12f);
    a = s * qn * kn * temp[h];
  } else {
    a = -INFINITY;
  }
  int rank = 0;
  for (int j = 0; j < 48; ++j) {
    float aj = __shfl(a, j);
    rank += (aj > a) ? 1 : 0;
  }
  float w0 = wmix[0], w1 = wmix[1];
  float wm = fmaxf(w0, w1);
  float e0 = expf(w0 - wm), e1 = expf(w1 - wm);
  float ws0 = e0 / (e0 + e1), ws1 = e1 / (e0 + e1);
  float c1 = pa1[0], c2 = pa2[0], c3 = pa3[0], c4 = pa4[0];
  float outv = ws0 * (c1 + c2 + c3 + c4) * fmaxf(a, 0.f);
  const int kks[4] = {24, 32, 36, 38};
  const float cs[4] = {c1, c2, c3, c4};
#pragma unroll
  for (int q = 0; q < 4; ++q) {
    float mv = (lane < 48) ? ((rank < kks[q]) ? a : a * 1e-6f) : -INFINITY;
    float mx = mv;
    for (int o = 32; o > 0; o >>= 1) mx = fmaxf(mx, __shfl_xor(mx, o));
    float e = (lane < 48) ? expf(mv - mx) : 0.f;
    float s = e;
    for (int o = 32; o > 0; o >>= 1) s += __shfl_xor(s, o);
    outv += ws1 * cs[q] * (e / s);
  }
  if (lane < 48) comb[(i64)row * 48 + lane] = outv;
}

// attn_out[n][c] = sum_d comb[b,h,cc,d] * V[n][768+h*48+d]  (V bf16) -> bf16
__global__ __launch_bounds__(384) void combv_kernel(const u16* __restrict__ dwo,
                                                    const float* __restrict__ comb,
                                                    u16* __restrict__ AO) {
  __shared__ float Vs[4][8][49];
  i64 p0 = (i64)blockIdx.x * 4;
  int b = (int)(p0 >> 12);
  int t = threadIdx.x;
  int h = t / 48, cc = t - h * 48;
#pragma unroll
  for (int px = 0; px < 4; ++px)
    Vs[px][h][cc] = bf2f(dwo[(p0 + px) * 1152 + 768 + t]);
  __syncthreads();
  float cr[48];
  const float* cp = comb + ((i64)(b * 8 + h) * 48 + cc) * 48;
#pragma unroll
  for (int d = 0; d < 48; d += 4) {
    float4 v = *(const float4*)(cp + d);
    cr[d] = v.x; cr[d + 1] = v.y; cr[d + 2] = v.z; cr[d + 3] = v.w;
  }
#pragma unroll
  for (int px = 0; px < 4; ++px) {
    float s = 0.f;
#pragma unroll
    for (int d = 0; d < 48; ++d) s += cr[d] * Vs[px][h][d];
    AO[(p0 + px) * 384 + t] = f2bf(s);
  }
}

// mat-vec (precompute)
__global__ void matvec_kernel(const float* __restrict__ Wm, int ldw, int koff,
                              const float* __restrict__ v, const float* __restrict__ add,
                              float* __restrict__ out, int K) {
  int ro = blockIdx.x;
  int t = threadIdx.x;
  const float* wp = Wm + (i64)ro * ldw + koff;
  float s = 0.f;
  for (int k = t; k < K; k += 256) s += wp[k] * v[k];
  __shared__ float sred[256];
  sred[t] = s;
  __syncthreads();
  for (int o = 128; o > 0; o >>= 1) {
    if (t < o) sred[t] += sred[t + o];
    __syncthreads();
  }
  if (t == 0) out[ro] = sred[0] + (add ? add[ro] : 0.f);
}

// 64x64 fp32 GEMM (weight-fold precompute only), split-K atomics
__global__ __launch_bounds__(256) void gemm64_kernel(
    const float* __restrict__ W, int ldw,
    const float* __restrict__ X,
    float* __restrict__ Y,
    int M, int N, int K, int ksplit) {
  int nt = blockIdx.x, mt = blockIdx.y;
  int ks = blockIdx.z;
  int kchunk = (((K + ksplit - 1) / ksplit) + 15) & ~15;
  int kbeg = ks * kchunk;
  int kend = min(K, kbeg + kchunk);
  __shared__ float As[16][68];
  __shared__ float Bs[16][68];
  int t = threadIdx.x, tx = t & 15, ty = t >> 4;
  int m0 = mt * 64, n0 = nt * 64;
  float acc[4][4];
#pragma unroll
  for (int i = 0; i < 4; ++i)
#pragma unroll
    for (int j = 0; j < 4; ++j) acc[i][j] = 0.f;
  for (int k0 = kbeg; k0 < kend; k0 += 16) {
    int kk = t & 15;
#pragma unroll
    for (int r = 0; r < 4; ++r) {
      int mm = (t >> 4) + r * 16;
      int gm = m0 + mm, gk = k0 + kk;
      As[kk][mm] = (gm < M && gk < kend) ? W[(i64)gm * ldw + gk] : 0.f;
    }
    int nn = t & 63;
#pragma unroll
    for (int r = 0; r < 4; ++r) {
      int k2 = (t >> 6) + r * 4;
      int gk = k0 + k2;
      Bs[k2][nn] = (gk < kend && n0 + nn < N) ? X[(i64)gk * N + n0 + nn] : 0.f;
    }
    __syncthreads();
#pragma unroll
    for (int kk3 = 0; kk3 < 16; ++kk3) {
      float4 av = *(const float4*)&As[kk3][ty * 4];
      float4 bv = *(const float4*)&Bs[kk3][tx * 4];
      float aa[4] = {av.x, av.y, av.z, av.w};
      float bb2[4] = {bv.x, bv.y, bv.z, bv.w};
#pragma unroll
      for (int i = 0; i < 4; ++i)
#pragma unroll
        for (int j = 0; j < 4; ++j) acc[i][j] += aa[i] * bb2[j];
    }
    __syncthreads();
  }
#pragma unroll
  for (int i = 0; i < 4; ++i) {
    int gm = m0 + ty * 4 + i;
    if (gm >= M || n0 + tx * 4 >= N) continue;
    for (int j = 0; j < 4; ++j) atomicAdd(&Y[(i64)gm * N + n0 + tx * 4 + j], acc[i][j]);
  }
}

// pack fp32 weight [M][ldw] (cols koff..koff+K) into MFMA fragment order
__global__ void pack_w_kernel(const float* __restrict__ W, int ldw, int koff, int M, int K,
                              int KS, u16* __restrict__ out, int nfrag) {
  int tid = blockIdx.x * 256 + threadIdx.x;
  int lane = tid & 63;
  int idx = tid >> 6;
  if (idx >= nfrag * KS) return;
  int ks = idx % KS, fm = idx / KS;
  int row = fm * 16 + (lane & 15);
  int kb = ks * 32 + (lane >> 4) * 8;
  union { u16 us[8]; uint4 q; } u;
#pragma unroll
  for (int j = 0; j < 8; ++j) {
    int k = kb + j;
    u.us[j] = (row < M && k < K) ? f2bf(W[(i64)row * ldw + koff + k]) : (u16)0;
  }
  *(uint4*)(out + (i64)idx * 512 + lane * 8) = u.q;
}

// ---------------- MFMA GEMM (m97 structure): 128n x 128m tile, BK=32 ----------------
__global__ __launch_bounds__(256) void gemm_nk_kernel(
    const u16* __restrict__ A1, int lda1, int KS1, const u16* __restrict__ Wp1,
    const u16* __restrict__ A2, int lda2, int KS2, const u16* __restrict__ Wp2,
    int nfrag, const float* __restrict__ bias,
    const float* __restrict__ Res, float* __restrict__ Yf, u16* __restrict__ Yh,
    int ldo, int M, int epi) {
  __shared__ __align__(16) u16 Ls[2][16][512];
  int t = threadIdx.x, lane = t & 63, w = t >> 6;
  int wn = w >> 1, wm = w & 1;
  i64 n0 = (i64)blockIdx.x * 128;
  int mt = blockIdx.y;

  f32x4 acc[4][4];
#pragma unroll
  for (int i = 0; i < 4; ++i)
#pragma unroll
    for (int r = 0; r < 4; ++r) acc[i][r] = (f32x4){0.f, 0.f, 0.f, 0.f};

  auto stage = [&](int kt, int buf) {
    const u16* A; int lda; const u16* Wp; int KSc; int ks;
    if (kt < KS1) { A = A1; lda = lda1; Wp = Wp1; KSc = KS1; ks = kt; }
    else { A = A2; lda = lda2; Wp = Wp2; KSc = KS2; ks = kt - KS1; }
#pragma unroll
    for (int j = 0; j < 2; ++j) {
      int f = w * 2 + j;
      const u16* srcA = A + (n0 + f * 16 + (lane & 15)) * (i64)lda + ks * 32 + (lane >> 4) * 8;
      gld_lds16(srcA, &Ls[buf][f][0]);
      int fm = mt * 8 + f;
      int fmc = min(fm, nfrag - 1);
      const u16* srcW = Wp + ((i64)fmc * KSc + ks) * 512 + lane * 8;
      gld_lds16(srcW, &Ls[buf][8 + f][0]);
    }
  };

  int KT = KS1 + KS2;
  stage(0, 0);
  __syncthreads();
  int s = 0;
  for (int kt = 0; kt < KT; ++kt) {
    if (kt + 1 < KT) stage(kt + 1, s ^ 1);
    bf16x8 af[4], wf[4];
#pragma unroll
    for (int i = 0; i < 4; ++i) {
      af[i] = *reinterpret_cast<const bf16x8*>(&Ls[s][wn * 4 + i][lane * 8]);
      wf[i] = *reinterpret_cast<const bf16x8*>(&Ls[s][8 + wm * 4 + i][lane * 8]);
    }
#pragma unroll
    for (int i = 0; i < 4; ++i)
#pragma unroll
      for (int r = 0; r < 4; ++r)
        acc[i][r] = __builtin_amdgcn_mfma_f32_16x16x32_bf16(af[i], wf[r], acc[i][r], 0, 0, 0);
    __syncthreads();
    s ^= 1;
  }

#pragma unroll
  for (int i = 0; i < 4; ++i) {
    int nbase = (int)n0 + (wn * 4 + i) * 16 + ((lane >> 4) << 2);
#pragma unroll
    for (int r = 0; r < 4; ++r) {
      int m = mt * 128 + (wm * 4 + r) * 16 + (lane & 15);
      if (epi == 1) {
        if (m < M) {
          float bv = bias[m];
          int b = nbase >> 12, p = nbase & 4095;
          i64 off = ((i64)b * DIMC + m) * 4096 + p;
          float4 rv = *(const float4*)(Res + off);
          float4 o;
          o.x = acc[i][r][0] + bv + rv.x;
          o.y = acc[i][r][1] + bv + rv.y;
          o.z = acc[i][r][2] + bv + rv.z;
          o.w = acc[i][r][3] + bv + rv.w;
          *(float4*)(Yf + off) = o;
        }
      } else {
        if (m < ldo) {
          float bv = (m < M) ? bias[m] : 0.f;
#pragma unroll
          for (int ii = 0; ii < 4; ++ii) {
            float v = acc[i][r][ii] + bv;
            if (epi == 2) {
              float gg = 0.5f * v * (1.f + erff(v * 0.70710678118f));
              v = gg * v;
            }
            if (m >= M) v = 0.f;
            Yh[(i64)(nbase + ii) * ldo + m] = f2bf(v);
          }
        }
      }
    }
  }
}

// ---------------- launch ----------------

extern "C" void kernel_launch(void* const* d_in, const int* in_sizes, int n_in,
                              void* d_out, int out_size, void* d_ws, size_t ws_size,
                              hipStream_t stream) {
  (void)in_sizes; (void)n_in; (void)out_size;
  const float* x       = (const float*)d_in[0];
  const float* spf     = (const float*)d_in[1];
  const float* ln1_w   = (const float*)d_in[2];
  const float* ln1_b   = (const float*)d_in[3];
  const float* qkv_w   = (const float*)d_in[4];
  const float* qkv_b   = (const float*)d_in[5];
  const float* qkvdw_w = (const float*)d_in[6];
  const float* qkvdw_b = (const float*)d_in[7];
  const float* proj_w  = (const float*)d_in[8];
  const float* proj_b  = (const float*)d_in[9];
  const float* temp    = (const float*)d_in[10];
  const float* a1      = (const float*)d_in[11];
  const float* a2      = (const float*)d_in[12];
  const float* a3      = (const float*)d_in[13];
  const float* a4      = (const float*)d_in[14];
  const float* wmix    = (const float*)d_in[15];
  const float* pout_w  = (const float*)d_in[16];
  const float* pout_b  = (const float*)d_in[17];
  const float* ln2_w   = (const float*)d_in[18];
  const float* ln2_b   = (const float*)d_in[19];
  const float* pin_w   = (const float*)d_in[20];
  const float* pin_b   = (const float*)d_in[21];
  const float* dw_w    = (const float*)d_in[22];
  const float* dw_b    = (const float*)d_in[23];
  const float* lin_w   = (const float*)d_in[24];
  const float* lin_b   = (const float*)d_in[25];
  const float* adj_w   = (const float*)d_in[26];
  const float* adj_b   = (const float*)d_in[27];
  const float* fout_w  = (const float*)d_in[28];
  const float* fout_b  = (const float*)d_in[29];
  float* out = (float*)d_out;
  float* ws = (float*)d_ws;

  const i64 PLANE = (i64)DIMC * HWN;  // 1,572,864
  const i64 FIXED = 5326592;
  const i64 PER = 9226240;
  int C = 8;
  while (C > 1 && (size_t)(FIXED + PER * C) * 4 > ws_size) C >>= 1;
  if ((size_t)(FIXED + PER * C) * 4 > ws_size) return;  // ws too small -> visible failure
  int nch = 8 / C;

  float* SPM   = ws;                          // [p][384] fp32
  float* W2v   = SPM + 1572864;
  float* W3v   = W2v + 392064;
  float* b2v   = W3v + 392064;
  float* b3v   = b2v + 1024;
  float* spfn  = b3v + 1024;
  float* mu1   = spfn + 12288;
  float* rs1   = mu1 + 32768;
  float* mu2   = rs1 + 32768;
  float* rs2   = mu2 + 32768;
  float* qssq  = rs2 + 32768;                 // C*384 (alloc 3072)
  float* kssq  = qssq + 3072;                 // C*384 (alloc 3072)
  float* packbase = kssq + 3072;
  u16* qkv_wp  = (u16*)packbase;              // 884736 u16
  u16* pout_wp = qkv_wp + 884736;             // 294912
  u16* pin_wp  = pout_wp + 294912;            // 786432
  u16* adj1_wp = pin_wp + 786432;             // 2097152
  u16* W3_wp   = adj1_wp + 2097152;           // 786432
  u16* fout_wp = W3_wp + 786432;              // 786432
  float* dyn   = packbase + 2818048;
  float* attnP = dyn;                         // C*294912
  float* comb  = attnP + (i64)C * 294912;     // C*18432
  float* arena4 = comb + (i64)C * 18432;      // C*786432 f32 (Xbf / AO / xn2 bf16)
  float* arena3 = arena4 + (i64)C * 786432;   // C*1572864 f32 (x_attn fp32)
  float* arena2 = arena3 + (i64)C * 1572864;  // C*2359296 f32 (qkv_bf / QS / fbf)
  float* arena1 = arena2 + (i64)C * 2359296;  // C*4194304 f32 (DWo bf16 / x1+x1d bf16)

  // ---- precompute: folded weights W2 = lin@pin2, W3 = adj2@W2 ----
  zero_kernel<<<dim3(3063), dim3(256), 0, stream>>>(W2v, 784128);
  matvec_kernel<<<dim3(1021), dim3(256), 0, stream>>>(lin_w, 1021, 0, pin_b + 1021, lin_b, b2v, 1021);
  gemm64_kernel<<<dim3(6, 16, 8), dim3(256), 0, stream>>>(
      lin_w, 1021, pin_w + (i64)1021 * 384, W2v, 1021, 384, 1021, 8);
  matvec_kernel<<<dim3(1021), dim3(256), 0, stream>>>(adj_w, 2042, 1021, b2v, adj_b, b3v, 1021);
  gemm64_kernel<<<dim3(6, 16, 8), dim3(256), 0, stream>>>(
      adj_w + 1021, 2042, W2v, W3v, 1021, 384, 1021, 8);

  // ---- pack weights to MFMA fragment layout (bf16) ----
  pack_w_kernel<<<dim3(216), dim3(256), 0, stream>>>(qkv_w, 384, 0, 1152, 384, 12, qkv_wp, 72);
  pack_w_kernel<<<dim3(72), dim3(256), 0, stream>>>(pout_w, 384, 0, 384, 384, 12, pout_wp, 24);
  pack_w_kernel<<<dim3(192), dim3(256), 0, stream>>>(pin_w, 384, 0, 1021, 384, 12, pin_wp, 64);
  pack_w_kernel<<<dim3(512), dim3(256), 0, stream>>>(adj_w, 2042, 0, 1021, 1021, 32, adj1_wp, 64);
  pack_w_kernel<<<dim3(192), dim3(256), 0, stream>>>(W3v, 384, 0, 1021, 384, 12, W3_wp, 64);
  pack_w_kernel<<<dim3(192), dim3(256), 0, stream>>>(fout_w, 1021, 0, 384, 1021, 32, fout_wp, 24);

  // ---- shared precompute ----
  l2row_kernel<<<dim3(192), dim3(64), 0, stream>>>(spf, spfn);
  spm_kernel<<<dim3(6144), dim3(256), 0, stream>>>(spfn, proj_w, proj_b, SPM);
  stats_kernel<<<dim3(32), dim3(256), 0, stream>>>(x, mu1, rs1, 8192);

  for (int ch = 0; ch < nch; ++ch) {
    int b0 = ch * C;
    const float* xb = x + (i64)b0 * PLANE;
    float* outb = out + (i64)b0 * PLANE;
    const float* m1 = mu1 + (i64)b0 * HWN;
    const float* r1 = rs1 + (i64)b0 * HWN;

    u16* Xbf    = (u16*)arena4;               // [n][384] bf16
    u16* qkv_bf = (u16*)arena2;               // [n][1152] bf16
    u16* DWo    = (u16*)arena1;               // [n][1152] bf16
    u16* QS     = (u16*)arena2;               // [n][384] bf16 (qkv_bf dead)
    u16* AO     = (u16*)arena4;               // [n][384] bf16 (Xbf dead)
    float* xatt = arena3;                     // [b][c][p] fp32
    u16* xn2    = (u16*)arena4;               // [n][384] bf16 (AO dead)
    u16* x1     = (u16*)arena1;               // [n][1024] bf16 (DWo dead)
    u16* x1d    = (u16*)(arena1 + (i64)C * 2097152);  // [n][1024] bf16
    u16* fbf    = (u16*)arena2;               // [n][1024] bf16 (QS dead)

    int NB = C * 32;  // n-tiles of 128

    // ---- attention ----
    zero_kernel<<<dim3((2 * C * 384 + 255) / 256), dim3(256), 0, stream>>>(qssq, 2 * C * 384);
    ln_t_kernel<<<dim3(64, 6, C), dim3(256), 0, stream>>>(xb, m1, r1, ln1_w, ln1_b, Xbf);
    gemm_nk_kernel<<<dim3(NB, 9), dim3(256), 0, stream>>>(
        Xbf, 384, 12, qkv_wp, nullptr, 0, 0, nullptr, 72,
        qkv_b, nullptr, nullptr, qkv_bf, 1152, 1152, 0);
    dw8_kernel<<<dim3(C * 128, 9), dim3(256), 0, stream>>>(
        qkv_bf, 1152, qkvdw_w, qkvdw_b, DWo, 1152);
    qknorm2_kernel<<<dim3(64, C, 2), dim3(192), 0, stream>>>(DWo, SPM, QS, qssq, kssq);
    attnS_kernel<<<dim3(16, C * 8), dim3(256), 0, stream>>>(QS, DWo, attnP);
    blend_kernel<<<dim3(96 * C), dim3(256), 0, stream>>>(attnP, qssq, kssq, temp, wmix,
                                                         a1, a2, a3, a4, comb);
    combv_kernel<<<dim3(C * 1024), dim3(384), 0, stream>>>(DWo, comb, AO);
    gemm_nk_kernel<<<dim3(NB, 3), dim3(256), 0, stream>>>(
        AO, 384, 12, pout_wp, nullptr, 0, 0, nullptr, 24,
        pout_b, xb, xatt, nullptr, 0, 384, 1);

    // ---- feed-forward ----
    stats_kernel<<<dim3((C * 1024 + 255) / 256), dim3(256), 0, stream>>>(xatt, mu2, rs2, C * 1024);
    ln_t_kernel<<<dim3(64, 6, C), dim3(256), 0, stream>>>(xatt, mu2, rs2, ln2_w, ln2_b, xn2);
    gemm_nk_kernel<<<dim3(NB, 8), dim3(256), 0, stream>>>(
        xn2, 384, 12, pin_wp, nullptr, 0, 0, nullptr, 64,
        pin_b, nullptr, nullptr, x1, 1024, 1021, 0);
    dw8_kernel<<<dim3(C * 128, 8), dim3(256), 0, stream>>>(
        x1, 1024, dw_w, dw_b, x1d, 1021);
    gemm_nk_kernel<<<dim3(NB, 8), dim3(256), 0, stream>>>(
        x1d, 1024, 32, adj1_wp, xn2, 384, 12, W3_wp, 64,
        b3v, nullptr, nullptr, fbf, 1024, 1021, 2);
    gemm_nk_kernel<<<dim3(NB, 3), dim3(256), 0, stream>>>(
        fbf, 1024, 32, fout_wp, nullptr, 0, 0, nullptr, 24,
        fout_b, xatt, outb, nullptr, 0, 384, 1);
  }
}

// Round 8
// 1092.162 us; speedup vs baseline: 4.6274x; 1.0544x over previous
//
#include <hip/hip_runtime.h>
#include <math.h>

typedef long long i64;
typedef unsigned short u16;
typedef unsigned int u32;

#define DIMC 384
#define DIM3 1152
#define HC 48
#define HWN 4096

using bf16x8 = __attribute__((ext_vector_type(8))) short;
using f32x4 = __attribute__((ext_vector_type(4))) float;

__device__ __forceinline__ float bf2f(u16 u) { u32 x = ((u32)u) << 16; return __uint_as_float(x); }
__device__ __forceinline__ u16 f2bf(float f) {
  u32 u = __float_as_uint(f);
  u32 r = u + 0x7FFFu + ((u >> 16) & 1u);
  return (u16)(r >> 16);
}

__device__ __forceinline__ void gld_lds16(const u16* g, u16* l) {
  __builtin_amdgcn_global_load_lds(
      (const __attribute__((address_space(1))) void*)g,
      (__attribute__((address_space(3))) void*)l, 16, 0, 0);
}

// ---------------- utility kernels ----------------

__global__ void zero_kernel(float* __restrict__ p, int n) {
  int i = blockIdx.x * 256 + threadIdx.x;
  if (i < n) p[i] = 0.f;
}

__device__ __forceinline__ float ld_as_f(const float* p) { return *p; }
__device__ __forceinline__ float ld_as_f(const u16* p) { return bf2f(*p); }

// per-pixel LayerNorm stats over C=384 channels ([b][c][p] layout), 4 px/thread
template <typename T>
__global__ void stats_kernel(const T* __restrict__ x, float* __restrict__ mu,
                             float* __restrict__ rs, int npix4) {
  int idx = blockIdx.x * 256 + threadIdx.x;
  if (idx >= npix4) return;
  int pg = idx * 4;
  int b = pg >> 12, p = pg & 4095;
  const T* xp = x + ((i64)b * DIMC) * HWN + p;
  float s0 = 0.f, s1 = 0.f, s2 = 0.f, s3 = 0.f;
  float q0 = 0.f, q1 = 0.f, q2 = 0.f, q3 = 0.f;
  for (int c = 0; c < DIMC; ++c) {
    const T* rp = xp + (i64)c * HWN;
    float v0 = ld_as_f(rp), v1 = ld_as_f(rp + 1), v2 = ld_as_f(rp + 2), v3 = ld_as_f(rp + 3);
    s0 += v0; s1 += v1; s2 += v2; s3 += v3;
    q0 += v0 * v0; q1 += v1 * v1; q2 += v2 * v2; q3 += v3 * v3;
  }
  const float inv = 1.f / DIMC;
  float4 m = make_float4(s0 * inv, s1 * inv, s2 * inv, s3 * inv);
  float4 r;
  r.x = rsqrtf(q0 * inv - m.x * m.x + 1e-5f);
  r.y = rsqrtf(q1 * inv - m.y * m.y + 1e-5f);
  r.z = rsqrtf(q2 * inv - m.z * m.z + 1e-5f);
  r.w = rsqrtf(q3 * inv - m.w * m.w + 1e-5f);
  *(float4*)(mu + (i64)pg) = m;
  *(float4*)(rs + (i64)pg) = r;
}

// LN apply + transpose [b][c][p] -> [n][384] bf16 (64x64 LDS tile)
template <typename T>
__global__ __launch_bounds__(256) void ln_t_kernel(
    const T* __restrict__ x, const float* __restrict__ mu, const float* __restrict__ rs,
    const float* __restrict__ g, const float* __restrict__ bb, u16* __restrict__ y) {
  __shared__ u16 tile[64][66];
  int p0 = blockIdx.x * 64, c0 = blockIdx.y * 64, b = blockIdx.z;
  int t = threadIdx.x;
  int tp = t & 63, tq = t >> 6;
  float m = mu[b * 4096 + p0 + tp], r = rs[b * 4096 + p0 + tp];
  const T* xp = x + (i64)b * DIMC * HWN + (i64)c0 * 4096 + p0;
#pragma unroll
  for (int i = 0; i < 16; ++i) {
    int c = tq + i * 4;
    float v = ld_as_f(xp + (i64)c * 4096 + tp);
    tile[c][tp] = f2bf((v - m) * r * g[c0 + c] + bb[c0 + c]);
  }
  __syncthreads();
#pragma unroll
  for (int i = 0; i < 16; ++i) {
    int p = tq + i * 4;
    y[((i64)b * 4096 + p0 + p) * 384 + c0 + tp] = tile[tp][p];
  }
}

// depthwise 3x3 pad1, [n][c] bf16 in -> bf16 out; 4 channels x 4 pixels per thread.
__global__ __launch_bounds__(256) void dw8_kernel(const u16* __restrict__ in, int ldin,
                                                  const float* __restrict__ w,
                                                  const float* __restrict__ bias,
                                                  u16* __restrict__ out, int ldo, int CH) {
  int t = threadIdx.x;
  int g = t & 31;
  int s = t >> 5;
  int c0 = (blockIdx.y * 32 + g) * 4;
  if (c0 >= ldo) return;
  i64 p0 = (i64)blockIdx.x * 32 + s * 4;
  i64 pb = p0 & ~4095LL;
  int sp = (int)(p0 & 4095);
  int y = sp >> 6, x0 = sp & 63;
  float wv[9][4];
  float acc[4][4];
#pragma unroll
  for (int cc = 0; cc < 4; ++cc) {
    bool val = (c0 + cc) < CH;
    float bv = val ? bias[c0 + cc] : 0.f;
#pragma unroll
    for (int i = 0; i < 4; ++i) acc[i][cc] = bv;
#pragma unroll
    for (int j = 0; j < 9; ++j) wv[j][cc] = val ? w[(c0 + cc) * 9 + j] : 0.f;
  }
#pragma unroll
  for (int dy = 0; dy < 3; ++dy) {
    int yy = y - 1 + dy;
    if ((unsigned)yy >= 64u) continue;
    float row[6][4];
#pragma unroll
    for (int dx = 0; dx < 6; ++dx) {
      int xx = x0 - 1 + dx;
      if ((unsigned)xx < 64u) {
        ushort4 v = *(const ushort4*)(in + (pb + yy * 64 + xx) * ldin + c0);
        row[dx][0] = bf2f(v.x); row[dx][1] = bf2f(v.y);
        row[dx][2] = bf2f(v.z); row[dx][3] = bf2f(v.w);
      } else {
        row[dx][0] = 0.f; row[dx][1] = 0.f; row[dx][2] = 0.f; row[dx][3] = 0.f;
      }
    }
#pragma unroll
    for (int i = 0; i < 4; ++i)
#pragma unroll
      for (int dx = 0; dx < 3; ++dx)
#pragma unroll
        for (int cc = 0; cc < 4; ++cc)
          acc[i][cc] += row[i + dx][cc] * wv[dy * 3 + dx][cc];
  }
#pragma unroll
  for (int i = 0; i < 4; ++i) {
    ushort4 o;
    o.x = (c0 + 0 < CH) ? f2bf(acc[i][0]) : (u16)0;
    o.y = (c0 + 1 < CH) ? f2bf(acc[i][1]) : (u16)0;
    o.z = (c0 + 2 < CH) ? f2bf(acc[i][2]) : (u16)0;
    o.w = (c0 + 3 < CH) ? f2bf(acc[i][3]) : (u16)0;
    *(ushort4*)(out + (p0 + i) * ldo + c0) = o;
  }
}

// fused: depthwise 3x3 on q (computed in regs) + W-axis l2n + spm mult -> QS bf16;
// plane ssq for q and k (k read from kv buffer).
__global__ __launch_bounds__(192) void dwqnorm_kernel(
    const u16* __restrict__ qkv, const float* __restrict__ w9,
    const float* __restrict__ bias, const float* __restrict__ spm,
    const u16* __restrict__ kv, u16* __restrict__ QS,
    float* __restrict__ qssq, float* __restrict__ kssq) {
  int y = blockIdx.x;
  int b = blockIdx.y;
  int c = blockIdx.z * 192 + threadIdx.x;
  float wv[9];
#pragma unroll
  for (int j = 0; j < 9; ++j) wv[j] = w9[c * 9 + j];
  float bv = bias[c];
  float acc[64];
#pragma unroll
  for (int i = 0; i < 64; ++i) acc[i] = bv;
  i64 rowbase = (i64)b * 4096;
#pragma unroll
  for (int dy = 0; dy < 3; ++dy) {
    int yy = y - 1 + dy;
    if ((unsigned)yy >= 64u) continue;
    const u16* rp = qkv + (rowbase + yy * 64) * 1152 + c;
    float w0 = wv[dy * 3 + 0], w1 = wv[dy * 3 + 1], w2 = wv[dy * 3 + 2];
#pragma unroll
    for (int xi = 0; xi < 64; ++xi) {
      float v = bf2f(rp[(i64)xi * 1152]);
      if (xi > 0) acc[xi - 1] += v * w2;
      acc[xi] += v * w1;
      if (xi < 63) acc[xi + 1] += v * w0;
    }
  }
  float qs = 0.f;
#pragma unroll
  for (int i = 0; i < 64; ++i) qs += acc[i] * acc[i];
  float rw = 1.f / fmaxf(sqrtf(qs), 1e-12f);
  float ps = 0.f;
  const float* sp = spm + (i64)(y * 64) * 384 + c;
  u16* qp = QS + (rowbase + y * 64) * 384 + c;
#pragma unroll
  for (int i = 0; i < 64; ++i) {
    float u = acc[i] * rw * sp[(i64)i * 384];
    qp[(i64)i * 384] = f2bf(u);
    ps += u * u;
  }
  atomicAdd(&qssq[b * 384 + c], ps);
  float ks = 0.f;
  const u16* kp = kv + (rowbase + y * 64) * 768 + c;
#pragma unroll
  for (int i = 0; i < 64; ++i) {
    float kvv = bf2f(kp[(i64)i * 768]);
    ks += kvv * kvv;
  }
  atomicAdd(&kssq[b * 384 + c], ks);
}

// l2-normalize rows of 64
__global__ void l2row_kernel(const float* __restrict__ in, float* __restrict__ out) {
  int r = blockIdx.x;
  int lane = threadIdx.x;
  float v = in[r * 64 + lane];
  float ss = v * v;
  for (int o = 32; o > 0; o >>= 1) ss += __shfl_xor(ss, o);
  float n = fmaxf(sqrtf(ss), 1e-12f);
  out[r * 64 + lane] = v / n;
}

// conv 3x3, 3 -> 384 channels, output [p][384]
__global__ void spm_kernel(const float* __restrict__ s, const float* __restrict__ w,
                           const float* __restrict__ bias, float* __restrict__ out) {
  int idx = blockIdx.x * 256 + threadIdx.x;
  int c = idx % 384, p = idx / 384;
  int xc = p & 63, yr = p >> 6;
  const float* wp = w + c * 27;
  float acc = bias[c];
  for (int ic = 0; ic < 3; ++ic)
    for (int dy = -1; dy <= 1; ++dy) {
      int yy = yr + dy; if ((unsigned)yy >= 64u) continue;
      for (int dx = -1; dx <= 1; ++dx) {
        int xx = xc + dx; if ((unsigned)xx >= 64u) continue;
        acc += s[ic * 4096 + yy * 64 + xx] * wp[ic * 9 + (dy + 1) * 3 + (dx + 1)];
      }
    }
  out[idx] = acc;
}

// attn partials: attnP[bh][ksp][48][48] = sum_n QS[n][qc] * K[n][kc]
__global__ __launch_bounds__(256) void attnS_kernel(const u16* __restrict__ QS,
                                                    const u16* __restrict__ kv,
                                                    float* __restrict__ attnP) {
  int ksp = blockIdx.x;
  int bh = blockIdx.y;
  int b = bh >> 3, h = bh & 7;
  __shared__ float qsm[64][49];
  __shared__ float ksm[64][49];
  int t = threadIdx.x, tc = t & 15, td = t >> 4;
  float acc[3][3] = {{0.f}};
  for (int sub = 0; sub < 4; ++sub) {
    i64 nb = (i64)b * 4096 + ksp * 256 + sub * 64;
    __syncthreads();
    for (int l = t; l < 4096; l += 256) {
      int row = l >> 6, cq = l & 63;
      if (cq < 48) {
        qsm[row][cq] = bf2f(QS[(nb + row) * 384 + h * 48 + cq]);
        ksm[row][cq] = bf2f(kv[(nb + row) * 768 + h * 48 + cq]);
      }
    }
    __syncthreads();
#pragma unroll 4
    for (int nn = 0; nn < 64; ++nn) {
      float a0 = qsm[nn][tc], a1 = qsm[nn][tc + 16], a2 = qsm[nn][tc + 32];
      float b0 = ksm[nn][td], b1 = ksm[nn][td + 16], b2 = ksm[nn][td + 32];
      acc[0][0] += a0 * b0; acc[0][1] += a0 * b1; acc[0][2] += a0 * b2;
      acc[1][0] += a1 * b0; acc[1][1] += a1 * b1; acc[1][2] += a1 * b2;
      acc[2][0] += a2 * b0; acc[2][1] += a2 * b1; acc[2][2] += a2 * b2;
    }
  }
  float* ap = attnP + ((i64)bh * 16 + ksp) * 2304;
#pragma unroll
  for (int i = 0; i < 3; ++i)
#pragma unroll
    for (int j = 0; j < 3; ++j)
      ap[(tc + 16 * i) * HC + (td + 16 * j)] = acc[i][j];
}

// blend: fold plane-l2n of q (row) and k (col) + temperature, relu/top-k softmax mix
__global__ void blend_kernel(const float* __restrict__ attnP, const float* __restrict__ qssq,
                             const float* __restrict__ kssq, const float* __restrict__ temp,
                             const float* __restrict__ wmix, const float* __restrict__ pa1,
                             const float* __restrict__ pa2, const float* __restrict__ pa3,
                             const float* __restrict__ pa4, float* __restrict__ comb) {
  int row = blockIdx.x * 4 + (threadIdx.x >> 6);
  int lane = threadIdx.x & 63;
  int bh = row / 48, cc = row - bh * 48;
  int b = bh >> 3, h = bh & 7;
  float a;
  if (lane < 48) {
    const float* pp = attnP + ((i64)bh * 16) * 2304 + cc * 48 + lane;
    float s = 0.f;
#pragma unroll
    for (int sp = 0; sp < 16; ++sp) s += pp[(i64)sp * 2304];
    float qn = 1.f / fmaxf(sqrtf(qssq[b * 384 + h * 48 + cc]), 1e-12f);
    float kn = 1.f / fmaxf(sqrtf(kssq[b * 384 + h * 48 + lane]), 1e-12f);
    a = s * qn * kn * temp[h];
  } else {
    a = -INFINITY;
  }
  int rank = 0;
  for (int j = 0; j < 48; ++j) {
    float aj = __shfl(a, j);
    rank += (aj > a) ? 1 : 0;
  }
  float w0 = wmix[0], w1 = wmix[1];
  float wm = fmaxf(w0, w1);
  float e0 = expf(w0 - wm), e1 = expf(w1 - wm);
  float ws0 = e0 / (e0 + e1), ws1 = e1 / (e0 + e1);
  float c1 = pa1[0], c2 = pa2[0], c3 = pa3[0], c4 = pa4[0];
  float outv = ws0 * (c1 + c2 + c3 + c4) * fmaxf(a, 0.f);
  const int kks[4] = {24, 32, 36, 38};
  const float cs[4] = {c1, c2, c3, c4};
#pragma unroll
  for (int q = 0; q < 4; ++q) {
    float mv = (lane < 48) ? ((rank < kks[q]) ? a : a * 1e-6f) : -INFINITY;
    float mx = mv;
    for (int o = 32; o > 0; o >>= 1) mx = fmaxf(mx, __shfl_xor(mx, o));
    float e = (lane < 48) ? expf(mv - mx) : 0.f;
    float s = e;
    for (int o = 32; o > 0; o >>= 1) s += __shfl_xor(s, o);
    outv += ws1 * cs[q] * (e / s);
  }
  if (lane < 48) comb[(i64)row * 48 + lane] = outv;
}

// attn_out[n][c] = sum_d comb[b,h,cc,d] * V[n][384+h*48+d]  (V in kv bf16) -> bf16
__global__ __launch_bounds__(384) void combv_kernel(const u16* __restrict__ kv,
                                                    const float* __restrict__ comb,
                                                    u16* __restrict__ AO) {
  __shared__ float Vs[4][8][49];
  i64 p0 = (i64)blockIdx.x * 4;
  int b = (int)(p0 >> 12);
  int t = threadIdx.x;
  int h = t / 48, cc = t - h * 48;
#pragma unroll
  for (int px = 0; px < 4; ++px)
    Vs[px][h][cc] = bf2f(kv[(p0 + px) * 768 + 384 + t]);
  __syncthreads();
  float cr[48];
  const float* cp = comb + ((i64)(b * 8 + h) * 48 + cc) * 48;
#pragma unroll
  for (int d = 0; d < 48; d += 4) {
    float4 v = *(const float4*)(cp + d);
    cr[d] = v.x; cr[d + 1] = v.y; cr[d + 2] = v.z; cr[d + 3] = v.w;
  }
#pragma unroll
  for (int px = 0; px < 4; ++px) {
    float s = 0.f;
#pragma unroll
    for (int d = 0; d < 48; ++d) s += cr[d] * Vs[px][h][d];
    AO[(p0 + px) * 384 + t] = f2bf(s);
  }
}

// mat-vec (precompute)
__global__ void matvec_kernel(const float* __restrict__ Wm, int ldw, int koff,
                              const float* __restrict__ v, const float* __restrict__ add,
                              float* __restrict__ out, int K) {
  int ro = blockIdx.x;
  int t = threadIdx.x;
  const float* wp = Wm + (i64)ro * ldw + koff;
  float s = 0.f;
  for (int k = t; k < K; k += 256) s += wp[k] * v[k];
  __shared__ float sred[256];
  sred[t] = s;
  __syncthreads();
  for (int o = 128; o > 0; o >>= 1) {
    if (t < o) sred[t] += sred[t + o];
    __syncthreads();
  }
  if (t == 0) out[ro] = sred[0] + (add ? add[ro] : 0.f);
}

// 64x64 fp32 GEMM (weight-fold precompute only), split-K atomics
__global__ __launch_bounds__(256) void gemm64_kernel(
    const float* __restrict__ W, int ldw,
    const float* __restrict__ X,
    float* __restrict__ Y,
    int M, int N, int K, int ksplit) {
  int nt = blockIdx.x, mt = blockIdx.y;
  int ks = blockIdx.z;
  int kchunk = (((K + ksplit - 1) / ksplit) + 15) & ~15;
  int kbeg = ks * kchunk;
  int kend = min(K, kbeg + kchunk);
  __shared__ float As[16][68];
  __shared__ float Bs[16][68];
  int t = threadIdx.x, tx = t & 15, ty = t >> 4;
  int m0 = mt * 64, n0 = nt * 64;
  float acc[4][4];
#pragma unroll
  for (int i = 0; i < 4; ++i)
#pragma unroll
    for (int j = 0; j < 4; ++j) acc[i][j] = 0.f;
  for (int k0 = kbeg; k0 < kend; k0 += 16) {
    int kk = t & 15;
#pragma unroll
    for (int r = 0; r < 4; ++r) {
      int mm = (t >> 4) + r * 16;
      int gm = m0 + mm, gk = k0 + kk;
      As[kk][mm] = (gm < M && gk < kend) ? W[(i64)gm * ldw + gk] : 0.f;
    }
    int nn = t & 63;
#pragma unroll
    for (int r = 0; r < 4; ++r) {
      int k2 = (t >> 6) + r * 4;
      int gk = k0 + k2;
      Bs[k2][nn] = (gk < kend && n0 + nn < N) ? X[(i64)gk * N + n0 + nn] : 0.f;
    }
    __syncthreads();
#pragma unroll
    for (int kk3 = 0; kk3 < 16; ++kk3) {
      float4 av = *(const float4*)&As[kk3][ty * 4];
      float4 bv = *(const float4*)&Bs[kk3][tx * 4];
      float aa[4] = {av.x, av.y, av.z, av.w};
      float bb2[4] = {bv.x, bv.y, bv.z, bv.w};
#pragma unroll
      for (int i = 0; i < 4; ++i)
#pragma unroll
        for (int j = 0; j < 4; ++j) acc[i][j] += aa[i] * bb2[j];
    }
    __syncthreads();
  }
#pragma unroll
  for (int i = 0; i < 4; ++i) {
    int gm = m0 + ty * 4 + i;
    if (gm >= M || n0 + tx * 4 >= N) continue;
    for (int j = 0; j < 4; ++j) atomicAdd(&Y[(i64)gm * N + n0 + tx * 4 + j], acc[i][j]);
  }
}

// pack fp32 weight [M][ldw] (cols koff..koff+K) into MFMA fragment order
__global__ void pack_w_kernel(const float* __restrict__ W, int ldw, int koff, int M, int K,
                              int KS, u16* __restrict__ out, int nfrag) {
  int tid = blockIdx.x * 256 + threadIdx.x;
  int lane = tid & 63;
  int idx = tid >> 6;
  if (idx >= nfrag * KS) return;
  int ks = idx % KS, fm = idx / KS;
  int row = fm * 16 + (lane & 15);
  int kb = ks * 32 + (lane >> 4) * 8;
  union { u16 us[8]; uint4 q; } u;
#pragma unroll
  for (int j = 0; j < 8; ++j) {
    int k = kb + j;
    u.us[j] = (row < M && k < K) ? f2bf(W[(i64)row * ldw + koff + k]) : (u16)0;
  }
  *(uint4*)(out + (i64)idx * 512 + lane * 8) = u.q;
}

// ---------------- MFMA GEMM: (NF*16)n x 128m tile, BK=32, NF*32 threads ----------------
// epi 0: bias -> bf16 Yh[n][ldo]; epi 2: bias+gelu(v)*v -> bf16 Yh[n][ldo];
// epi 1: bias + Res(fp32 [b][c][p]) -> bf16 Yh[b][c][p]; epi 3: bias + Res(bf16) -> fp32 Yf[b][c][p]
template <int NF>
__global__ __launch_bounds__(NF * 32) void gemm_nk_kernel(
    const u16* __restrict__ A1, int lda1, int KS1, const u16* __restrict__ Wp1,
    const u16* __restrict__ A2, int lda2, int KS2, const u16* __restrict__ Wp2,
    int nfrag, const float* __restrict__ bias,
    const void* __restrict__ Res, float* __restrict__ Yf, u16* __restrict__ Yh,
    int ldo, int M, int epi) {
  __shared__ __align__(16) u16 Ls[2][NF + 8][512];
  int t = threadIdx.x, lane = t & 63, w = t >> 6;
  int wn = w >> 1, wm = w & 1;
  i64 n0 = (i64)blockIdx.x * (NF * 16);
  int mt = blockIdx.y;

  f32x4 acc[4][4];
#pragma unroll
  for (int i = 0; i < 4; ++i)
#pragma unroll
    for (int r = 0; r < 4; ++r) acc[i][r] = (f32x4){0.f, 0.f, 0.f, 0.f};

  auto stage = [&](int kt, int buf) {
    const u16* A; int lda; const u16* Wp; int KSc; int ks;
    if (kt < KS1) { A = A1; lda = lda1; Wp = Wp1; KSc = KS1; ks = kt; }
    else { A = A2; lda = lda2; Wp = Wp2; KSc = KS2; ks = kt - KS1; }
#pragma unroll
    for (int j = 0; j < 2; ++j) {
      int f = w * 2 + j;
      const u16* srcA = A + (n0 + f * 16 + (lane & 15)) * (i64)lda + ks * 32 + (lane >> 4) * 8;
      gld_lds16(srcA, &Ls[buf][f][0]);
    }
    if constexpr (NF == 8) {
#pragma unroll
      for (int j = 0; j < 2; ++j) {
        int f = w * 2 + j;
        int fmc = min(mt * 8 + f, nfrag - 1);
        gld_lds16(Wp + ((i64)fmc * KSc + ks) * 512 + lane * 8, &Ls[buf][NF + f][0]);
      }
    } else {
      int fmc = min(mt * 8 + w, nfrag - 1);
      gld_lds16(Wp + ((i64)fmc * KSc + ks) * 512 + lane * 8, &Ls[buf][NF + w][0]);
    }
  };

  int KT = KS1 + KS2;
  stage(0, 0);
  __syncthreads();
  int s = 0;
  for (int kt = 0; kt < KT; ++kt) {
    if (kt + 1 < KT) stage(kt + 1, s ^ 1);
    bf16x8 af[4], wf[4];
#pragma unroll
    for (int i = 0; i < 4; ++i) {
      af[i] = *reinterpret_cast<const bf16x8*>(&Ls[s][wn * 4 + i][lane * 8]);
      wf[i] = *reinterpret_cast<const bf16x8*>(&Ls[s][NF + wm * 4 + i][lane * 8]);
    }
#pragma unroll
    for (int i = 0; i < 4; ++i)
#pragma unroll
      for (int r = 0; r < 4; ++r)
        acc[i][r] = __builtin_amdgcn_mfma_f32_16x16x32_bf16(af[i], wf[r], acc[i][r], 0, 0, 0);
    __syncthreads();
    s ^= 1;
  }

#pragma unroll
  for (int i = 0; i < 4; ++i) {
    int nbase = (int)n0 + (wn * 4 + i) * 16 + ((lane >> 4) << 2);
#pragma unroll
    for (int r = 0; r < 4; ++r) {
      int m = mt * 128 + (wm * 4 + r) * 16 + (lane & 15);
      if (epi == 1 || epi == 3) {
        if (m < M) {
          float bv = bias[m];
          int b = nbase >> 12, p = nbase & 4095;
          i64 off = ((i64)b * DIMC + m) * 4096 + p;
          if (epi == 1) {
            float4 rv = *(const float4*)((const float*)Res + off);
            ushort4 o;
            o.x = f2bf(acc[i][r][0] + bv + rv.x);
            o.y = f2bf(acc[i][r][1] + bv + rv.y);
            o.z = f2bf(acc[i][r][2] + bv + rv.z);
            o.w = f2bf(acc[i][r][3] + bv + rv.w);
            *(ushort4*)(Yh + off) = o;
          } else {
            ushort4 rv = *(const ushort4*)((const u16*)Res + off);
            float4 o;
            o.x = acc[i][r][0] + bv + bf2f(rv.x);
            o.y = acc[i][r][1] + bv + bf2f(rv.y);
            o.z = acc[i][r][2] + bv + bf2f(rv.z);
            o.w = acc[i][r][3] + bv + bf2f(rv.w);
            *(float4*)(Yf + off) = o;
          }
        }
      } else {
        if (m < ldo) {
          float bv = (m < M) ? bias[m] : 0.f;
#pragma unroll
          for (int ii = 0; ii < 4; ++ii) {
            float v = acc[i][r][ii] + bv;
            if (epi == 2) {
              float gg = 0.5f * v * (1.f + erff(v * 0.70710678118f));
              v = gg * v;
            }
            if (m >= M) v = 0.f;
            Yh[(i64)(nbase + ii) * ldo + m] = f2bf(v);
          }
        }
      }
    }
  }
}

// ---------------- launch ----------------

extern "C" void kernel_launch(void* const* d_in, const int* in_sizes, int n_in,
                              void* d_out, int out_size, void* d_ws, size_t ws_size,
                              hipStream_t stream) {
  (void)in_sizes; (void)n_in; (void)out_size;
  const float* x       = (const float*)d_in[0];
  const float* spf     = (const float*)d_in[1];
  const float* ln1_w   = (const float*)d_in[2];
  const float* ln1_b   = (const float*)d_in[3];
  const float* qkv_w   = (const float*)d_in[4];
  const float* qkv_b   = (const float*)d_in[5];
  const float* qkvdw_w = (const float*)d_in[6];
  const float* qkvdw_b = (const float*)d_in[7];
  const float* proj_w  = (const float*)d_in[8];
  const float* proj_b  = (const float*)d_in[9];
  const float* temp    = (const float*)d_in[10];
  const float* a1      = (const float*)d_in[11];
  const float* a2      = (const float*)d_in[12];
  const float* a3      = (const float*)d_in[13];
  const float* a4      = (const float*)d_in[14];
  const float* wmix    = (const float*)d_in[15];
  const float* pout_w  = (const float*)d_in[16];
  const float* pout_b  = (const float*)d_in[17];
  const float* ln2_w   = (const float*)d_in[18];
  const float* ln2_b   = (const float*)d_in[19];
  const float* pin_w   = (const float*)d_in[20];
  const float* pin_b   = (const float*)d_in[21];
  const float* dw_w    = (const float*)d_in[22];
  const float* dw_b    = (const float*)d_in[23];
  const float* lin_w   = (const float*)d_in[24];
  const float* lin_b   = (const float*)d_in[25];
  const float* adj_w   = (const float*)d_in[26];
  const float* adj_b   = (const float*)d_in[27];
  const float* fout_w  = (const float*)d_in[28];
  const float* fout_b  = (const float*)d_in[29];
  float* out = (float*)d_out;
  float* ws = (float*)d_ws;

  const i64 PLANE = (i64)DIMC * HWN;  // 1,572,864
  const i64 FIXED = 5326592;
  const i64 PER = 8439808;
  int C = 8;
  while (C > 1 && (size_t)(FIXED + PER * C) * 4 > ws_size) C >>= 1;
  if ((size_t)(FIXED + PER * C) * 4 > ws_size) return;  // ws too small -> visible failure
  int nch = 8 / C;

  float* SPM   = ws;                          // [p][384] fp32
  float* W2v   = SPM + 1572864;
  float* W3v   = W2v + 392064;
  float* b2v   = W3v + 392064;
  float* b3v   = b2v + 1024;
  float* spfn  = b3v + 1024;
  float* mu1   = spfn + 12288;
  float* rs1   = mu1 + 32768;
  float* mu2   = rs1 + 32768;
  float* rs2   = mu2 + 32768;
  float* qssq  = rs2 + 32768;
  float* kssq  = qssq + 3072;
  float* packbase = kssq + 3072;
  u16* qkv_wp  = (u16*)packbase;              // 884736 u16
  u16* pout_wp = qkv_wp + 884736;             // 294912
  u16* pin_wp  = pout_wp + 294912;            // 786432
  u16* adj1_wp = pin_wp + 786432;             // 2097152
  u16* W3_wp   = adj1_wp + 2097152;           // 786432
  u16* fout_wp = W3_wp + 786432;              // 786432
  float* dyn   = packbase + 2818048;
  float* attnP = dyn;                          // C*294912
  float* comb  = attnP + (i64)C * 294912;      // C*18432
  float* R1    = comb + (i64)C * 18432;        // C*2359296 (qkv_bf / x1)
  float* R2    = R1 + (i64)C * 2359296;        // C*2097152 (kv / x1d)
  float* R3    = R2 + (i64)C * 2097152;        // C*2097152 (Xbf / QS / AO / fbf)
  float* R4    = R3 + (i64)C * 2097152;        // C*786432 (xatt bf16)
  float* R5    = R4 + (i64)C * 786432;         // C*786432 (xn2 bf16)

  // ---- precompute: folded weights W2 = lin@pin2, W3 = adj2@W2 ----
  zero_kernel<<<dim3(3063), dim3(256), 0, stream>>>(W2v, 784128);
  matvec_kernel<<<dim3(1021), dim3(256), 0, stream>>>(lin_w, 1021, 0, pin_b + 1021, lin_b, b2v, 1021);
  gemm64_kernel<<<dim3(6, 16, 8), dim3(256), 0, stream>>>(
      lin_w, 1021, pin_w + (i64)1021 * 384, W2v, 1021, 384, 1021, 8);
  matvec_kernel<<<dim3(1021), dim3(256), 0, stream>>>(adj_w, 2042, 1021, b2v, adj_b, b3v, 1021);
  gemm64_kernel<<<dim3(6, 16, 8), dim3(256), 0, stream>>>(
      adj_w + 1021, 2042, W2v, W3v, 1021, 384, 1021, 8);

  // ---- pack weights to MFMA fragment layout (bf16) ----
  pack_w_kernel<<<dim3(216), dim3(256), 0, stream>>>(qkv_w, 384, 0, 1152, 384, 12, qkv_wp, 72);
  pack_w_kernel<<<dim3(72), dim3(256), 0, stream>>>(pout_w, 384, 0, 384, 384, 12, pout_wp, 24);
  pack_w_kernel<<<dim3(192), dim3(256), 0, stream>>>(pin_w, 384, 0, 1021, 384, 12, pin_wp, 64);
  pack_w_kernel<<<dim3(512), dim3(256), 0, stream>>>(adj_w, 2042, 0, 1021, 1021, 32, adj1_wp, 64);
  pack_w_kernel<<<dim3(192), dim3(256), 0, stream>>>(W3v, 384, 0, 1021, 384, 12, W3_wp, 64);
  pack_w_kernel<<<dim3(192), dim3(256), 0, stream>>>(fout_w, 1021, 0, 384, 1021, 32, fout_wp, 24);

  // ---- shared precompute ----
  l2row_kernel<<<dim3(192), dim3(64), 0, stream>>>(spf, spfn);
  spm_kernel<<<dim3(6144), dim3(256), 0, stream>>>(spfn, proj_w, proj_b, SPM);
  stats_kernel<float><<<dim3(32), dim3(256), 0, stream>>>(x, mu1, rs1, 8192);

  for (int ch = 0; ch < nch; ++ch) {
    int b0 = ch * C;
    const float* xb = x + (i64)b0 * PLANE;
    float* outb = out + (i64)b0 * PLANE;
    const float* m1 = mu1 + (i64)b0 * HWN;
    const float* r1 = rs1 + (i64)b0 * HWN;

    u16* Xbf    = (u16*)R3;    // [n][384]
    u16* qkv_bf = (u16*)R1;    // [n][1152]
    u16* kvb    = (u16*)R2;    // [n][768] (k,v)
    u16* QS     = (u16*)R3;    // [n][384] (Xbf dead)
    u16* AO     = (u16*)R3;    // [n][384] (QS dead)
    u16* xatt   = (u16*)R4;    // [b][c][p] bf16
    u16* xn2    = (u16*)R5;    // [n][384]
    u16* x1     = (u16*)R1;    // [n][1024] (qkv_bf dead)
    u16* x1d    = (u16*)R2;    // [n][1024] (kv dead)
    u16* fbf    = (u16*)R3;    // [n][1024] (AO dead)

    int NB16 = C * 16;  // 256-wide n tiles
    int NB8  = C * 32;  // 128-wide n tiles

    // ---- attention ----
    zero_kernel<<<dim3((2 * C * 384 + 255) / 256), dim3(256), 0, stream>>>(qssq, 2 * C * 384);
    ln_t_kernel<float><<<dim3(64, 6, C), dim3(256), 0, stream>>>(xb, m1, r1, ln1_w, ln1_b, Xbf);
    gemm_nk_kernel<16><<<dim3(NB16, 9), dim3(512), 0, stream>>>(
        Xbf, 384, 12, qkv_wp, nullptr, 0, 0, nullptr, 72,
        qkv_b, nullptr, nullptr, qkv_bf, 1152, 1152, 0);
    dw8_kernel<<<dim3(C * 128, 6), dim3(256), 0, stream>>>(
        qkv_bf + 384, 1152, qkvdw_w + 384 * 9, qkvdw_b + 384, kvb, 768, 768);
    dwqnorm_kernel<<<dim3(64, C, 2), dim3(192), 0, stream>>>(
        qkv_bf, qkvdw_w, qkvdw_b, SPM, kvb, QS, qssq, kssq);
    attnS_kernel<<<dim3(16, C * 8), dim3(256), 0, stream>>>(QS, kvb, attnP);
    blend_kernel<<<dim3(96 * C), dim3(256), 0, stream>>>(attnP, qssq, kssq, temp, wmix,
                                                         a1, a2, a3, a4, comb);
    combv_kernel<<<dim3(C * 1024), dim3(384), 0, stream>>>(kvb, comb, AO);
    gemm_nk_kernel<8><<<dim3(NB8, 3), dim3(256), 0, stream>>>(
        AO, 384, 12, pout_wp, nullptr, 0, 0, nullptr, 24,
        pout_b, xb, nullptr, xatt, 0, 384, 1);

    // ---- feed-forward ----
    stats_kernel<u16><<<dim3((C * 1024 + 255) / 256), dim3(256), 0, stream>>>(xatt, mu2, rs2,
                                                                              C * 1024);
    ln_t_kernel<u16><<<dim3(64, 6, C), dim3(256), 0, stream>>>(xatt, mu2, rs2, ln2_w, ln2_b, xn2);
    gemm_nk_kernel<16><<<dim3(NB16, 8), dim3(512), 0, stream>>>(
        xn2, 384, 12, pin_wp, nullptr, 0, 0, nullptr, 64,
        pin_b, nullptr, nullptr, x1, 1024, 1021, 0);
    dw8_kernel<<<dim3(C * 128, 8), dim3(256), 0, stream>>>(
        x1, 1024, dw_w, dw_b, x1d, 1024, 1021);
    gemm_nk_kernel<16><<<dim3(NB16, 8), dim3(512), 0, stream>>>(
        x1d, 1024, 32, adj1_wp, xn2, 384, 12, W3_wp, 64,
        b3v, nullptr, nullptr, fbf, 1024, 1021, 2);
    gemm_nk_kernel<8><<<dim3(NB8, 3), dim3(256), 0, stream>>>(
        fbf, 1024, 32, fout_wp, nullptr, 0, 0, nullptr, 24,
        fout_b, xatt, outb, nullptr, 0, 384, 3);
  }
}

// Round 9
// 928.397 us; speedup vs baseline: 5.4437x; 1.1764x over previous
//
#include <hip/hip_runtime.h>
#include <math.h>

typedef long long i64;
typedef unsigned short u16;
typedef unsigned int u32;

#define DIMC 384
#define DIM3 1152
#define HC 48
#define HWN 4096

using bf16x8 = __attribute__((ext_vector_type(8))) short;
using f32x4 = __attribute__((ext_vector_type(4))) float;

__device__ __forceinline__ float bf2f(u16 u) { u32 x = ((u32)u) << 16; return __uint_as_float(x); }
__device__ __forceinline__ u16 f2bf(float f) {
  u32 u = __float_as_uint(f);
  u32 r = u + 0x7FFFu + ((u >> 16) & 1u);
  return (u16)(r >> 16);
}
__device__ __forceinline__ u16 to_bf16(float f) { return f2bf(f); }
__device__ __forceinline__ u16 to_bf16(u16 u) { return u; }
__device__ __forceinline__ float ld_as_f(const float* p) { return *p; }
__device__ __forceinline__ float ld_as_f(const u16* p) { return bf2f(*p); }

__device__ __forceinline__ void gld_lds16(const u16* g, u16* l) {
  __builtin_amdgcn_global_load_lds(
      (const __attribute__((address_space(1))) void*)g,
      (__attribute__((address_space(3))) void*)l, 16, 0, 0);
}

// ---------------- utility kernels ----------------

__global__ void zero_kernel(float* __restrict__ p, int n) {
  int i = blockIdx.x * 256 + threadIdx.x;
  if (i < n) p[i] = 0.f;
}

// fp32 [M rows, K cols, row-stride lds] -> bf16 [1024][1024], zero padded
__global__ void cvt_pad_kernel(const float* __restrict__ src, int lds, int M, int K,
                               u16* __restrict__ out) {
  int idx = blockIdx.x * 256 + threadIdx.x;  // 1024*1024
  int r = idx >> 10, k = idx & 1023;
  out[idx] = (r < M && k < K) ? f2bf(src[(i64)r * lds + k]) : (u16)0;
}

// per-pixel LayerNorm stats over C=384 channels ([b][c][p] layout), 4 px/thread
template <typename T>
__global__ void stats_kernel(const T* __restrict__ x, float* __restrict__ mu,
                             float* __restrict__ rs, int npix4) {
  int idx = blockIdx.x * 256 + threadIdx.x;
  if (idx >= npix4) return;
  int pg = idx * 4;
  int b = pg >> 12, p = pg & 4095;
  const T* xp = x + ((i64)b * DIMC) * HWN + p;
  float s0 = 0.f, s1 = 0.f, s2 = 0.f, s3 = 0.f;
  float q0 = 0.f, q1 = 0.f, q2 = 0.f, q3 = 0.f;
  for (int c = 0; c < DIMC; ++c) {
    const T* rp = xp + (i64)c * HWN;
    float v0 = ld_as_f(rp), v1 = ld_as_f(rp + 1), v2 = ld_as_f(rp + 2), v3 = ld_as_f(rp + 3);
    s0 += v0; s1 += v1; s2 += v2; s3 += v3;
    q0 += v0 * v0; q1 += v1 * v1; q2 += v2 * v2; q3 += v3 * v3;
  }
  const float inv = 1.f / DIMC;
  float4 m = make_float4(s0 * inv, s1 * inv, s2 * inv, s3 * inv);
  float4 r;
  r.x = rsqrtf(q0 * inv - m.x * m.x + 1e-5f);
  r.y = rsqrtf(q1 * inv - m.y * m.y + 1e-5f);
  r.z = rsqrtf(q2 * inv - m.z * m.z + 1e-5f);
  r.w = rsqrtf(q3 * inv - m.w * m.w + 1e-5f);
  *(float4*)(mu + (i64)pg) = m;
  *(float4*)(rs + (i64)pg) = r;
}

// LN apply + transpose [b][c][p] -> [n][384] bf16 (64x64 LDS tile)
template <typename T>
__global__ __launch_bounds__(256) void ln_t_kernel(
    const T* __restrict__ x, const float* __restrict__ mu, const float* __restrict__ rs,
    const float* __restrict__ g, const float* __restrict__ bb, u16* __restrict__ y) {
  __shared__ u16 tile[64][66];
  int p0 = blockIdx.x * 64, c0 = blockIdx.y * 64, b = blockIdx.z;
  int t = threadIdx.x;
  int tp = t & 63, tq = t >> 6;
  float m = mu[b * 4096 + p0 + tp], r = rs[b * 4096 + p0 + tp];
  const T* xp = x + (i64)b * DIMC * HWN + (i64)c0 * 4096 + p0;
#pragma unroll
  for (int i = 0; i < 16; ++i) {
    int c = tq + i * 4;
    float v = ld_as_f(xp + (i64)c * 4096 + tp);
    tile[c][tp] = f2bf((v - m) * r * g[c0 + c] + bb[c0 + c]);
  }
  __syncthreads();
#pragma unroll
  for (int i = 0; i < 16; ++i) {
    int p = tq + i * 4;
    y[((i64)b * 4096 + p0 + p) * 384 + c0 + tp] = tile[tp][p];
  }
}

// depthwise 3x3 pad1, [n][c] bf16 in -> bf16 out; 4 channels x 4 pixels per thread.
__global__ __launch_bounds__(256) void dw8_kernel(const u16* __restrict__ in, int ldin,
                                                  const float* __restrict__ w,
                                                  const float* __restrict__ bias,
                                                  u16* __restrict__ out, int ldo, int CH) {
  int t = threadIdx.x;
  int g = t & 31;
  int s = t >> 5;
  int c0 = (blockIdx.y * 32 + g) * 4;
  if (c0 >= ldo) return;
  i64 p0 = (i64)blockIdx.x * 32 + s * 4;
  i64 pb = p0 & ~4095LL;
  int sp = (int)(p0 & 4095);
  int y = sp >> 6, x0 = sp & 63;
  float wv[9][4];
  float acc[4][4];
#pragma unroll
  for (int cc = 0; cc < 4; ++cc) {
    bool val = (c0 + cc) < CH;
    float bv = val ? bias[c0 + cc] : 0.f;
#pragma unroll
    for (int i = 0; i < 4; ++i) acc[i][cc] = bv;
#pragma unroll
    for (int j = 0; j < 9; ++j) wv[j][cc] = val ? w[(c0 + cc) * 9 + j] : 0.f;
  }
#pragma unroll
  for (int dy = 0; dy < 3; ++dy) {
    int yy = y - 1 + dy;
    if ((unsigned)yy >= 64u) continue;
    float row[6][4];
#pragma unroll
    for (int dx = 0; dx < 6; ++dx) {
      int xx = x0 - 1 + dx;
      if ((unsigned)xx < 64u) {
        ushort4 v = *(const ushort4*)(in + (pb + yy * 64 + xx) * ldin + c0);
        row[dx][0] = bf2f(v.x); row[dx][1] = bf2f(v.y);
        row[dx][2] = bf2f(v.z); row[dx][3] = bf2f(v.w);
      } else {
        row[dx][0] = 0.f; row[dx][1] = 0.f; row[dx][2] = 0.f; row[dx][3] = 0.f;
      }
    }
#pragma unroll
    for (int i = 0; i < 4; ++i)
#pragma unroll
      for (int dx = 0; dx < 3; ++dx)
#pragma unroll
        for (int cc = 0; cc < 4; ++cc)
          acc[i][cc] += row[i + dx][cc] * wv[dy * 3 + dx][cc];
  }
#pragma unroll
  for (int i = 0; i < 4; ++i) {
    ushort4 o;
    o.x = (c0 + 0 < CH) ? f2bf(acc[i][0]) : (u16)0;
    o.y = (c0 + 1 < CH) ? f2bf(acc[i][1]) : (u16)0;
    o.z = (c0 + 2 < CH) ? f2bf(acc[i][2]) : (u16)0;
    o.w = (c0 + 3 < CH) ? f2bf(acc[i][3]) : (u16)0;
    *(ushort4*)(out + (p0 + i) * ldo + c0) = o;
  }
}

// fused: depthwise 3x3 on q (in regs) + W-axis l2n + spm mult -> QS bf16; plane ssq q,k.
__global__ __launch_bounds__(192) void dwqnorm_kernel(
    const u16* __restrict__ qkv, const float* __restrict__ w9,
    const float* __restrict__ bias, const float* __restrict__ spm,
    const u16* __restrict__ kv, u16* __restrict__ QS,
    float* __restrict__ qssq, float* __restrict__ kssq) {
  int y = blockIdx.x;
  int b = blockIdx.y;
  int c = blockIdx.z * 192 + threadIdx.x;
  float wv[9];
#pragma unroll
  for (int j = 0; j < 9; ++j) wv[j] = w9[c * 9 + j];
  float bv = bias[c];
  float acc[64];
#pragma unroll
  for (int i = 0; i < 64; ++i) acc[i] = bv;
  i64 rowbase = (i64)b * 4096;
#pragma unroll
  for (int dy = 0; dy < 3; ++dy) {
    int yy = y - 1 + dy;
    if ((unsigned)yy >= 64u) continue;
    const u16* rp = qkv + (rowbase + yy * 64) * 1152 + c;
    float w0 = wv[dy * 3 + 0], w1 = wv[dy * 3 + 1], w2 = wv[dy * 3 + 2];
#pragma unroll
    for (int xi = 0; xi < 64; ++xi) {
      float v = bf2f(rp[(i64)xi * 1152]);
      if (xi > 0) acc[xi - 1] += v * w2;
      acc[xi] += v * w1;
      if (xi < 63) acc[xi + 1] += v * w0;
    }
  }
  float qs = 0.f;
#pragma unroll
  for (int i = 0; i < 64; ++i) qs += acc[i] * acc[i];
  float rw = 1.f / fmaxf(sqrtf(qs), 1e-12f);
  float ps = 0.f;
  const float* sp = spm + (i64)(y * 64) * 384 + c;
  u16* qp = QS + (rowbase + y * 64) * 384 + c;
#pragma unroll
  for (int i = 0; i < 64; ++i) {
    float u = acc[i] * rw * sp[(i64)i * 384];
    qp[(i64)i * 384] = f2bf(u);
    ps += u * u;
  }
  atomicAdd(&qssq[b * 384 + c], ps);
  float ks = 0.f;
  const u16* kp = kv + (rowbase + y * 64) * 768 + c;
#pragma unroll
  for (int i = 0; i < 64; ++i) {
    float kvv = bf2f(kp[(i64)i * 768]);
    ks += kvv * kvv;
  }
  atomicAdd(&kssq[b * 384 + c], ks);
}

// l2-normalize rows of 64
__global__ void l2row_kernel(const float* __restrict__ in, float* __restrict__ out) {
  int r = blockIdx.x;
  int lane = threadIdx.x;
  float v = in[r * 64 + lane];
  float ss = v * v;
  for (int o = 32; o > 0; o >>= 1) ss += __shfl_xor(ss, o);
  float n = fmaxf(sqrtf(ss), 1e-12f);
  out[r * 64 + lane] = v / n;
}

// conv 3x3, 3 -> 384 channels, output [p][384]
__global__ void spm_kernel(const float* __restrict__ s, const float* __restrict__ w,
                           const float* __restrict__ bias, float* __restrict__ out) {
  int idx = blockIdx.x * 256 + threadIdx.x;
  int c = idx % 384, p = idx / 384;
  int xc = p & 63, yr = p >> 6;
  const float* wp = w + c * 27;
  float acc = bias[c];
  for (int ic = 0; ic < 3; ++ic)
    for (int dy = -1; dy <= 1; ++dy) {
      int yy = yr + dy; if ((unsigned)yy >= 64u) continue;
      for (int dx = -1; dx <= 1; ++dx) {
        int xx = xc + dx; if ((unsigned)xx >= 64u) continue;
        acc += s[ic * 4096 + yy * 64 + xx] * wp[ic * 9 + (dy + 1) * 3 + (dx + 1)];
      }
    }
  out[idx] = acc;
}

// attn partials: attnP[bh][ksp][48][48] = sum_n QS[n][qc] * K[n][kc]
__global__ __launch_bounds__(256) void attnS_kernel(const u16* __restrict__ QS,
                                                    const u16* __restrict__ kv,
                                                    float* __restrict__ attnP) {
  int ksp = blockIdx.x;
  int bh = blockIdx.y;
  int b = bh >> 3, h = bh & 7;
  __shared__ float qsm[64][49];
  __shared__ float ksm[64][49];
  int t = threadIdx.x, tc = t & 15, td = t >> 4;
  float acc[3][3] = {{0.f}};
  for (int sub = 0; sub < 4; ++sub) {
    i64 nb = (i64)b * 4096 + ksp * 256 + sub * 64;
    __syncthreads();
    for (int l = t; l < 4096; l += 256) {
      int row = l >> 6, cq = l & 63;
      if (cq < 48) {
        qsm[row][cq] = bf2f(QS[(nb + row) * 384 + h * 48 + cq]);
        ksm[row][cq] = bf2f(kv[(nb + row) * 768 + h * 48 + cq]);
      }
    }
    __syncthreads();
#pragma unroll 4
    for (int nn = 0; nn < 64; ++nn) {
      float a0 = qsm[nn][tc], a1 = qsm[nn][tc + 16], a2 = qsm[nn][tc + 32];
      float b0 = ksm[nn][td], b1 = ksm[nn][td + 16], b2 = ksm[nn][td + 32];
      acc[0][0] += a0 * b0; acc[0][1] += a0 * b1; acc[0][2] += a0 * b2;
      acc[1][0] += a1 * b0; acc[1][1] += a1 * b1; acc[1][2] += a1 * b2;
      acc[2][0] += a2 * b0; acc[2][1] += a2 * b1; acc[2][2] += a2 * b2;
    }
  }
  float* ap = attnP + ((i64)bh * 16 + ksp) * 2304;
#pragma unroll
  for (int i = 0; i < 3; ++i)
#pragma unroll
    for (int j = 0; j < 3; ++j)
      ap[(tc + 16 * i) * HC + (td + 16 * j)] = acc[i][j];
}

// blend: fold plane-l2n of q (row) and k (col) + temperature, relu/top-k softmax mix
__global__ void blend_kernel(const float* __restrict__ attnP, const float* __restrict__ qssq,
                             const float* __restrict__ kssq, const float* __restrict__ temp,
                             const float* __restrict__ wmix, const float* __restrict__ pa1,
                             const float* __restrict__ pa2, const float* __restrict__ pa3,
                             const float* __restrict__ pa4, float* __restrict__ comb) {
  int row = blockIdx.x * 4 + (threadIdx.x >> 6);
  int lane = threadIdx.x & 63;
  int bh = row / 48, cc = row - bh * 48;
  int b = bh >> 3, h = bh & 7;
  float a;
  if (lane < 48) {
    const float* pp = attnP + ((i64)bh * 16) * 2304 + cc * 48 + lane;
    float s = 0.f;
#pragma unroll
    for (int sp = 0; sp < 16; ++sp) s += pp[(i64)sp * 2304];
    float qn = 1.f / fmaxf(sqrtf(qssq[b * 384 + h * 48 + cc]), 1e-12f);
    float kn = 1.f / fmaxf(sqrtf(kssq[b * 384 + h * 48 + lane]), 1e-12f);
    a = s * qn * kn * temp[h];
  } else {
    a = -INFINITY;
  }
  int rank = 0;
  for (int j = 0; j < 48; ++j) {
    float aj = __shfl(a, j);
    rank += (aj > a) ? 1 : 0;
  }
  float w0 = wmix[0], w1 = wmix[1];
  float wm = fmaxf(w0, w1);
  float e0 = expf(w0 - wm), e1 = expf(w1 - wm);
  float ws0 = e0 / (e0 + e1), ws1 = e1 / (e0 + e1);
  float c1 = pa1[0], c2 = pa2[0], c3 = pa3[0], c4 = pa4[0];
  float outv = ws0 * (c1 + c2 + c3 + c4) * fmaxf(a, 0.f);
  const int kks[4] = {24, 32, 36, 38};
  const float cs[4] = {c1, c2, c3, c4};
#pragma unroll
  for (int q = 0; q < 4; ++q) {
    float mv = (lane < 48) ? ((rank < kks[q]) ? a : a * 1e-6f) : -INFINITY;
    float mx = mv;
    for (int o = 32; o > 0; o >>= 1) mx = fmaxf(mx, __shfl_xor(mx, o));
    float e = (lane < 48) ? expf(mv - mx) : 0.f;
    float s = e;
    for (int o = 32; o > 0; o >>= 1) s += __shfl_xor(s, o);
    outv += ws1 * cs[q] * (e / s);
  }
  if (lane < 48) comb[(i64)row * 48 + lane] = outv;
}

// attn_out[n][c] = sum_d comb[b,h,cc,d] * V[n][384+h*48+d]  (V in kv bf16) -> bf16
__global__ __launch_bounds__(384) void combv_kernel(const u16* __restrict__ kv,
                                                    const float* __restrict__ comb,
                                                    u16* __restrict__ AO) {
  __shared__ float Vs[4][8][49];
  i64 p0 = (i64)blockIdx.x * 4;
  int b = (int)(p0 >> 12);
  int t = threadIdx.x;
  int h = t / 48, cc = t - h * 48;
#pragma unroll
  for (int px = 0; px < 4; ++px)
    Vs[px][h][cc] = bf2f(kv[(p0 + px) * 768 + 384 + t]);
  __syncthreads();
  float cr[48];
  const float* cp = comb + ((i64)(b * 8 + h) * 48 + cc) * 48;
#pragma unroll
  for (int d = 0; d < 48; d += 4) {
    float4 v = *(const float4*)(cp + d);
    cr[d] = v.x; cr[d + 1] = v.y; cr[d + 2] = v.z; cr[d + 3] = v.w;
  }
#pragma unroll
  for (int px = 0; px < 4; ++px) {
    float s = 0.f;
#pragma unroll
    for (int d = 0; d < 48; ++d) s += cr[d] * Vs[px][h][d];
    AO[(p0 + px) * 384 + t] = f2bf(s);
  }
}

// mat-vec (precompute)
__global__ void matvec_kernel(const float* __restrict__ Wm, int ldw, int koff,
                              const float* __restrict__ v, const float* __restrict__ add,
                              float* __restrict__ out, int K) {
  int ro = blockIdx.x;
  int t = threadIdx.x;
  const float* wp = Wm + (i64)ro * ldw + koff;
  float s = 0.f;
  for (int k = t; k < K; k += 256) s += wp[k] * v[k];
  __shared__ float sred[256];
  sred[t] = s;
  __syncthreads();
  for (int o = 128; o > 0; o >>= 1) {
    if (t < o) sred[t] += sred[t + o];
    __syncthreads();
  }
  if (t == 0) out[ro] = sred[0] + (add ? add[ro] : 0.f);
}

// pack weight [M][ldw] (cols koff..koff+K) into MFMA fragment order (row-major src)
template <typename T>
__global__ void pack_w_kernel(const T* __restrict__ W, int ldw, int koff, int M, int K,
                              int KS, u16* __restrict__ out, int nfrag) {
  int tid = blockIdx.x * 256 + threadIdx.x;
  int lane = tid & 63;
  int idx = tid >> 6;
  if (idx >= nfrag * KS) return;
  int ks = idx % KS, fm = idx / KS;
  int row = fm * 16 + (lane & 15);
  int kb = ks * 32 + (lane >> 4) * 8;
  union { u16 us[8]; uint4 q; } u;
#pragma unroll
  for (int j = 0; j < 8; ++j) {
    int k = kb + j;
    u.us[j] = (row < M && k < K) ? to_bf16(W[(i64)row * ldw + koff + k]) : (u16)0;
  }
  *(uint4*)(out + (i64)idx * 512 + lane * 8) = u.q;
}

// pack TRANSPOSED weight: element (row, k) = src[(kbase + k) * ldk + row]
template <typename T>
__global__ void pack_wT_kernel(const T* __restrict__ src, int ldk, i64 kbase, int M, int K,
                               int KS, u16* __restrict__ out, int nfrag) {
  int tid = blockIdx.x * 256 + threadIdx.x;
  int lane = tid & 63;
  int idx = tid >> 6;
  if (idx >= nfrag * KS) return;
  int ks = idx % KS, fm = idx / KS;
  int row = fm * 16 + (lane & 15);
  int kb = ks * 32 + (lane >> 4) * 8;
  union { u16 us[8]; uint4 q; } u;
#pragma unroll
  for (int j = 0; j < 8; ++j) {
    int k = kb + j;
    u.us[j] = (row < M && k < K) ? to_bf16(src[(kbase + k) * (i64)ldk + row]) : (u16)0;
  }
  *(uint4*)(out + (i64)idx * 512 + lane * 8) = u.q;
}

// ---------------- MFMA GEMM: (NF*16)n x 128m tile, BK=32, NF*32 threads ----------------
// epi 0: bias -> bf16 Yh[n][ldo]; epi 2: bias+gelu(v)*v -> bf16 Yh[n][ldo];
// epi 1: bias + Res(fp32 [b][c][p]) -> bf16 Yh[b][c][p]; epi 3: bias + Res(bf16) -> fp32 Yf
template <int NF>
__global__ __launch_bounds__(NF * 32) void gemm_nk_kernel(
    const u16* __restrict__ A1, int lda1, int KS1, const u16* __restrict__ Wp1,
    const u16* __restrict__ A2, int lda2, int KS2, const u16* __restrict__ Wp2,
    int nfrag, const float* __restrict__ bias,
    const void* __restrict__ Res, float* __restrict__ Yf, u16* __restrict__ Yh,
    int ldo, int M, int epi) {
  __shared__ __align__(16) u16 Ls[2][NF + 8][512];
  int t = threadIdx.x, lane = t & 63, w = t >> 6;
  int wn = w >> 1, wm = w & 1;
  i64 n0 = (i64)blockIdx.x * (NF * 16);
  int mt = blockIdx.y;

  f32x4 acc[4][4];
#pragma unroll
  for (int i = 0; i < 4; ++i)
#pragma unroll
    for (int r = 0; r < 4; ++r) acc[i][r] = (f32x4){0.f, 0.f, 0.f, 0.f};

  auto stage = [&](int kt, int buf) {
    const u16* A; int lda; const u16* Wp; int KSc; int ks;
    if (kt < KS1) { A = A1; lda = lda1; Wp = Wp1; KSc = KS1; ks = kt; }
    else { A = A2; lda = lda2; Wp = Wp2; KSc = KS2; ks = kt - KS1; }
#pragma unroll
    for (int j = 0; j < 2; ++j) {
      int f = w * 2 + j;
      const u16* srcA = A + (n0 + f * 16 + (lane & 15)) * (i64)lda + ks * 32 + (lane >> 4) * 8;
      gld_lds16(srcA, &Ls[buf][f][0]);
    }
    if constexpr (NF == 8) {
#pragma unroll
      for (int j = 0; j < 2; ++j) {
        int f = w * 2 + j;
        int fmc = min(mt * 8 + f, nfrag - 1);
        gld_lds16(Wp + ((i64)fmc * KSc + ks) * 512 + lane * 8, &Ls[buf][NF + f][0]);
      }
    } else {
      int fmc = min(mt * 8 + w, nfrag - 1);
      gld_lds16(Wp + ((i64)fmc * KSc + ks) * 512 + lane * 8, &Ls[buf][NF + w][0]);
    }
  };

  int KT = KS1 + KS2;
  stage(0, 0);
  __syncthreads();
  int s = 0;
  for (int kt = 0; kt < KT; ++kt) {
    if (kt + 1 < KT) stage(kt + 1, s ^ 1);
    bf16x8 af[4], wf[4];
#pragma unroll
    for (int i = 0; i < 4; ++i) {
      af[i] = *reinterpret_cast<const bf16x8*>(&Ls[s][wn * 4 + i][lane * 8]);
      wf[i] = *reinterpret_cast<const bf16x8*>(&Ls[s][NF + wm * 4 + i][lane * 8]);
    }
#pragma unroll
    for (int i = 0; i < 4; ++i)
#pragma unroll
      for (int r = 0; r < 4; ++r)
        acc[i][r] = __builtin_amdgcn_mfma_f32_16x16x32_bf16(af[i], wf[r], acc[i][r], 0, 0, 0);
    __syncthreads();
    s ^= 1;
  }

#pragma unroll
  for (int i = 0; i < 4; ++i) {
    int nbase = (int)n0 + (wn * 4 + i) * 16 + ((lane >> 4) << 2);
#pragma unroll
    for (int r = 0; r < 4; ++r) {
      int m = mt * 128 + (wm * 4 + r) * 16 + (lane & 15);
      if (epi == 1 || epi == 3) {
        if (m < M) {
          float bv = bias[m];
          int b = nbase >> 12, p = nbase & 4095;
          i64 off = ((i64)b * DIMC + m) * 4096 + p;
          if (epi == 1) {
            float4 rv = *(const float4*)((const float*)Res + off);
            ushort4 o;
            o.x = f2bf(acc[i][r][0] + bv + rv.x);
            o.y = f2bf(acc[i][r][1] + bv + rv.y);
            o.z = f2bf(acc[i][r][2] + bv + rv.z);
            o.w = f2bf(acc[i][r][3] + bv + rv.w);
            *(ushort4*)(Yh + off) = o;
          } else {
            ushort4 rv = *(const ushort4*)((const u16*)Res + off);
            float4 o;
            o.x = acc[i][r][0] + bv + bf2f(rv.x);
            o.y = acc[i][r][1] + bv + bf2f(rv.y);
            o.z = acc[i][r][2] + bv + bf2f(rv.z);
            o.w = acc[i][r][3] + bv + bf2f(rv.w);
            *(float4*)(Yf + off) = o;
          }
        }
      } else {
        if (m < ldo) {
          float bv = (m < M) ? bias[m] : 0.f;
#pragma unroll
          for (int ii = 0; ii < 4; ++ii) {
            float v = acc[i][r][ii] + bv;
            if (epi == 2) {
              float gg = 0.5f * v * (1.f + erff(v * 0.70710678118f));
              v = gg * v;
            }
            if (m >= M) v = 0.f;
            Yh[(i64)(nbase + ii) * ldo + m] = f2bf(v);
          }
        }
      }
    }
  }
}

// ---------------- launch ----------------

extern "C" void kernel_launch(void* const* d_in, const int* in_sizes, int n_in,
                              void* d_out, int out_size, void* d_ws, size_t ws_size,
                              hipStream_t stream) {
  (void)in_sizes; (void)n_in; (void)out_size;
  const float* x       = (const float*)d_in[0];
  const float* spf     = (const float*)d_in[1];
  const float* ln1_w   = (const float*)d_in[2];
  const float* ln1_b   = (const float*)d_in[3];
  const float* qkv_w   = (const float*)d_in[4];
  const float* qkv_b   = (const float*)d_in[5];
  const float* qkvdw_w = (const float*)d_in[6];
  const float* qkvdw_b = (const float*)d_in[7];
  const float* proj_w  = (const float*)d_in[8];
  const float* proj_b  = (const float*)d_in[9];
  const float* temp    = (const float*)d_in[10];
  const float* a1      = (const float*)d_in[11];
  const float* a2      = (const float*)d_in[12];
  const float* a3      = (const float*)d_in[13];
  const float* a4      = (const float*)d_in[14];
  const float* wmix    = (const float*)d_in[15];
  const float* pout_w  = (const float*)d_in[16];
  const float* pout_b  = (const float*)d_in[17];
  const float* ln2_w   = (const float*)d_in[18];
  const float* ln2_b   = (const float*)d_in[19];
  const float* pin_w   = (const float*)d_in[20];
  const float* pin_b   = (const float*)d_in[21];
  const float* dw_w    = (const float*)d_in[22];
  const float* dw_b    = (const float*)d_in[23];
  const float* lin_w   = (const float*)d_in[24];
  const float* lin_b   = (const float*)d_in[25];
  const float* adj_w   = (const float*)d_in[26];
  const float* adj_b   = (const float*)d_in[27];
  const float* fout_w  = (const float*)d_in[28];
  const float* fout_b  = (const float*)d_in[29];
  float* out = (float*)d_out;
  float* ws = (float*)d_ws;

  const i64 PLANE = (i64)DIMC * HWN;  // 1,572,864
  const i64 FIXED = 4543488;
  const i64 PER = 6342656;
  int C = 8;
  while (C > 1 && (size_t)(FIXED + PER * C) * 4 > ws_size) C >>= 1;
  if ((size_t)(FIXED + PER * C) * 4 > ws_size) return;  // ws too small -> visible failure
  int nch = 8 / C;

  float* SPM   = ws;                          // 1572864
  float* b2v   = SPM + 1572864;               // 1024
  float* b3v   = b2v + 1024;                  // 1024
  float* zbias = b3v + 1024;                  // 1024
  float* spfn  = zbias + 1024;                // 12288
  float* mu1   = spfn + 12288;                // 32768
  float* rs1   = mu1 + 32768;
  float* mu2   = rs1 + 32768;
  float* rs2   = mu2 + 32768;
  float* qssq  = rs2 + 32768;                 // 3072
  float* kssq  = qssq + 3072;                 // 3072
  float* packbase = kssq + 3072;              // 2818048 fl of packed weights
  u16* qkv_wp  = (u16*)packbase;              // 884736 u16
  u16* pout_wp = qkv_wp + 884736;             // 294912
  u16* pin_wp  = pout_wp + 294912;            // 786432
  u16* adj1_wp = pin_wp + 786432;             // 2097152
  u16* W3_wp   = adj1_wp + 2097152;           // 786432
  u16* fout_wp = W3_wp + 786432;              // 786432
  float* dyn   = packbase + 2818048;

  // chunk arenas (floats)
  float* attnP = dyn;                          // C*294912
  float* comb  = attnP + (i64)C * 294912;      // C*18432
  float* RA    = comb + (i64)C * 18432;        // C*786432  (Xbf/QS/AO/xn2 bf16)
  float* RD    = RA + (i64)C * 786432;         // C*786432  (xatt bf16)
  float* RB    = RD + (i64)C * 786432;         // C*2359296 (qkv_bf/x1/fbf bf16)
  float* RC    = RB + (i64)C * 2359296;        // C*2097152 (kv/x1d bf16)

  // precompute temporaries (alias chunk arenas; dead before chunk loop starts)
  u16* linbf    = (u16*)dyn;                   // 1,048,576 u16
  u16* adjbf    = linbf + 1048576;             // 1,048,576
  u16* W2bf     = adjbf + 1048576;             // 393,216 ([1024][384])
  u16* W3bf     = W2bf + 393216;               // 393,216
  u16* pin2T_wp = W3bf + 393216;               // 393,216
  u16* W2T_wp   = pin2T_wp + 393216;           // 393,216

  // ---- precompute: folded weights via MFMA ----
  zero_kernel<<<dim3(4), dim3(256), 0, stream>>>(zbias, 1024);
  matvec_kernel<<<dim3(1021), dim3(256), 0, stream>>>(lin_w, 1021, 0, pin_b + 1021, lin_b, b2v, 1021);
  matvec_kernel<<<dim3(1021), dim3(256), 0, stream>>>(adj_w, 2042, 1021, b2v, adj_b, b3v, 1021);
  cvt_pad_kernel<<<dim3(4096), dim3(256), 0, stream>>>(lin_w, 1021, 1021, 1021, linbf);
  cvt_pad_kernel<<<dim3(4096), dim3(256), 0, stream>>>(adj_w + 1021, 2042, 1021, 1021, adjbf);
  pack_wT_kernel<float><<<dim3(192), dim3(256), 0, stream>>>(pin_w, 384, 1021, 384, 1021, 32,
                                                             pin2T_wp, 24);
  // W2 = lin @ pin2  -> bf16 [1024][384]
  gemm_nk_kernel<8><<<dim3(8, 3), dim3(256), 0, stream>>>(
      linbf, 1024, 32, pin2T_wp, nullptr, 0, 0, nullptr, 24,
      zbias, nullptr, nullptr, W2bf, 384, 384, 0);
  pack_wT_kernel<u16><<<dim3(192), dim3(256), 0, stream>>>(W2bf, 384, 0, 384, 1021, 32,
                                                           W2T_wp, 24);
  // W3 = adj2 @ W2  -> bf16 [1024][384]
  gemm_nk_kernel<8><<<dim3(8, 3), dim3(256), 0, stream>>>(
      adjbf, 1024, 32, W2T_wp, nullptr, 0, 0, nullptr, 24,
      zbias, nullptr, nullptr, W3bf, 384, 384, 0);
  pack_w_kernel<u16><<<dim3(192), dim3(256), 0, stream>>>(W3bf, 384, 0, 1021, 384, 12, W3_wp, 64);

  // ---- pack weights to MFMA fragment layout (bf16) ----
  pack_w_kernel<float><<<dim3(216), dim3(256), 0, stream>>>(qkv_w, 384, 0, 1152, 384, 12, qkv_wp, 72);
  pack_w_kernel<float><<<dim3(72), dim3(256), 0, stream>>>(pout_w, 384, 0, 384, 384, 12, pout_wp, 24);
  pack_w_kernel<float><<<dim3(192), dim3(256), 0, stream>>>(pin_w, 384, 0, 1021, 384, 12, pin_wp, 64);
  pack_w_kernel<float><<<dim3(512), dim3(256), 0, stream>>>(adj_w, 2042, 0, 1021, 1021, 32, adj1_wp, 64);
  pack_w_kernel<float><<<dim3(192), dim3(256), 0, stream>>>(fout_w, 1021, 0, 384, 1021, 32, fout_wp, 24);

  // ---- shared precompute ----
  l2row_kernel<<<dim3(192), dim3(64), 0, stream>>>(spf, spfn);
  spm_kernel<<<dim3(6144), dim3(256), 0, stream>>>(spfn, proj_w, proj_b, SPM);
  stats_kernel<float><<<dim3(32), dim3(256), 0, stream>>>(x, mu1, rs1, 8192);

  for (int ch = 0; ch < nch; ++ch) {
    int b0 = ch * C;
    const float* xb = x + (i64)b0 * PLANE;
    float* outb = out + (i64)b0 * PLANE;
    const float* m1 = mu1 + (i64)b0 * HWN;
    const float* r1 = rs1 + (i64)b0 * HWN;

    u16* Xbf    = (u16*)RA;    // [n][384]
    u16* qkv_bf = (u16*)RB;    // [n][1152]
    u16* kvb    = (u16*)RC;    // [n][768]
    u16* QS     = (u16*)RA;    // (Xbf dead)
    u16* AO     = (u16*)RA;    // (QS dead)
    u16* xatt   = (u16*)RD;    // [b][c][p] bf16
    u16* xn2    = (u16*)RA;    // (AO dead)
    u16* x1     = (u16*)RB;    // [n][1024] (qkv_bf dead)
    u16* x1d    = (u16*)RC;    // [n][1024] (kv dead)
    u16* fbf    = (u16*)RB;    // [n][1024] (x1 dead)

    int NB16 = C * 16;
    int NB8  = C * 32;

    // ---- attention ----
    zero_kernel<<<dim3((2 * C * 384 + 255) / 256), dim3(256), 0, stream>>>(qssq, 2 * C * 384);
    ln_t_kernel<float><<<dim3(64, 6, C), dim3(256), 0, stream>>>(xb, m1, r1, ln1_w, ln1_b, Xbf);
    gemm_nk_kernel<16><<<dim3(NB16, 9), dim3(512), 0, stream>>>(
        Xbf, 384, 12, qkv_wp, nullptr, 0, 0, nullptr, 72,
        qkv_b, nullptr, nullptr, qkv_bf, 1152, 1152, 0);
    dw8_kernel<<<dim3(C * 128, 6), dim3(256), 0, stream>>>(
        qkv_bf + 384, 1152, qkvdw_w + 384 * 9, qkvdw_b + 384, kvb, 768, 768);
    dwqnorm_kernel<<<dim3(64, C, 2), dim3(192), 0, stream>>>(
        qkv_bf, qkvdw_w, qkvdw_b, SPM, kvb, QS, qssq, kssq);
    attnS_kernel<<<dim3(16, C * 8), dim3(256), 0, stream>>>(QS, kvb, attnP);
    blend_kernel<<<dim3(96 * C), dim3(256), 0, stream>>>(attnP, qssq, kssq, temp, wmix,
                                                         a1, a2, a3, a4, comb);
    combv_kernel<<<dim3(C * 1024), dim3(384), 0, stream>>>(kvb, comb, AO);
    gemm_nk_kernel<8><<<dim3(NB8, 3), dim3(256), 0, stream>>>(
        AO, 384, 12, pout_wp, nullptr, 0, 0, nullptr, 24,
        pout_b, xb, nullptr, xatt, 0, 384, 1);

    // ---- feed-forward ----
    stats_kernel<u16><<<dim3((C * 1024 + 255) / 256), dim3(256), 0, stream>>>(xatt, mu2, rs2,
                                                                              C * 1024);
    ln_t_kernel<u16><<<dim3(64, 6, C), dim3(256), 0, stream>>>(xatt, mu2, rs2, ln2_w, ln2_b, xn2);
    gemm_nk_kernel<16><<<dim3(NB16, 8), dim3(512), 0, stream>>>(
        xn2, 384, 12, pin_wp, nullptr, 0, 0, nullptr, 64,
        pin_b, nullptr, nullptr, x1, 1024, 1021, 0);
    dw8_kernel<<<dim3(C * 128, 8), dim3(256), 0, stream>>>(
        x1, 1024, dw_w, dw_b, x1d, 1024, 1021);
    gemm_nk_kernel<16><<<dim3(NB16, 8), dim3(512), 0, stream>>>(
        x1d, 1024, 32, adj1_wp, xn2, 384, 12, W3_wp, 64,
        b3v, nullptr, nullptr, fbf, 1024, 1021, 2);
    gemm_nk_kernel<8><<<dim3(NB8, 3), dim3(256), 0, stream>>>(
        fbf, 1024, 32, fout_wp, nullptr, 0, 0, nullptr, 24,
        fout_b, xatt, outb, nullptr, 0, 384, 3);
  }
}

// Round 10
// 895.426 us; speedup vs baseline: 5.6441x; 1.0368x over previous
//
#include <hip/hip_runtime.h>
#include <math.h>

typedef long long i64;
typedef unsigned short u16;
typedef unsigned int u32;

#define DIMC 384
#define DIM3 1152
#define HC 48
#define HWN 4096

using bf16x8 = __attribute__((ext_vector_type(8))) short;
using f32x4 = __attribute__((ext_vector_type(4))) float;

__device__ __forceinline__ float bf2f(u16 u) { u32 x = ((u32)u) << 16; return __uint_as_float(x); }
__device__ __forceinline__ u16 f2bf(float f) {
  u32 u = __float_as_uint(f);
  u32 r = u + 0x7FFFu + ((u >> 16) & 1u);
  return (u16)(r >> 16);
}
__device__ __forceinline__ u16 to_bf16(float f) { return f2bf(f); }
__device__ __forceinline__ u16 to_bf16(u16 u) { return u; }
__device__ __forceinline__ float ld_as_f(const float* p) { return *p; }
__device__ __forceinline__ float ld_as_f(const u16* p) { return bf2f(*p); }

__device__ __forceinline__ void gld_lds16(const u16* g, u16* l) {
  __builtin_amdgcn_global_load_lds(
      (const __attribute__((address_space(1))) void*)g,
      (__attribute__((address_space(3))) void*)l, 16, 0, 0);
}

// ---------------- utility kernels ----------------

// fp32 [M rows, K cols, row-stride lds] -> bf16 [1024][1024], zero padded
__global__ void cvt_pad_kernel(const float* __restrict__ src, int lds, int M, int K,
                               u16* __restrict__ out) {
  int idx = blockIdx.x * 256 + threadIdx.x;  // 1024*1024
  int r = idx >> 10, k = idx & 1023;
  out[idx] = (r < M && k < K) ? f2bf(src[(i64)r * lds + k]) : (u16)0;
}

// per-pixel LayerNorm stats over C=384 channels ([b][c][p] layout), 4 px/thread
template <typename T>
__global__ void stats_kernel(const T* __restrict__ x, float* __restrict__ mu,
                             float* __restrict__ rs, int npix4) {
  int idx = blockIdx.x * 256 + threadIdx.x;
  if (idx >= npix4) return;
  int pg = idx * 4;
  int b = pg >> 12, p = pg & 4095;
  const T* xp = x + ((i64)b * DIMC) * HWN + p;
  float s0 = 0.f, s1 = 0.f, s2 = 0.f, s3 = 0.f;
  float q0 = 0.f, q1 = 0.f, q2 = 0.f, q3 = 0.f;
  for (int c = 0; c < DIMC; ++c) {
    const T* rp = xp + (i64)c * HWN;
    float v0 = ld_as_f(rp), v1 = ld_as_f(rp + 1), v2 = ld_as_f(rp + 2), v3 = ld_as_f(rp + 3);
    s0 += v0; s1 += v1; s2 += v2; s3 += v3;
    q0 += v0 * v0; q1 += v1 * v1; q2 += v2 * v2; q3 += v3 * v3;
  }
  const float inv = 1.f / DIMC;
  float4 m = make_float4(s0 * inv, s1 * inv, s2 * inv, s3 * inv);
  float4 r;
  r.x = rsqrtf(q0 * inv - m.x * m.x + 1e-5f);
  r.y = rsqrtf(q1 * inv - m.y * m.y + 1e-5f);
  r.z = rsqrtf(q2 * inv - m.z * m.z + 1e-5f);
  r.w = rsqrtf(q3 * inv - m.w * m.w + 1e-5f);
  *(float4*)(mu + (i64)pg) = m;
  *(float4*)(rs + (i64)pg) = r;
}

// LN apply + transpose [b][c][p] -> [n][384] bf16 (64x64 LDS tile)
template <typename T>
__global__ __launch_bounds__(256) void ln_t_kernel(
    const T* __restrict__ x, const float* __restrict__ mu, const float* __restrict__ rs,
    const float* __restrict__ g, const float* __restrict__ bb, u16* __restrict__ y) {
  __shared__ u16 tile[64][66];
  int p0 = blockIdx.x * 64, c0 = blockIdx.y * 64, b = blockIdx.z;
  int t = threadIdx.x;
  int tp = t & 63, tq = t >> 6;
  float m = mu[b * 4096 + p0 + tp], r = rs[b * 4096 + p0 + tp];
  const T* xp = x + (i64)b * DIMC * HWN + (i64)c0 * 4096 + p0;
#pragma unroll
  for (int i = 0; i < 16; ++i) {
    int c = tq + i * 4;
    float v = ld_as_f(xp + (i64)c * 4096 + tp);
    tile[c][tp] = f2bf((v - m) * r * g[c0 + c] + bb[c0 + c]);
  }
  __syncthreads();
#pragma unroll
  for (int i = 0; i < 16; ++i) {
    int p = tq + i * 4;
    y[((i64)b * 4096 + p0 + p) * 384 + c0 + tp] = tile[tp][p];
  }
}

// depthwise 3x3 pad1, [n][c] bf16 in -> bf16 out; 4 channels x 4 pixels per thread.
__global__ __launch_bounds__(256) void dw8_kernel(const u16* __restrict__ in, int ldin,
                                                  const float* __restrict__ w,
                                                  const float* __restrict__ bias,
                                                  u16* __restrict__ out, int ldo, int CH) {
  int t = threadIdx.x;
  int g = t & 31;
  int s = t >> 5;
  int c0 = (blockIdx.y * 32 + g) * 4;
  if (c0 >= ldo) return;
  i64 p0 = (i64)blockIdx.x * 32 + s * 4;
  i64 pb = p0 & ~4095LL;
  int sp = (int)(p0 & 4095);
  int y = sp >> 6, x0 = sp & 63;
  float wv[9][4];
  float acc[4][4];
#pragma unroll
  for (int cc = 0; cc < 4; ++cc) {
    bool val = (c0 + cc) < CH;
    float bv = val ? bias[c0 + cc] : 0.f;
#pragma unroll
    for (int i = 0; i < 4; ++i) acc[i][cc] = bv;
#pragma unroll
    for (int j = 0; j < 9; ++j) wv[j][cc] = val ? w[(c0 + cc) * 9 + j] : 0.f;
  }
#pragma unroll
  for (int dy = 0; dy < 3; ++dy) {
    int yy = y - 1 + dy;
    if ((unsigned)yy >= 64u) continue;
    float row[6][4];
#pragma unroll
    for (int dx = 0; dx < 6; ++dx) {
      int xx = x0 - 1 + dx;
      if ((unsigned)xx < 64u) {
        ushort4 v = *(const ushort4*)(in + (pb + yy * 64 + xx) * ldin + c0);
        row[dx][0] = bf2f(v.x); row[dx][1] = bf2f(v.y);
        row[dx][2] = bf2f(v.z); row[dx][3] = bf2f(v.w);
      } else {
        row[dx][0] = 0.f; row[dx][1] = 0.f; row[dx][2] = 0.f; row[dx][3] = 0.f;
      }
    }
#pragma unroll
    for (int i = 0; i < 4; ++i)
#pragma unroll
      for (int dx = 0; dx < 3; ++dx)
#pragma unroll
        for (int cc = 0; cc < 4; ++cc)
          acc[i][cc] += row[i + dx][cc] * wv[dy * 3 + dx][cc];
  }
#pragma unroll
  for (int i = 0; i < 4; ++i) {
    ushort4 o;
    o.x = (c0 + 0 < CH) ? f2bf(acc[i][0]) : (u16)0;
    o.y = (c0 + 1 < CH) ? f2bf(acc[i][1]) : (u16)0;
    o.z = (c0 + 2 < CH) ? f2bf(acc[i][2]) : (u16)0;
    o.w = (c0 + 3 < CH) ? f2bf(acc[i][3]) : (u16)0;
    *(ushort4*)(out + (p0 + i) * ldo + c0) = o;
  }
}

// fused: depthwise 3x3 on q (in regs, q in [n][384]) + W-axis l2n + spm mult -> QS bf16;
// plane ssq for q and k (k read from kv buffer).
__global__ __launch_bounds__(192) void dwqnorm_kernel(
    const u16* __restrict__ qraw, const float* __restrict__ w9,
    const float* __restrict__ bias, const float* __restrict__ spm,
    const u16* __restrict__ kv, u16* __restrict__ QS,
    float* __restrict__ qssq, float* __restrict__ kssq) {
  int y = blockIdx.x;
  int b = blockIdx.y;
  int c = blockIdx.z * 192 + threadIdx.x;
  float wv[9];
#pragma unroll
  for (int j = 0; j < 9; ++j) wv[j] = w9[c * 9 + j];
  float bv = bias[c];
  float acc[64];
#pragma unroll
  for (int i = 0; i < 64; ++i) acc[i] = bv;
  i64 rowbase = (i64)b * 4096;
#pragma unroll
  for (int dy = 0; dy < 3; ++dy) {
    int yy = y - 1 + dy;
    if ((unsigned)yy >= 64u) continue;
    const u16* rp = qraw + (rowbase + yy * 64) * 384 + c;
    float w0 = wv[dy * 3 + 0], w1 = wv[dy * 3 + 1], w2 = wv[dy * 3 + 2];
#pragma unroll
    for (int xi = 0; xi < 64; ++xi) {
      float v = bf2f(rp[(i64)xi * 384]);
      if (xi > 0) acc[xi - 1] += v * w2;
      acc[xi] += v * w1;
      if (xi < 63) acc[xi + 1] += v * w0;
    }
  }
  float qs = 0.f;
#pragma unroll
  for (int i = 0; i < 64; ++i) qs += acc[i] * acc[i];
  float rw = 1.f / fmaxf(sqrtf(qs), 1e-12f);
  float ps = 0.f;
  const float* sp = spm + (i64)(y * 64) * 384 + c;
  u16* qp = QS + (rowbase + y * 64) * 384 + c;
#pragma unroll
  for (int i = 0; i < 64; ++i) {
    float u = acc[i] * rw * sp[(i64)i * 384];
    qp[(i64)i * 384] = f2bf(u);
    ps += u * u;
  }
  atomicAdd(&qssq[b * 384 + c], ps);
  float ks = 0.f;
  const u16* kp = kv + (rowbase + y * 64) * 768 + c;
#pragma unroll
  for (int i = 0; i < 64; ++i) {
    float kvv = bf2f(kp[(i64)i * 768]);
    ks += kvv * kvv;
  }
  atomicAdd(&kssq[b * 384 + c], ks);
}

// l2-normalize rows of 64
__global__ void l2row_kernel(const float* __restrict__ in, float* __restrict__ out) {
  int r = blockIdx.x;
  int lane = threadIdx.x;
  float v = in[r * 64 + lane];
  float ss = v * v;
  for (int o = 32; o > 0; o >>= 1) ss += __shfl_xor(ss, o);
  float n = fmaxf(sqrtf(ss), 1e-12f);
  out[r * 64 + lane] = v / n;
}

// conv 3x3, 3 -> 384 channels, output [p][384]
__global__ void spm_kernel(const float* __restrict__ s, const float* __restrict__ w,
                           const float* __restrict__ bias, float* __restrict__ out) {
  int idx = blockIdx.x * 256 + threadIdx.x;
  int c = idx % 384, p = idx / 384;
  int xc = p & 63, yr = p >> 6;
  const float* wp = w + c * 27;
  float acc = bias[c];
  for (int ic = 0; ic < 3; ++ic)
    for (int dy = -1; dy <= 1; ++dy) {
      int yy = yr + dy; if ((unsigned)yy >= 64u) continue;
      for (int dx = -1; dx <= 1; ++dx) {
        int xx = xc + dx; if ((unsigned)xx >= 64u) continue;
        acc += s[ic * 4096 + yy * 64 + xx] * wp[ic * 9 + (dy + 1) * 3 + (dx + 1)];
      }
    }
  out[idx] = acc;
}

// attn partials: attnP[bh][ksp][48][48] = sum_n QS[n][qc] * K[n][kc]
__global__ __launch_bounds__(256) void attnS_kernel(const u16* __restrict__ QS,
                                                    const u16* __restrict__ kv,
                                                    float* __restrict__ attnP) {
  int ksp = blockIdx.x;
  int bh = blockIdx.y;
  int b = bh >> 3, h = bh & 7;
  __shared__ float qsm[64][49];
  __shared__ float ksm[64][49];
  int t = threadIdx.x, tc = t & 15, td = t >> 4;
  float acc[3][3] = {{0.f}};
  for (int sub = 0; sub < 4; ++sub) {
    i64 nb = (i64)b * 4096 + ksp * 256 + sub * 64;
    __syncthreads();
    for (int l = t; l < 4096; l += 256) {
      int row = l >> 6, cq = l & 63;
      if (cq < 48) {
        qsm[row][cq] = bf2f(QS[(nb + row) * 384 + h * 48 + cq]);
        ksm[row][cq] = bf2f(kv[(nb + row) * 768 + h * 48 + cq]);
      }
    }
    __syncthreads();
#pragma unroll 4
    for (int nn = 0; nn < 64; ++nn) {
      float a0 = qsm[nn][tc], a1 = qsm[nn][tc + 16], a2 = qsm[nn][tc + 32];
      float b0 = ksm[nn][td], b1 = ksm[nn][td + 16], b2 = ksm[nn][td + 32];
      acc[0][0] += a0 * b0; acc[0][1] += a0 * b1; acc[0][2] += a0 * b2;
      acc[1][0] += a1 * b0; acc[1][1] += a1 * b1; acc[1][2] += a1 * b2;
      acc[2][0] += a2 * b0; acc[2][1] += a2 * b1; acc[2][2] += a2 * b2;
    }
  }
  float* ap = attnP + ((i64)bh * 16 + ksp) * 2304;
#pragma unroll
  for (int i = 0; i < 3; ++i)
#pragma unroll
    for (int j = 0; j < 3; ++j)
      ap[(tc + 16 * i) * HC + (td + 16 * j)] = acc[i][j];
}

// blend: fold plane-l2n of q (row) and k (col) + temperature, relu/top-k softmax mix
__global__ void blend_kernel(const float* __restrict__ attnP, const float* __restrict__ qssq,
                             const float* __restrict__ kssq, const float* __restrict__ temp,
                             const float* __restrict__ wmix, const float* __restrict__ pa1,
                             const float* __restrict__ pa2, const float* __restrict__ pa3,
                             const float* __restrict__ pa4, float* __restrict__ comb) {
  int row = blockIdx.x * 4 + (threadIdx.x >> 6);
  int lane = threadIdx.x & 63;
  int bh = row / 48, cc = row - bh * 48;
  int b = bh >> 3, h = bh & 7;
  float a;
  if (lane < 48) {
    const float* pp = attnP + ((i64)bh * 16) * 2304 + cc * 48 + lane;
    float s = 0.f;
#pragma unroll
    for (int sp = 0; sp < 16; ++sp) s += pp[(i64)sp * 2304];
    float qn = 1.f / fmaxf(sqrtf(qssq[b * 384 + h * 48 + cc]), 1e-12f);
    float kn = 1.f / fmaxf(sqrtf(kssq[b * 384 + h * 48 + lane]), 1e-12f);
    a = s * qn * kn * temp[h];
  } else {
    a = -INFINITY;
  }
  int rank = 0;
  for (int j = 0; j < 48; ++j) {
    float aj = __shfl(a, j);
    rank += (aj > a) ? 1 : 0;
  }
  float w0 = wmix[0], w1 = wmix[1];
  float wm = fmaxf(w0, w1);
  float e0 = expf(w0 - wm), e1 = expf(w1 - wm);
  float ws0 = e0 / (e0 + e1), ws1 = e1 / (e0 + e1);
  float c1 = pa1[0], c2 = pa2[0], c3 = pa3[0], c4 = pa4[0];
  float outv = ws0 * (c1 + c2 + c3 + c4) * fmaxf(a, 0.f);
  const int kks[4] = {24, 32, 36, 38};
  const float cs[4] = {c1, c2, c3, c4};
#pragma unroll
  for (int q = 0; q < 4; ++q) {
    float mv = (lane < 48) ? ((rank < kks[q]) ? a : a * 1e-6f) : -INFINITY;
    float mx = mv;
    for (int o = 32; o > 0; o >>= 1) mx = fmaxf(mx, __shfl_xor(mx, o));
    float e = (lane < 48) ? expf(mv - mx) : 0.f;
    float s = e;
    for (int o = 32; o > 0; o >>= 1) s += __shfl_xor(s, o);
    outv += ws1 * cs[q] * (e / s);
  }
  if (lane < 48) comb[(i64)row * 48 + lane] = outv;
}

// attn_out[n][c] = sum_d comb[b,h,cc,d] * V[n][384+h*48+d]  (V in kv bf16) -> bf16
__global__ __launch_bounds__(384) void combv_kernel(const u16* __restrict__ kv,
                                                    const float* __restrict__ comb,
                                                    u16* __restrict__ AO) {
  __shared__ float Vs[4][8][49];
  i64 p0 = (i64)blockIdx.x * 4;
  int b = (int)(p0 >> 12);
  int t = threadIdx.x;
  int h = t / 48, cc = t - h * 48;
#pragma unroll
  for (int px = 0; px < 4; ++px)
    Vs[px][h][cc] = bf2f(kv[(p0 + px) * 768 + 384 + t]);
  __syncthreads();
  float cr[48];
  const float* cp = comb + ((i64)(b * 8 + h) * 48 + cc) * 48;
#pragma unroll
  for (int d = 0; d < 48; d += 4) {
    float4 v = *(const float4*)(cp + d);
    cr[d] = v.x; cr[d + 1] = v.y; cr[d + 2] = v.z; cr[d + 3] = v.w;
  }
#pragma unroll
  for (int px = 0; px < 4; ++px) {
    float s = 0.f;
#pragma unroll
    for (int d = 0; d < 48; ++d) s += cr[d] * Vs[px][h][d];
    AO[(p0 + px) * 384 + t] = f2bf(s);
  }
}

// mat-vec (precompute)
__global__ void matvec_kernel(const float* __restrict__ Wm, int ldw, int koff,
                              const float* __restrict__ v, const float* __restrict__ add,
                              float* __restrict__ out, int K) {
  int ro = blockIdx.x;
  int t = threadIdx.x;
  const float* wp = Wm + (i64)ro * ldw + koff;
  float s = 0.f;
  for (int k = t; k < K; k += 256) s += wp[k] * v[k];
  __shared__ float sred[256];
  sred[t] = s;
  __syncthreads();
  for (int o = 128; o > 0; o >>= 1) {
    if (t < o) sred[t] += sred[t + o];
    __syncthreads();
  }
  if (t == 0) out[ro] = sred[0] + (add ? add[ro] : 0.f);
}

// pack weight [M][ldw] (cols koff..koff+K) into MFMA fragment order (row-major src)
template <typename T>
__global__ void pack_w_kernel(const T* __restrict__ W, int ldw, int koff, int M, int K,
                              int KS, u16* __restrict__ out, int nfrag) {
  int tid = blockIdx.x * 256 + threadIdx.x;
  int lane = tid & 63;
  int idx = tid >> 6;
  if (idx >= nfrag * KS) return;
  int ks = idx % KS, fm = idx / KS;
  int row = fm * 16 + (lane & 15);
  int kb = ks * 32 + (lane >> 4) * 8;
  union { u16 us[8]; uint4 q; } u;
#pragma unroll
  for (int j = 0; j < 8; ++j) {
    int k = kb + j;
    u.us[j] = (row < M && k < K) ? to_bf16(W[(i64)row * ldw + koff + k]) : (u16)0;
  }
  *(uint4*)(out + (i64)idx * 512 + lane * 8) = u.q;
}

// pack TRANSPOSED weight: element (row, k) = src[(kbase + k) * ldk + row]
template <typename T>
__global__ void pack_wT_kernel(const T* __restrict__ src, int ldk, i64 kbase, int M, int K,
                               int KS, u16* __restrict__ out, int nfrag) {
  int tid = blockIdx.x * 256 + threadIdx.x;
  int lane = tid & 63;
  int idx = tid >> 6;
  if (idx >= nfrag * KS) return;
  int ks = idx % KS, fm = idx / KS;
  int row = fm * 16 + (lane & 15);
  int kb = ks * 32 + (lane >> 4) * 8;
  union { u16 us[8]; uint4 q; } u;
#pragma unroll
  for (int j = 0; j < 8; ++j) {
    int k = kb + j;
    u.us[j] = (row < M && k < K) ? to_bf16(src[(kbase + k) * (i64)ldk + row]) : (u16)0;
  }
  *(uint4*)(out + (i64)idx * 512 + lane * 8) = u.q;
}

// ---------------- MFMA GEMM: (NF*16)n x 128m tile, BK=32, NF*32 threads ----------------
// SWAP=true (epi 0/2): operandi swapped -> m contiguous per thread -> ushort4 stores to
//   Yh[n][ldo] (m < msplit) or Yh2[n][ld2] (m >= msplit, offset by msplit).
// SWAP=false: epi 1 (bias + fp32 Res [b][c][p] -> bf16 Yh), epi 3 (bias + bf16 Res -> fp32 Yf).
template <int NF, bool SWAP>
__global__ __launch_bounds__(NF * 32) void gemm_nk_kernel(
    const u16* __restrict__ A1, int lda1, int KS1, const u16* __restrict__ Wp1,
    const u16* __restrict__ A2, int lda2, int KS2, const u16* __restrict__ Wp2,
    int nfrag, const float* __restrict__ bias,
    const void* __restrict__ Res, float* __restrict__ Yf, u16* __restrict__ Yh,
    int ldo, int msplit, u16* __restrict__ Yh2, int ld2,
    int M, int epi) {
  __shared__ __align__(16) u16 Ls[2][NF + 8][512];
  int t = threadIdx.x, lane = t & 63, w = t >> 6;
  int wn = w >> 1, wm = w & 1;
  i64 n0 = (i64)blockIdx.x * (NF * 16);
  int mt = blockIdx.y;

  f32x4 acc[4][4];
#pragma unroll
  for (int i = 0; i < 4; ++i)
#pragma unroll
    for (int r = 0; r < 4; ++r) acc[i][r] = (f32x4){0.f, 0.f, 0.f, 0.f};

  auto stage = [&](int kt, int buf) {
    const u16* A; int lda; const u16* Wp; int KSc; int ks;
    if (kt < KS1) { A = A1; lda = lda1; Wp = Wp1; KSc = KS1; ks = kt; }
    else { A = A2; lda = lda2; Wp = Wp2; KSc = KS2; ks = kt - KS1; }
#pragma unroll
    for (int j = 0; j < 2; ++j) {
      int f = w * 2 + j;
      const u16* srcA = A + (n0 + f * 16 + (lane & 15)) * (i64)lda + ks * 32 + (lane >> 4) * 8;
      gld_lds16(srcA, &Ls[buf][f][0]);
    }
    if constexpr (NF == 8) {
#pragma unroll
      for (int j = 0; j < 2; ++j) {
        int f = w * 2 + j;
        int fmc = min(mt * 8 + f, nfrag - 1);
        gld_lds16(Wp + ((i64)fmc * KSc + ks) * 512 + lane * 8, &Ls[buf][NF + f][0]);
      }
    } else {
      int fmc = min(mt * 8 + w, nfrag - 1);
      gld_lds16(Wp + ((i64)fmc * KSc + ks) * 512 + lane * 8, &Ls[buf][NF + w][0]);
    }
  };

  int KT = KS1 + KS2;
  stage(0, 0);
  __syncthreads();
  int s = 0;
  for (int kt = 0; kt < KT; ++kt) {
    if (kt + 1 < KT) stage(kt + 1, s ^ 1);
    bf16x8 af[4], wf[4];
#pragma unroll
    for (int i = 0; i < 4; ++i) {
      af[i] = *reinterpret_cast<const bf16x8*>(&Ls[s][wn * 4 + i][lane * 8]);
      wf[i] = *reinterpret_cast<const bf16x8*>(&Ls[s][NF + wm * 4 + i][lane * 8]);
    }
#pragma unroll
    for (int i = 0; i < 4; ++i)
#pragma unroll
      for (int r = 0; r < 4; ++r) {
        if constexpr (SWAP)
          acc[i][r] = __builtin_amdgcn_mfma_f32_16x16x32_bf16(wf[r], af[i], acc[i][r], 0, 0, 0);
        else
          acc[i][r] = __builtin_amdgcn_mfma_f32_16x16x32_bf16(af[i], wf[r], acc[i][r], 0, 0, 0);
      }
    __syncthreads();
    s ^= 1;
  }

  if constexpr (SWAP) {
    // output: n = lane&15 (per n-frag i), m = 4 contiguous per thread (per m-frag r)
#pragma unroll
    for (int i = 0; i < 4; ++i) {
      i64 n = n0 + (wn * 4 + i) * 16 + (lane & 15);
#pragma unroll
      for (int r = 0; r < 4; ++r) {
        int m4 = mt * 128 + (wm * 4 + r) * 16 + ((lane >> 4) << 2);
        float4 bv = *(const float4*)(bias + m4);
        float v0 = acc[i][r][0] + bv.x;
        float v1 = acc[i][r][1] + bv.y;
        float v2 = acc[i][r][2] + bv.z;
        float v3 = acc[i][r][3] + bv.w;
        if (epi == 2) {
          float g0 = 0.5f * v0 * (1.f + erff(v0 * 0.70710678118f));
          float g1 = 0.5f * v1 * (1.f + erff(v1 * 0.70710678118f));
          float g2 = 0.5f * v2 * (1.f + erff(v2 * 0.70710678118f));
          float g3 = 0.5f * v3 * (1.f + erff(v3 * 0.70710678118f));
          v0 *= g0; v1 *= g1; v2 *= g2; v3 *= g3;
        }
        ushort4 o;
        o.x = f2bf(v0); o.y = f2bf(v1); o.z = f2bf(v2); o.w = f2bf(v3);
        u16* dst = (m4 < msplit) ? (Yh + n * (i64)ldo + m4)
                                 : (Yh2 + n * (i64)ld2 + (m4 - msplit));
        *(ushort4*)dst = o;
      }
    }
  } else {
#pragma unroll
    for (int i = 0; i < 4; ++i) {
      int nbase = (int)n0 + (wn * 4 + i) * 16 + ((lane >> 4) << 2);
#pragma unroll
      for (int r = 0; r < 4; ++r) {
        int m = mt * 128 + (wm * 4 + r) * 16 + (lane & 15);
        if (m < M) {
          float bv = bias[m];
          int b = nbase >> 12, p = nbase & 4095;
          i64 off = ((i64)b * DIMC + m) * 4096 + p;
          if (epi == 1) {
            float4 rv = *(const float4*)((const float*)Res + off);
            ushort4 o;
            o.x = f2bf(acc[i][r][0] + bv + rv.x);
            o.y = f2bf(acc[i][r][1] + bv + rv.y);
            o.z = f2bf(acc[i][r][2] + bv + rv.z);
            o.w = f2bf(acc[i][r][3] + bv + rv.w);
            *(ushort4*)(Yh + off) = o;
          } else {
            ushort4 rv = *(const ushort4*)((const u16*)Res + off);
            float4 o;
            o.x = acc[i][r][0] + bv + bf2f(rv.x);
            o.y = acc[i][r][1] + bv + bf2f(rv.y);
            o.z = acc[i][r][2] + bv + bf2f(rv.z);
            o.w = acc[i][r][3] + bv + bf2f(rv.w);
            *(float4*)(Yf + off) = o;
          }
        }
      }
    }
  }
}

// ---------------- launch ----------------

extern "C" void kernel_launch(void* const* d_in, const int* in_sizes, int n_in,
                              void* d_out, int out_size, void* d_ws, size_t ws_size,
                              hipStream_t stream) {
  (void)in_sizes; (void)n_in; (void)out_size;
  const float* x       = (const float*)d_in[0];
  const float* spf     = (const float*)d_in[1];
  const float* ln1_w   = (const float*)d_in[2];
  const float* ln1_b   = (const float*)d_in[3];
  const float* qkv_w   = (const float*)d_in[4];
  const float* qkv_b   = (const float*)d_in[5];
  const float* qkvdw_w = (const float*)d_in[6];
  const float* qkvdw_b = (const float*)d_in[7];
  const float* proj_w  = (const float*)d_in[8];
  const float* proj_b  = (const float*)d_in[9];
  const float* temp    = (const float*)d_in[10];
  const float* a1      = (const float*)d_in[11];
  const float* a2      = (const float*)d_in[12];
  const float* a3      = (const float*)d_in[13];
  const float* a4      = (const float*)d_in[14];
  const float* wmix    = (const float*)d_in[15];
  const float* pout_w  = (const float*)d_in[16];
  const float* pout_b  = (const float*)d_in[17];
  const float* ln2_w   = (const float*)d_in[18];
  const float* ln2_b   = (const float*)d_in[19];
  const float* pin_w   = (const float*)d_in[20];
  const float* pin_b   = (const float*)d_in[21];
  const float* dw_w    = (const float*)d_in[22];
  const float* dw_b    = (const float*)d_in[23];
  const float* lin_w   = (const float*)d_in[24];
  const float* lin_b   = (const float*)d_in[25];
  const float* adj_w   = (const float*)d_in[26];
  const float* adj_b   = (const float*)d_in[27];
  const float* fout_w  = (const float*)d_in[28];
  const float* fout_b  = (const float*)d_in[29];
  float* out = (float*)d_out;
  float* ws = (float*)d_ws;

  const i64 PLANE = (i64)DIMC * HWN;  // 1,572,864
  const i64 FIXED = 4543488;
  const i64 PER = 6342656;
  int C = 8;
  while (C > 1 && (size_t)(FIXED + PER * C) * 4 > ws_size) C >>= 1;
  if ((size_t)(FIXED + PER * C) * 4 > ws_size) return;  // ws too small -> visible failure
  int nch = 8 / C;

  float* SPM   = ws;                          // 1572864
  float* b2v   = SPM + 1572864;               // 1024
  float* b3v   = b2v + 1024;                  // 1024
  float* zbias = b3v + 1024;                  // 1024
  float* spfn  = zbias + 1024;                // 12288
  float* mu1   = spfn + 12288;                // 32768
  float* rs1   = mu1 + 32768;
  float* mu2   = rs1 + 32768;
  float* rs2   = mu2 + 32768;
  float* qssq  = rs2 + 32768;                 // 3072
  float* kssq  = qssq + 3072;                 // 3072
  float* packbase = kssq + 3072;
  u16* qkv_wp  = (u16*)packbase;              // 884736 u16
  u16* pout_wp = qkv_wp + 884736;             // 294912
  u16* pin_wp  = pout_wp + 294912;            // 786432
  u16* adj1_wp = pin_wp + 786432;             // 2097152
  u16* W3_wp   = adj1_wp + 2097152;           // 786432
  u16* fout_wp = W3_wp + 786432;              // 786432
  float* dyn   = packbase + 2818048;

  // chunk arenas (floats)
  float* attnP = dyn;                          // C*294912
  float* comb  = attnP + (i64)C * 294912;      // C*18432
  float* RA    = comb + (i64)C * 18432;        // C*786432  (Xbf/QS/AO/xn2 bf16)
  float* RD    = RA + (i64)C * 786432;         // C*786432  (xatt bf16)
  float* RB    = RD + (i64)C * 786432;         // C*2359296 (qraw+kvraw / x1 / fbf bf16)
  float* RC    = RB + (i64)C * 2359296;        // C*2097152 (kv / x1d bf16)

  // precompute temporaries (alias chunk arenas; dead before chunk loop starts)
  u16* linbf    = (u16*)dyn;                   // 1,048,576 u16
  u16* adjbf    = linbf + 1048576;             // 1,048,576
  u16* W2bf     = adjbf + 1048576;             // 393,216 ([1024][384])
  u16* W3bf     = W2bf + 393216;               // 393,216
  u16* pin2T_wp = W3bf + 393216;               // 393,216
  u16* W2T_wp   = pin2T_wp + 393216;           // 393,216

  // ---- precompute: folded weights via MFMA ----
  hipMemsetAsync(b2v, 0, 3 * 1024 * sizeof(float), stream);  // b2v, b3v, zbias
  matvec_kernel<<<dim3(1021), dim3(256), 0, stream>>>(lin_w, 1021, 0, pin_b + 1021, lin_b, b2v, 1021);
  matvec_kernel<<<dim3(1021), dim3(256), 0, stream>>>(adj_w, 2042, 1021, b2v, adj_b, b3v, 1021);
  cvt_pad_kernel<<<dim3(4096), dim3(256), 0, stream>>>(lin_w, 1021, 1021, 1021, linbf);
  cvt_pad_kernel<<<dim3(4096), dim3(256), 0, stream>>>(adj_w + 1021, 2042, 1021, 1021, adjbf);
  pack_wT_kernel<float><<<dim3(192), dim3(256), 0, stream>>>(pin_w, 384, 1021, 384, 1021, 32,
                                                             pin2T_wp, 24);
  // W2 = lin @ pin2  -> bf16 [1024][384]
  gemm_nk_kernel<8, true><<<dim3(8, 3), dim3(256), 0, stream>>>(
      linbf, 1024, 32, pin2T_wp, nullptr, 0, 0, nullptr, 24,
      zbias, nullptr, nullptr, W2bf, 384, 1 << 30, nullptr, 0, 384, 0);
  pack_wT_kernel<u16><<<dim3(192), dim3(256), 0, stream>>>(W2bf, 384, 0, 384, 1021, 32,
                                                           W2T_wp, 24);
  // W3 = adj2 @ W2  -> bf16 [1024][384]
  gemm_nk_kernel<8, true><<<dim3(8, 3), dim3(256), 0, stream>>>(
      adjbf, 1024, 32, W2T_wp, nullptr, 0, 0, nullptr, 24,
      zbias, nullptr, nullptr, W3bf, 384, 1 << 30, nullptr, 0, 384, 0);
  pack_w_kernel<u16><<<dim3(192), dim3(256), 0, stream>>>(W3bf, 384, 0, 1021, 384, 12, W3_wp, 64);

  // ---- pack weights to MFMA fragment layout (bf16) ----
  pack_w_kernel<float><<<dim3(216), dim3(256), 0, stream>>>(qkv_w, 384, 0, 1152, 384, 12, qkv_wp, 72);
  pack_w_kernel<float><<<dim3(72), dim3(256), 0, stream>>>(pout_w, 384, 0, 384, 384, 12, pout_wp, 24);
  pack_w_kernel<float><<<dim3(192), dim3(256), 0, stream>>>(pin_w, 384, 0, 1021, 384, 12, pin_wp, 64);
  pack_w_kernel<float><<<dim3(512), dim3(256), 0, stream>>>(adj_w, 2042, 0, 1021, 1021, 32, adj1_wp, 64);
  pack_w_kernel<float><<<dim3(192), dim3(256), 0, stream>>>(fout_w, 1021, 0, 384, 1021, 32, fout_wp, 24);

  // ---- shared precompute ----
  l2row_kernel<<<dim3(192), dim3(64), 0, stream>>>(spf, spfn);
  spm_kernel<<<dim3(6144), dim3(256), 0, stream>>>(spfn, proj_w, proj_b, SPM);
  stats_kernel<float><<<dim3(32), dim3(256), 0, stream>>>(x, mu1, rs1, 8192);

  for (int ch = 0; ch < nch; ++ch) {
    int b0 = ch * C;
    const float* xb = x + (i64)b0 * PLANE;
    float* outb = out + (i64)b0 * PLANE;
    const float* m1 = mu1 + (i64)b0 * HWN;
    const float* r1 = rs1 + (i64)b0 * HWN;

    i64 NTOT = (i64)C * 4096;
    u16* Xbf   = (u16*)RA;                 // [n][384]
    u16* qraw  = (u16*)RB;                 // [n][384] (q pre-dw)
    u16* kvraw = qraw + NTOT * 384;        // [n][768] (k,v pre-dw)
    u16* kvb   = (u16*)RC;                 // [n][768] (k,v post-dw)
    u16* QS    = (u16*)RA;                 // (Xbf dead)
    u16* AO    = (u16*)RA;                 // (QS dead)
    u16* xatt  = (u16*)RD;                 // [b][c][p] bf16
    u16* xn2   = (u16*)RA;                 // (AO dead)
    u16* x1    = (u16*)RB;                 // [n][1024] (qraw/kvraw dead)
    u16* x1d   = (u16*)RC;                 // [n][1024] (kvb dead)
    u16* fbf   = (u16*)RB;                 // [n][1024] (x1 dead)

    int NB16 = C * 16;

    // ---- attention ----
    hipMemsetAsync(qssq, 0, 2 * 3072 * sizeof(float), stream);
    ln_t_kernel<float><<<dim3(64, 6, C), dim3(256), 0, stream>>>(xb, m1, r1, ln1_w, ln1_b, Xbf);
    gemm_nk_kernel<16, true><<<dim3(NB16, 9), dim3(512), 0, stream>>>(
        Xbf, 384, 12, qkv_wp, nullptr, 0, 0, nullptr, 72,
        qkv_b, nullptr, nullptr, qraw, 384, 384, kvraw, 768, 1152, 0);
    dw8_kernel<<<dim3(C * 128, 6), dim3(256), 0, stream>>>(
        kvraw, 768, qkvdw_w + 384 * 9, qkvdw_b + 384, kvb, 768, 768);
    dwqnorm_kernel<<<dim3(64, C, 2), dim3(192), 0, stream>>>(
        qraw, qkvdw_w, qkvdw_b, SPM, kvb, QS, qssq, kssq);
    attnS_kernel<<<dim3(16, C * 8), dim3(256), 0, stream>>>(QS, kvb, attnP);
    blend_kernel<<<dim3(96 * C), dim3(256), 0, stream>>>(attnP, qssq, kssq, temp, wmix,
                                                         a1, a2, a3, a4, comb);
    combv_kernel<<<dim3(C * 1024), dim3(384), 0, stream>>>(kvb, comb, AO);
    gemm_nk_kernel<16, false><<<dim3(NB16, 3), dim3(512), 0, stream>>>(
        AO, 384, 12, pout_wp, nullptr, 0, 0, nullptr, 24,
        pout_b, xb, nullptr, xatt, 0, 1 << 30, nullptr, 0, 384, 1);

    // ---- feed-forward ----
    stats_kernel<u16><<<dim3((C * 1024 + 255) / 256), dim3(256), 0, stream>>>(xatt, mu2, rs2,
                                                                              C * 1024);
    ln_t_kernel<u16><<<dim3(64, 6, C), dim3(256), 0, stream>>>(xatt, mu2, rs2, ln2_w, ln2_b, xn2);
    gemm_nk_kernel<16, true><<<dim3(NB16, 8), dim3(512), 0, stream>>>(
        xn2, 384, 12, pin_wp, nullptr, 0, 0, nullptr, 64,
        pin_b, nullptr, nullptr, x1, 1024, 1 << 30, nullptr, 0, 1021, 0);
    dw8_kernel<<<dim3(C * 128, 8), dim3(256), 0, stream>>>(
        x1, 1024, dw_w, dw_b, x1d, 1024, 1021);
    gemm_nk_kernel<16, true><<<dim3(NB16, 8), dim3(512), 0, stream>>>(
        x1d, 1024, 32, adj1_wp, xn2, 384, 12, W3_wp, 64,
        b3v, nullptr, nullptr, fbf, 1024, 1 << 30, nullptr, 0, 1021, 2);
    gemm_nk_kernel<16, false><<<dim3(NB16, 3), dim3(512), 0, stream>>>(
        fbf, 1024, 32, fout_wp, nullptr, 0, 0, nullptr, 24,
        fout_b, xatt, outb, nullptr, 0, 1 << 30, nullptr, 0, 384, 3);
  }
}